// Round 2
// baseline (8897.572 us; speedup 1.0000x reference)
//
#include <hip/hip_runtime.h>
#include <hip/hip_bf16.h>

typedef unsigned short u16;
typedef unsigned int u32;
typedef __attribute__((ext_vector_type(8))) short short8;
typedef __attribute__((ext_vector_type(4))) float floatx4;

#define BB 32
#define CC 512
#define LL 16
#define DD 256
#define HH 1024
#define PP 16
#define NLAY 4

__device__ __forceinline__ float bf2f(u16 u) {
  u32 x = ((u32)u) << 16; float f; __builtin_memcpy(&f, &x, 4); return f;
}
__device__ __forceinline__ u16 f2bf(float f) {
  __hip_bfloat16 h = __float2bfloat16(f);
  u16 r; __builtin_memcpy(&r, &h, 2); return r;
}

// ---------------- fp32 -> bf16 weight conversion (one launch, 8 segments) ----------------
__global__ __launch_bounds__(256) void cvt_kernel(
    const float* __restrict__ s0, const float* __restrict__ s1,
    const float* __restrict__ s2, const float* __restrict__ s3,
    const float* __restrict__ s4, const float* __restrict__ s5,
    const float* __restrict__ s6, const float* __restrict__ s7,
    u16* __restrict__ dst)
{
  const float* srcs[8] = {s0, s1, s2, s3, s4, s5, s6, s7};
  const int pfx[8] = {786432, 1048576, 2097152, 3145728, 3407872, 6553600, 7602176, 7618560};
  int e = (blockIdx.x * 256 + threadIdx.x) * 4;
  int seg = 0;
  while (e >= pfx[seg]) seg++;
  int start = seg ? pfx[seg - 1] : 0;
  float4 f = *(const float4*)(srcs[seg] + (e - start));
  u16 o[4] = {f2bf(f.x), f2bf(f.y), f2bf(f.z), f2bf(f.w)};
  *(uint2*)(dst + e) = *(const uint2*)o;
}

// ---------------- embed + masked mean pool ----------------
__global__ __launch_bounds__(256) void embed_kernel(
    const int* __restrict__ vi, const int* __restrict__ si, const int* __restrict__ mk,
    const float* __restrict__ ve, const float* __restrict__ se,
    const float* __restrict__ lpe, const float* __restrict__ cpe,
    float* __restrict__ x, u16* __restrict__ xb)
{
  int bc = blockIdx.x;
  int c = bc & (CC - 1);
  int d = threadIdx.x;
  int base = bc * LL;
  float acc = 0.f; int cnt = 0;
  #pragma unroll
  for (int l = 0; l < LL; ++l) {
    if (mk[base + l]) {
      int v = vi[base + l], s = si[base + l];
      acc += ve[v * DD + d] + se[s * DD + d] + lpe[l * DD + d];
      cnt++;
    }
  }
  float r = acc / (float)cnt + cpe[c * DD + d];
  size_t o = (size_t)bc * DD + d;
  x[o] = r; xb[o] = f2bf(r);
}

// ---------------- MFMA GEMM: out[M,N] = A[M,K](bf16) @ W[N,K]^T(bf16) + bias(f32) ----------------
// block tile 64x128, per-wave 32x64 (2x4 of 16x16x32 mfma), BK=64.
// flags: bit0 = exact gelu, bit1 = fp32 output (else bf16)
__global__ __launch_bounds__(256) void gemm_kernel(
    const u16* __restrict__ A, const u16* __restrict__ W, const float* __restrict__ bias,
    const float* __restrict__ res, void* __restrict__ out,
    int M, int N, int K, int flags)
{
  __shared__ u16 As[64 * 64];
  __shared__ u16 Bs[128 * 64];
  int t = threadIdx.x;
  int lane = t & 63, wv = t >> 6;
  int wm = wv & 1, wn = wv >> 1;
  int bn0 = blockIdx.x * 128, bm0 = blockIdx.y * 64;
  int lr = t >> 2, lc = (t & 3) * 16;
  bool aok = (bm0 + lr) < M;
  const u16* Ap  = A + (size_t)(bm0 + lr) * K + lc;
  const u16* Wp0 = W + (size_t)(bn0 + lr) * K + lc;
  const u16* Wp1 = W + (size_t)(bn0 + 64 + lr) * K + lc;
  floatx4 acc[2][4];
  #pragma unroll
  for (int i = 0; i < 2; ++i)
    #pragma unroll
    for (int j = 0; j < 4; ++j)
      acc[i][j] = (floatx4){0.f, 0.f, 0.f, 0.f};
  int mr = lane & 15, qq = lane >> 4;
  for (int k0 = 0; k0 < K; k0 += 64) {
    uint4 a0 = {0,0,0,0}, a1 = {0,0,0,0};
    if (aok) { a0 = *(const uint4*)Ap; a1 = *(const uint4*)(Ap + 8); }
    uint4 w00 = *(const uint4*)Wp0, w01 = *(const uint4*)(Wp0 + 8);
    uint4 w10 = *(const uint4*)Wp1, w11 = *(const uint4*)(Wp1 + 8);
    Ap += 64; Wp0 += 64; Wp1 += 64;
    __syncthreads();
    *(uint4*)&As[lr * 64 + lc] = a0;         *(uint4*)&As[lr * 64 + lc + 8] = a1;
    *(uint4*)&Bs[lr * 64 + lc] = w00;        *(uint4*)&Bs[lr * 64 + lc + 8] = w01;
    *(uint4*)&Bs[(64 + lr) * 64 + lc] = w10; *(uint4*)&Bs[(64 + lr) * 64 + lc + 8] = w11;
    __syncthreads();
    #pragma unroll
    for (int ks = 0; ks < 2; ++ks) {
      short8 af[2], bfr[4];
      #pragma unroll
      for (int i = 0; i < 2; ++i)
        af[i] = *(const short8*)&As[(wm * 32 + i * 16 + mr) * 64 + ks * 32 + qq * 8];
      #pragma unroll
      for (int j = 0; j < 4; ++j)
        bfr[j] = *(const short8*)&Bs[(wn * 64 + j * 16 + mr) * 64 + ks * 32 + qq * 8];
      #pragma unroll
      for (int i = 0; i < 2; ++i)
        #pragma unroll
        for (int j = 0; j < 4; ++j)
          acc[i][j] = __builtin_amdgcn_mfma_f32_16x16x32_bf16(af[i], bfr[j], acc[i][j], 0, 0, 0);
    }
  }
  bool do_gelu = (flags & 1) != 0, of32 = (flags & 2) != 0;
  #pragma unroll
  for (int j = 0; j < 4; ++j) {
    int gn = bn0 + wn * 64 + j * 16 + mr;
    float bv = bias[gn];
    #pragma unroll
    for (int i = 0; i < 2; ++i) {
      #pragma unroll
      for (int r = 0; r < 4; ++r) {
        int gm = bm0 + wm * 32 + i * 16 + qq * 4 + r;
        if (gm < M) {
          float v = acc[i][j][r] + bv;
          if (do_gelu) v = 0.5f * v * (1.f + erff(v * 0.70710678118654752f));
          if (res) v += res[(size_t)gm * N + gn];
          if (of32) ((float*)out)[(size_t)gm * N + gn] = v;
          else      ((u16*)out)[(size_t)gm * N + gn] = f2bf(v);
        }
      }
    }
  }
}

// ---------------- LayerNorm rows (D=256 or 1024), fp32 in, fp32/bf16 out ----------------
__global__ __launch_bounds__(256) void ln_kernel(
    const float* __restrict__ in, const float* __restrict__ w, const float* __restrict__ b,
    float* __restrict__ outf, u16* __restrict__ outb, int D)
{
  int row = blockIdx.x, t = threadIdx.x;
  const float* xr = in + (size_t)row * D;
  int nv = D >> 8;
  float v[4];
  float s = 0.f, s2 = 0.f;
  for (int i = 0; i < nv; ++i) { float xv = xr[t + i * 256]; v[i] = xv; s += xv; s2 += xv * xv; }
  #pragma unroll
  for (int off = 32; off > 0; off >>= 1) { s += __shfl_xor(s, off); s2 += __shfl_xor(s2, off); }
  __shared__ float ss[4], ssq[4];
  int lane = t & 63, wvi = t >> 6;
  if (lane == 0) { ss[wvi] = s; ssq[wvi] = s2; }
  __syncthreads();
  s = ss[0] + ss[1] + ss[2] + ss[3];
  s2 = ssq[0] + ssq[1] + ssq[2] + ssq[3];
  float mean = s / (float)D;
  float var = s2 / (float)D - mean * mean;
  float inv = rsqrtf(var + 1e-5f);
  for (int i = 0; i < nv; ++i) {
    int col = t + i * 256;
    float y = (v[i] - mean) * inv * w[col] + b[col];
    size_t o = (size_t)row * D + col;
    if (outf) outf[o] = y;
    if (outb) outb[o] = f2bf(y);
  }
}

// ---------------- encoder self-attention, dh=32, S=512, NH=8 ----------------
// grid (2 query-halves, NH, B). K transposed in LDS; V read from global (L1-resident 32KB).
// LDS = 32KB Kt + 8KB prow = 40KB.
__global__ __launch_bounds__(256) void attn_enc_kernel(
    const u16* __restrict__ qkv, u16* __restrict__ out)
{
  __shared__ u16 Kt[32 * 512];
  __shared__ float prow[4 * 512];
  int qhalf = blockIdx.x, h = blockIdx.y, b = blockIdx.z;
  int t = threadIdx.x, lane = t & 63, w = t >> 6;
  #pragma unroll
  for (int it = 0; it < 8; ++it) {
    int idx = t + it * 256;
    int j = idx >> 2, d0 = (idx & 3) * 8;
    const u16* kp = qkv + ((size_t)(b * CC + j)) * 768 + 256 + h * 32 + d0;
    uint4 kk = *(const uint4*)kp;
    u16 tmp[8]; *(uint4*)tmp = kk;
    #pragma unroll
    for (int i = 0; i < 8; ++i) Kt[(d0 + i) * 512 + j] = tmp[i];
  }
  __syncthreads();
  int d2 = lane & 15, qt = lane >> 4;
  const u16* vbase = qkv + (size_t)b * CC * 768 + 512 + h * 32 + d2 * 2;
  for (int qi = 0; qi < 64; ++qi) {
    int q = qhalf * 256 + w * 64 + qi;
    const u16* qp = qkv + ((size_t)(b * CC + q)) * 768 + h * 32;
    float qv[32];
    #pragma unroll
    for (int dd = 0; dd < 32; dd += 8) {
      u16 tq[8]; *(uint4*)tq = *(const uint4*)(qp + dd);
      #pragma unroll
      for (int i = 0; i < 8; ++i) qv[dd + i] = bf2f(tq[i]);
    }
    float s[8];
    #pragma unroll
    for (int tt = 0; tt < 8; ++tt) {
      int j = tt * 64 + lane;
      float a = 0.f;
      #pragma unroll
      for (int d = 0; d < 32; ++d) a += qv[d] * bf2f(Kt[d * 512 + j]);
      s[tt] = a * 0.17677669529663687f;  // 1/sqrt(32)
    }
    float m = -1e30f;
    #pragma unroll
    for (int tt = 0; tt < 8; ++tt) m = fmaxf(m, s[tt]);
    #pragma unroll
    for (int off = 32; off > 0; off >>= 1) m = fmaxf(m, __shfl_xor(m, off));
    float l = 0.f;
    #pragma unroll
    for (int tt = 0; tt < 8; ++tt) {
      float pe = __expf(s[tt] - m);
      l += pe;
      prow[w * 512 + tt * 64 + lane] = pe;
    }
    #pragma unroll
    for (int off = 32; off > 0; off >>= 1) l += __shfl_xor(l, off);
    float inv = 1.f / l;
    float ax = 0.f, ay = 0.f;
    for (int jj = 0; jj < 128; ++jj) {
      int j = qt * 128 + jj;
      float pe = prow[w * 512 + j];
      u32 vv = *(const u32*)(vbase + (size_t)j * 768);
      ax += pe * bf2f((u16)(vv & 0xffff));
      ay += pe * bf2f((u16)(vv >> 16));
    }
    ax += __shfl_xor(ax, 16); ax += __shfl_xor(ax, 32);
    ay += __shfl_xor(ay, 16); ay += __shfl_xor(ay, 32);
    if (lane < 16) {
      size_t o = ((size_t)(b * CC + q)) * DD + h * 32 + d2 * 2;
      u32 pk = (u32)f2bf(ax * inv) | ((u32)f2bf(ay * inv) << 16);
      *(u32*)(out + o) = pk;
    }
  }
}

// ---------------- prefix cross-attention: qh[16,H] vs kb/vb[B*C,H], dh=128 ----------------
__global__ __launch_bounds__(256) void attn_pref_kernel(
    const u16* __restrict__ qh, const u16* __restrict__ kb, const u16* __restrict__ vb,
    u16* __restrict__ out)
{
  __shared__ float qs[16 * 128];
  __shared__ float prow[16 * 512];
  int h = blockIdx.x, b = blockIdx.y;
  int t = threadIdx.x, lane = t & 63, w = t >> 6;
  for (int idx = t; idx < 2048; idx += 256) {
    int r = idx >> 7, d = idx & 127;
    qs[idx] = bf2f(qh[r * HH + h * 128 + d]);
  }
  __syncthreads();
  float a[8][4];
  #pragma unroll
  for (int tt = 0; tt < 8; ++tt)
    #pragma unroll
    for (int r = 0; r < 4; ++r) a[tt][r] = 0.f;
  for (int dd = 0; dd < 128; dd += 8) {
    float qr[4][8];
    #pragma unroll
    for (int r = 0; r < 4; ++r)
      #pragma unroll
      for (int i = 0; i < 8; ++i) qr[r][i] = qs[(w * 4 + r) * 128 + dd + i];
    #pragma unroll
    for (int tt = 0; tt < 8; ++tt) {
      int j = tt * 64 + lane;
      const u16* kp = kb + ((size_t)(b * CC + j)) * HH + h * 128 + dd;
      u16 tk[8]; *(uint4*)tk = *(const uint4*)kp;
      #pragma unroll
      for (int i = 0; i < 8; ++i) {
        float kf = bf2f(tk[i]);
        #pragma unroll
        for (int r = 0; r < 4; ++r) a[tt][r] += qr[r][i] * kf;
      }
    }
  }
  for (int r = 0; r < 4; ++r) {
    float m = -1e30f;
    #pragma unroll
    for (int tt = 0; tt < 8; ++tt) m = fmaxf(m, a[tt][r] * 0.08838834764831845f);
    #pragma unroll
    for (int off = 32; off > 0; off >>= 1) m = fmaxf(m, __shfl_xor(m, off));
    float l = 0.f; float pe[8];
    #pragma unroll
    for (int tt = 0; tt < 8; ++tt) { pe[tt] = __expf(a[tt][r] * 0.08838834764831845f - m); l += pe[tt]; }
    #pragma unroll
    for (int off = 32; off > 0; off >>= 1) l += __shfl_xor(l, off);
    float inv = 1.f / l;
    #pragma unroll
    for (int tt = 0; tt < 8; ++tt) prow[(w * 4 + r) * 512 + tt * 64 + lane] = pe[tt] * inv;
  }
  int dl = lane * 2;
  float ox[4] = {0,0,0,0}, oy[4] = {0,0,0,0};
  for (int j = 0; j < 512; ++j) {
    const u16* vp = vb + ((size_t)(b * CC + j)) * HH + h * 128 + dl;
    u32 vv = *(const u32*)vp;
    float vx = bf2f((u16)(vv & 0xffff)), vy = bf2f((u16)(vv >> 16));
    #pragma unroll
    for (int r = 0; r < 4; ++r) {
      float pe = prow[(w * 4 + r) * 512 + j];
      ox[r] += pe * vx; oy[r] += pe * vy;
    }
  }
  #pragma unroll
  for (int r = 0; r < 4; ++r) {
    size_t o = ((size_t)(b * PP + w * 4 + r)) * HH + h * 128 + dl;
    u32 pk = (u32)f2bf(ox[r]) | ((u32)f2bf(oy[r]) << 16);
    *(u32*)(out + o) = pk;
  }
}

// residual for prefix output: broadcast pq (fp32) over batch
__global__ __launch_bounds__(256) void fillres_kernel(const float* __restrict__ pq, float* __restrict__ res)
{
  int i = blockIdx.x * 256 + threadIdx.x;  // 512*1024 total
  int pr = (i >> 10) & 15; int chn = i & 1023;
  res[i] = pq[pr * HH + chn];
}

extern "C" void kernel_launch(void* const* d_in, const int* in_sizes, int n_in,
                              void* d_out, int out_size, void* d_ws, size_t ws_size,
                              hipStream_t stream)
{
  const int* vi = (const int*)d_in[0];
  const int* si = (const int*)d_in[1];
  const int* mk = (const int*)d_in[2];
  const float* ve   = (const float*)d_in[3];
  const float* se   = (const float*)d_in[4];
  const float* lpe  = (const float*)d_in[5];
  const float* cpe  = (const float*)d_in[6];
  const float* eiw  = (const float*)d_in[7];
  const float* eib  = (const float*)d_in[8];
  const float* eow  = (const float*)d_in[9];
  const float* eob  = (const float*)d_in[10];
  const float* f1w  = (const float*)d_in[11];
  const float* f1b  = (const float*)d_in[12];
  const float* f2w  = (const float*)d_in[13];
  const float* f2b  = (const float*)d_in[14];
  const float* n1w  = (const float*)d_in[15];
  const float* n1b  = (const float*)d_in[16];
  const float* n2w  = (const float*)d_in[17];
  const float* n2b  = (const float*)d_in[18];
  const float* tlw  = (const float*)d_in[19];
  const float* tlb  = (const float*)d_in[20];
  const float* thw  = (const float*)d_in[21];
  const float* thb  = (const float*)d_in[22];
  const float* pq   = (const float*)d_in[23];
  const float* paiw = (const float*)d_in[24];
  const float* paib = (const float*)d_in[25];
  const float* paow = (const float*)d_in[26];
  const float* paob = (const float*)d_in[27];
  const float* pnw  = (const float*)d_in[28];
  const float* pnb  = (const float*)d_in[29];

  const int NROW = BB * CC;  // 16384
  const size_t MB = 1048576;
  char* base = (char*)d_ws;
  // phase overlays (total <= ~126 MiB):
  float* x    = (float*)(base);              // [0,16M)   fp32 residual
  float* resb = (float*)(base + 16 * MB);    // [16M,32M) fp32 gemm out
  u16* xb     = (u16*)(base + 32 * MB);      // [32M,40M) bf16 residual copy
  char* pool  = base + 40 * MB;              // [40M,72M)
  u16* qkvb   = (u16*)pool;                  //   qkv 24MB (encoder)
  u16* atto   = (u16*)(pool + 24 * MB);      //   attn out 8MB (encoder)
  u16* h1     = (u16*)pool;                  //   ff hidden 32MB (encoder, qkv/atto dead)
  u16* ch     = (u16*)pool;                  //   clause hidden 32MB (final, h1 dead)
  u16* vb     = (u16*)(base + 72 * MB);      // [72M,104M) prefix V
  u16* wbf    = (u16*)(base + 104 * MB);     // [104M,~118.6M) bf16 weights
  u16* kb     = (u16*)base;                  // final phase: overlays x+resb (dead)
  u16* tln    = xb;                          // final phase: overlays xb (dead)
  u16* qh     = (u16*)(base + 120 * MB);
  u16* prefo  = qh + 32768;
  float* prefres = (float*)(base + 122 * MB);
  float* prefout = (float*)(base + 124 * MB);

  // bf16 weight views (offsets in elements within wbf)
  u16* eiw_b  = wbf + 0;
  u16* eow_b  = wbf + 786432;
  u16* f1w_b  = wbf + 1048576;
  u16* f2w_b  = wbf + 2097152;
  u16* thw_b  = wbf + 3145728;
  u16* paiw_b = wbf + 3407872;
  u16* paow_b = wbf + 6553600;
  u16* pqb    = wbf + 7602176;

  dim3 blk(256);
  cvt_kernel<<<7440, blk, 0, stream>>>(eiw, eow, f1w, f2w, thw, paiw, paow, pq, wbf);
  embed_kernel<<<NROW, blk, 0, stream>>>(vi, si, mk, ve, se, lpe, cpe, x, xb);
  for (int i = 0; i < NLAY; ++i) {
    gemm_kernel<<<dim3(768/128, NROW/64), blk, 0, stream>>>(
        xb, eiw_b + (size_t)i*768*DD, eib + i*768, nullptr, qkvb, NROW, 768, DD, 0);
    attn_enc_kernel<<<dim3(2, 8, BB), blk, 0, stream>>>(qkvb, atto);
    gemm_kernel<<<dim3(256/128, NROW/64), blk, 0, stream>>>(
        atto, eow_b + (size_t)i*DD*DD, eob + i*DD, x, resb, NROW, DD, DD, 2);
    ln_kernel<<<NROW, blk, 0, stream>>>(resb, n1w + i*DD, n1b + i*DD, x, xb, DD);
    gemm_kernel<<<dim3(1024/128, NROW/64), blk, 0, stream>>>(
        xb, f1w_b + (size_t)i*HH*DD, f1b + i*HH, nullptr, h1, NROW, HH, DD, 1);
    gemm_kernel<<<dim3(256/128, NROW/64), blk, 0, stream>>>(
        h1, f2w_b + (size_t)i*DD*HH, f2b + i*DD, x, resb, NROW, DD, HH, 2);
    ln_kernel<<<NROW, blk, 0, stream>>>(resb, n2w + i*DD, n2b + i*DD, x, xb, DD);
  }
  // final: to_hidden + prefix adapter
  ln_kernel<<<NROW, blk, 0, stream>>>(x, tlw, tlb, nullptr, tln, DD);
  gemm_kernel<<<dim3(1024/128, NROW/64), blk, 0, stream>>>(
      tln, thw_b, thb, nullptr, ch, NROW, HH, DD, 0);
  gemm_kernel<<<dim3(1024/128, NROW/64), blk, 0, stream>>>(
      ch, paiw_b + (size_t)HH*HH, paib + HH, nullptr, kb, NROW, HH, HH, 0);
  gemm_kernel<<<dim3(1024/128, NROW/64), blk, 0, stream>>>(
      ch, paiw_b + (size_t)2*HH*HH, paib + 2*HH, nullptr, vb, NROW, HH, HH, 0);
  gemm_kernel<<<dim3(1024/128, 1), blk, 0, stream>>>(
      pqb, paiw_b, paib, nullptr, qh, PP, HH, HH, 0);
  attn_pref_kernel<<<dim3(8, BB), blk, 0, stream>>>(qh, kb, vb, prefo);
  fillres_kernel<<<2048, blk, 0, stream>>>(pq, prefres);
  gemm_kernel<<<dim3(1024/128, (BB*PP)/64), blk, 0, stream>>>(
      prefo, paow_b, paob, prefres, prefout, BB*PP, HH, HH, 2);
  ln_kernel<<<BB*PP, blk, 0, stream>>>(prefout, pnw, pnb, (float*)d_out, nullptr, HH);
}

// Round 3
// 1235.001 us; speedup vs baseline: 7.2045x; 7.2045x over previous
//
#include <hip/hip_runtime.h>
#include <hip/hip_bf16.h>

typedef unsigned short u16;
typedef unsigned int u32;
typedef __attribute__((ext_vector_type(8))) short short8;
typedef __attribute__((ext_vector_type(4))) float floatx4;

#define BB 32
#define CC 512
#define LL 16
#define DD 256
#define HH 1024
#define PP 16
#define NLAY 4

__device__ __forceinline__ float bf2f(u16 u) {
  u32 x = ((u32)u) << 16; float f; __builtin_memcpy(&f, &x, 4); return f;
}
__device__ __forceinline__ u16 f2bf(float f) {
  __hip_bfloat16 h = __float2bfloat16(f);
  u16 r; __builtin_memcpy(&r, &h, 2); return r;
}

// ---------------- fp32 -> bf16 weight conversion (one launch, 8 segments) ----------------
__global__ __launch_bounds__(256) void cvt_kernel(
    const float* __restrict__ s0, const float* __restrict__ s1,
    const float* __restrict__ s2, const float* __restrict__ s3,
    const float* __restrict__ s4, const float* __restrict__ s5,
    const float* __restrict__ s6, const float* __restrict__ s7,
    u16* __restrict__ dst)
{
  const float* srcs[8] = {s0, s1, s2, s3, s4, s5, s6, s7};
  const int pfx[8] = {786432, 1048576, 2097152, 3145728, 3407872, 6553600, 7602176, 7618560};
  int e = (blockIdx.x * 256 + threadIdx.x) * 4;
  int seg = 0;
  while (e >= pfx[seg]) seg++;
  int start = seg ? pfx[seg - 1] : 0;
  float4 f = *(const float4*)(srcs[seg] + (e - start));
  u16 o[4] = {f2bf(f.x), f2bf(f.y), f2bf(f.z), f2bf(f.w)};
  *(uint2*)(dst + e) = *(const uint2*)o;
}

// ---------------- embed + masked mean pool ----------------
__global__ __launch_bounds__(256) void embed_kernel(
    const int* __restrict__ vi, const int* __restrict__ si, const int* __restrict__ mk,
    const float* __restrict__ ve, const float* __restrict__ se,
    const float* __restrict__ lpe, const float* __restrict__ cpe,
    float* __restrict__ x, u16* __restrict__ xb)
{
  int bc = blockIdx.x;
  int c = bc & (CC - 1);
  int d = threadIdx.x;
  int base = bc * LL;
  float acc = 0.f; int cnt = 0;
  #pragma unroll
  for (int l = 0; l < LL; ++l) {
    if (mk[base + l]) {
      int v = vi[base + l], s = si[base + l];
      acc += ve[v * DD + d] + se[s * DD + d] + lpe[l * DD + d];
      cnt++;
    }
  }
  float r = acc / (float)cnt + cpe[c * DD + d];
  size_t o = (size_t)bc * DD + d;
  x[o] = r; xb[o] = f2bf(r);
}

// ---------------- MFMA GEMM: out[M,N] = A[M,K](bf16) @ W[N,K]^T(bf16) + bias(f32) ----------------
// flags: bit0 = exact gelu, bit1 = fp32 output (else bf16)
__global__ __launch_bounds__(256) void gemm_kernel(
    const u16* __restrict__ A, const u16* __restrict__ W, const float* __restrict__ bias,
    const float* __restrict__ res, void* __restrict__ out,
    int M, int N, int K, int flags)
{
  __shared__ __align__(16) u16 As[64 * 64];
  __shared__ __align__(16) u16 Bs[128 * 64];
  int t = threadIdx.x;
  int lane = t & 63, wv = t >> 6;
  int wm = wv & 1, wn = wv >> 1;
  int bn0 = blockIdx.x * 128, bm0 = blockIdx.y * 64;
  int lr = t >> 2, lc = (t & 3) * 16;
  bool aok = (bm0 + lr) < M;
  const u16* Ap  = A + (size_t)(bm0 + lr) * K + lc;
  const u16* Wp0 = W + (size_t)(bn0 + lr) * K + lc;
  const u16* Wp1 = W + (size_t)(bn0 + 64 + lr) * K + lc;
  floatx4 acc[2][4];
  #pragma unroll
  for (int i = 0; i < 2; ++i)
    #pragma unroll
    for (int j = 0; j < 4; ++j)
      acc[i][j] = (floatx4){0.f, 0.f, 0.f, 0.f};
  int mr = lane & 15, qq = lane >> 4;
  for (int k0 = 0; k0 < K; k0 += 64) {
    uint4 a0 = {0,0,0,0}, a1 = {0,0,0,0};
    if (aok) { a0 = *(const uint4*)Ap; a1 = *(const uint4*)(Ap + 8); }
    uint4 w00 = *(const uint4*)Wp0, w01 = *(const uint4*)(Wp0 + 8);
    uint4 w10 = *(const uint4*)Wp1, w11 = *(const uint4*)(Wp1 + 8);
    Ap += 64; Wp0 += 64; Wp1 += 64;
    __syncthreads();
    *(uint4*)&As[lr * 64 + lc] = a0;         *(uint4*)&As[lr * 64 + lc + 8] = a1;
    *(uint4*)&Bs[lr * 64 + lc] = w00;        *(uint4*)&Bs[lr * 64 + lc + 8] = w01;
    *(uint4*)&Bs[(64 + lr) * 64 + lc] = w10; *(uint4*)&Bs[(64 + lr) * 64 + lc + 8] = w11;
    __syncthreads();
    #pragma unroll
    for (int ks = 0; ks < 2; ++ks) {
      short8 af[2], bfr[4];
      #pragma unroll
      for (int i = 0; i < 2; ++i)
        af[i] = *(const short8*)&As[(wm * 32 + i * 16 + mr) * 64 + ks * 32 + qq * 8];
      #pragma unroll
      for (int j = 0; j < 4; ++j)
        bfr[j] = *(const short8*)&Bs[(wn * 64 + j * 16 + mr) * 64 + ks * 32 + qq * 8];
      #pragma unroll
      for (int i = 0; i < 2; ++i)
        #pragma unroll
        for (int j = 0; j < 4; ++j)
          acc[i][j] = __builtin_amdgcn_mfma_f32_16x16x32_bf16(af[i], bfr[j], acc[i][j], 0, 0, 0);
    }
  }
  bool do_gelu = (flags & 1) != 0, of32 = (flags & 2) != 0;
  #pragma unroll
  for (int j = 0; j < 4; ++j) {
    int gn = bn0 + wn * 64 + j * 16 + mr;
    float bv = bias[gn];
    #pragma unroll
    for (int i = 0; i < 2; ++i) {
      #pragma unroll
      for (int r = 0; r < 4; ++r) {
        int gm = bm0 + wm * 32 + i * 16 + qq * 4 + r;
        if (gm < M) {
          float v = acc[i][j][r] + bv;
          if (do_gelu) v = 0.5f * v * (1.f + erff(v * 0.70710678118654752f));
          if (res) v += res[(size_t)gm * N + gn];
          if (of32) ((float*)out)[(size_t)gm * N + gn] = v;
          else      ((u16*)out)[(size_t)gm * N + gn] = f2bf(v);
        }
      }
    }
  }
}

// ---------------- LayerNorm rows (D=256 or 1024), fp32 in, fp32/bf16 out ----------------
__global__ __launch_bounds__(256) void ln_kernel(
    const float* __restrict__ in, const float* __restrict__ w, const float* __restrict__ b,
    float* __restrict__ outf, u16* __restrict__ outb, int D)
{
  int row = blockIdx.x, t = threadIdx.x;
  const float* xr = in + (size_t)row * D;
  int nv = D >> 8;
  float v[4];
  float s = 0.f, s2 = 0.f;
  for (int i = 0; i < nv; ++i) { float xv = xr[t + i * 256]; v[i] = xv; s += xv; s2 += xv * xv; }
  #pragma unroll
  for (int off = 32; off > 0; off >>= 1) { s += __shfl_xor(s, off); s2 += __shfl_xor(s2, off); }
  __shared__ float ss[4], ssq[4];
  int lane = t & 63, wvi = t >> 6;
  if (lane == 0) { ss[wvi] = s; ssq[wvi] = s2; }
  __syncthreads();
  s = ss[0] + ss[1] + ss[2] + ss[3];
  s2 = ssq[0] + ssq[1] + ssq[2] + ssq[3];
  float mean = s / (float)D;
  float var = s2 / (float)D - mean * mean;
  float inv = rsqrtf(var + 1e-5f);
  for (int i = 0; i < nv; ++i) {
    int col = t + i * 256;
    float y = (v[i] - mean) * inv * w[col] + b[col];
    size_t o = (size_t)row * D + col;
    if (outf) outf[o] = y;
    if (outb) outb[o] = f2bf(y);
  }
}

// ---------------- V reshape: qkv[row][512+h*32+d] -> vt[bh][d][jt*128 + perm(jl)] ----------------
// perm(jl) = (jl&15)*8 + (jl>>4)  (so PV's A/B k-orders match the P-store pattern)
__global__ __launch_bounds__(256) void reshape_v_kernel(
    const u16* __restrict__ qkv, u16* __restrict__ vt)
{
  __shared__ __align__(16) u16 T[32 * 136];
  int jt = blockIdx.x, h = blockIdx.y, b = blockIdx.z;
  int t = threadIdx.x;
  int d0 = (t & 3) * 8;
  #pragma unroll
  for (int rep = 0; rep < 2; ++rep) {
    int jl = (t >> 2) + rep * 64;
    uint4 vv = *(const uint4*)(qkv + (size_t)(b * CC + jt * 128 + jl) * 768 + 512 + h * 32 + d0);
    u16 tmp[8]; *(uint4*)tmp = vv;
    int jp = (jl & 15) * 8 + (jl >> 4);
    #pragma unroll
    for (int i = 0; i < 8; ++i) T[(d0 + i) * 136 + jp] = tmp[i];
  }
  __syncthreads();
  int bh = b * 8 + h;
  int d = t >> 3;
  #pragma unroll
  for (int rep = 0; rep < 2; ++rep) {
    int jp = (t & 7) * 8 + rep * 64;
    uint4 vv = *(const uint4*)&T[d * 136 + jp];
    *(uint4*)(vt + (size_t)bh * 16384 + d * 512 + jt * 128 + jp) = vv;
  }
}

// ---------------- encoder self-attention v2: MFMA flash-style ----------------
// grid (4 qtiles, 8 h, 32 b). Block: 128 q rows; wave: 32 rows (2 m-tiles).
// dh=32 = one 16x16x32 k-step. No max-subtract (scores structurally bounded, |scaled| << 1).
__global__ __launch_bounds__(256) void attn_enc2_kernel(
    const u16* __restrict__ qkv, const u16* __restrict__ vt, u16* __restrict__ out)
{
  __shared__ __align__(16) u16 Ks[128 * 40];     // K tile, pad 40
  __shared__ __align__(16) u16 Vt[32 * 136];     // V^T tile (j pre-permuted), pad 136
  __shared__ __align__(16) u16 Pl[4 * 32 * 136]; // per-wave P tiles, k-permuted
  int qt = blockIdx.x, h = blockIdx.y, b = blockIdx.z;
  int t = threadIdx.x, lane = t & 63, w = t >> 6;
  int mrow = lane & 15, quad = lane >> 4;
  int bh = b * 8 + h;
  int q0 = qt * 128 + w * 32;
  short8 qf[2];
  #pragma unroll
  for (int mi = 0; mi < 2; ++mi)
    qf[mi] = *(const short8*)(qkv + (size_t)(b * CC + q0 + mi * 16 + mrow) * 768 + h * 32 + quad * 8);
  floatx4 o[2][2];
  #pragma unroll
  for (int mi = 0; mi < 2; ++mi)
    #pragma unroll
    for (int di = 0; di < 2; ++di) o[mi][di] = (floatx4){0.f, 0.f, 0.f, 0.f};
  float lst[2][4] = {{0.f,0.f,0.f,0.f},{0.f,0.f,0.f,0.f}};
  const float sc = 0.17677669529663687f * 1.4426950408889634f;  // (1/sqrt(32))*log2(e)
  const floatx4 zf = (floatx4){0.f, 0.f, 0.f, 0.f};
  for (int jt = 0; jt < 4; ++jt) {
    if (jt) __syncthreads();
    {  // stage K tile (natural layout, padded)
      int j = t >> 1, half = t & 1;
      uint4 kk = *(const uint4*)(qkv + (size_t)(b * CC + jt * 128 + j) * 768 + 256 + h * 32 + half * 8);
      *(uint4*)&Ks[j * 40 + half * 8] = kk;
    }
    {  // stage Vt tile (already transposed+permuted in global)
      int d = t >> 3;
      #pragma unroll
      for (int rep = 0; rep < 2; ++rep) {
        int jp = (t & 7) * 8 + rep * 64;
        uint4 vv = *(const uint4*)(vt + (size_t)bh * 16384 + d * 512 + jt * 128 + jp);
        *(uint4*)&Vt[d * 136 + jp] = vv;
      }
    }
    __syncthreads();
    floatx4 s[2][8];
    #pragma unroll
    for (int nj = 0; nj < 8; ++nj) {
      short8 bf = *(const short8*)&Ks[(nj * 16 + mrow) * 40 + quad * 8];
      s[0][nj] = __builtin_amdgcn_mfma_f32_16x16x32_bf16(qf[0], bf, zf, 0, 0, 0);
      s[1][nj] = __builtin_amdgcn_mfma_f32_16x16x32_bf16(qf[1], bf, zf, 0, 0, 0);
    }
    // exp + row-sum partials + packed P store (k' = mrow*8+nj matches vt perm)
    #pragma unroll
    for (int mi = 0; mi < 2; ++mi) {
      #pragma unroll
      for (int r = 0; r < 4; ++r) {
        float ps = 0.f; u16 hv[8];
        #pragma unroll
        for (int nj = 0; nj < 8; ++nj) {
          float p = exp2f(s[mi][nj][r] * sc);
          ps += p; hv[nj] = f2bf(p);
        }
        lst[mi][r] += ps;
        *(uint4*)&Pl[(w * 32 + mi * 16 + quad * 4 + r) * 136 + mrow * 8] = *(uint4*)hv;
      }
    }
    #pragma unroll
    for (int ks = 0; ks < 4; ++ks) {
      short8 a0 = *(const short8*)&Pl[(w * 32 + mrow) * 136 + ks * 32 + quad * 8];
      short8 a1 = *(const short8*)&Pl[(w * 32 + 16 + mrow) * 136 + ks * 32 + quad * 8];
      short8 b0 = *(const short8*)&Vt[mrow * 136 + ks * 32 + quad * 8];
      short8 b1 = *(const short8*)&Vt[(16 + mrow) * 136 + ks * 32 + quad * 8];
      o[0][0] = __builtin_amdgcn_mfma_f32_16x16x32_bf16(a0, b0, o[0][0], 0, 0, 0);
      o[0][1] = __builtin_amdgcn_mfma_f32_16x16x32_bf16(a0, b1, o[0][1], 0, 0, 0);
      o[1][0] = __builtin_amdgcn_mfma_f32_16x16x32_bf16(a1, b0, o[1][0], 0, 0, 0);
      o[1][1] = __builtin_amdgcn_mfma_f32_16x16x32_bf16(a1, b1, o[1][1], 0, 0, 0);
    }
  }
  #pragma unroll
  for (int mi = 0; mi < 2; ++mi) {
    #pragma unroll
    for (int r = 0; r < 4; ++r) {
      float l = lst[mi][r];
      l += __shfl_xor(l, 1); l += __shfl_xor(l, 2);
      l += __shfl_xor(l, 4); l += __shfl_xor(l, 8);
      float inv = 1.f / l;
      int row = b * CC + q0 + mi * 16 + quad * 4 + r;
      #pragma unroll
      for (int di = 0; di < 2; ++di)
        out[(size_t)row * DD + h * 32 + di * 16 + mrow] = f2bf(o[mi][di][r] * inv);
    }
  }
}

// ---------------- prefix cross-attention: qh[16,H] vs kb/vb[B*C,H], dh=128 ----------------
__global__ __launch_bounds__(256) void attn_pref_kernel(
    const u16* __restrict__ qh, const u16* __restrict__ kb, const u16* __restrict__ vb,
    u16* __restrict__ out)
{
  __shared__ float qs[16 * 128];
  __shared__ float prow[16 * 512];
  int h = blockIdx.x, b = blockIdx.y;
  int t = threadIdx.x, lane = t & 63, w = t >> 6;
  for (int idx = t; idx < 2048; idx += 256) {
    int r = idx >> 7, d = idx & 127;
    qs[idx] = bf2f(qh[r * HH + h * 128 + d]);
  }
  __syncthreads();
  float a[8][4];
  #pragma unroll
  for (int tt = 0; tt < 8; ++tt)
    #pragma unroll
    for (int r = 0; r < 4; ++r) a[tt][r] = 0.f;
  for (int dd = 0; dd < 128; dd += 8) {
    float qr[4][8];
    #pragma unroll
    for (int r = 0; r < 4; ++r)
      #pragma unroll
      for (int i = 0; i < 8; ++i) qr[r][i] = qs[(w * 4 + r) * 128 + dd + i];
    #pragma unroll
    for (int tt = 0; tt < 8; ++tt) {
      int j = tt * 64 + lane;
      const u16* kp = kb + ((size_t)(b * CC + j)) * HH + h * 128 + dd;
      u16 tk[8]; *(uint4*)tk = *(const uint4*)kp;
      #pragma unroll
      for (int i = 0; i < 8; ++i) {
        float kf = bf2f(tk[i]);
        #pragma unroll
        for (int r = 0; r < 4; ++r) a[tt][r] += qr[r][i] * kf;
      }
    }
  }
  for (int r = 0; r < 4; ++r) {
    float m = -1e30f;
    #pragma unroll
    for (int tt = 0; tt < 8; ++tt) m = fmaxf(m, a[tt][r] * 0.08838834764831845f);
    #pragma unroll
    for (int off = 32; off > 0; off >>= 1) m = fmaxf(m, __shfl_xor(m, off));
    float l = 0.f; float pe[8];
    #pragma unroll
    for (int tt = 0; tt < 8; ++tt) { pe[tt] = __expf(a[tt][r] * 0.08838834764831845f - m); l += pe[tt]; }
    #pragma unroll
    for (int off = 32; off > 0; off >>= 1) l += __shfl_xor(l, off);
    float inv = 1.f / l;
    #pragma unroll
    for (int tt = 0; tt < 8; ++tt) prow[(w * 4 + r) * 512 + tt * 64 + lane] = pe[tt] * inv;
  }
  int dl = lane * 2;
  float ox[4] = {0,0,0,0}, oy[4] = {0,0,0,0};
  for (int j = 0; j < 512; ++j) {
    const u16* vp = vb + ((size_t)(b * CC + j)) * HH + h * 128 + dl;
    u32 vv = *(const u32*)vp;
    float vx = bf2f((u16)(vv & 0xffff)), vy = bf2f((u16)(vv >> 16));
    #pragma unroll
    for (int r = 0; r < 4; ++r) {
      float pe = prow[(w * 4 + r) * 512 + j];
      ox[r] += pe * vx; oy[r] += pe * vy;
    }
  }
  #pragma unroll
  for (int r = 0; r < 4; ++r) {
    size_t o = ((size_t)(b * PP + w * 4 + r)) * HH + h * 128 + dl;
    u32 pk = (u32)f2bf(ox[r]) | ((u32)f2bf(oy[r]) << 16);
    *(u32*)(out + o) = pk;
  }
}

// residual for prefix output: broadcast pq (fp32) over batch
__global__ __launch_bounds__(256) void fillres_kernel(const float* __restrict__ pq, float* __restrict__ res)
{
  int i = blockIdx.x * 256 + threadIdx.x;  // 512*1024 total
  int pr = (i >> 10) & 15; int chn = i & 1023;
  res[i] = pq[pr * HH + chn];
}

extern "C" void kernel_launch(void* const* d_in, const int* in_sizes, int n_in,
                              void* d_out, int out_size, void* d_ws, size_t ws_size,
                              hipStream_t stream)
{
  const int* vi = (const int*)d_in[0];
  const int* si = (const int*)d_in[1];
  const int* mk = (const int*)d_in[2];
  const float* ve   = (const float*)d_in[3];
  const float* se   = (const float*)d_in[4];
  const float* lpe  = (const float*)d_in[5];
  const float* cpe  = (const float*)d_in[6];
  const float* eiw  = (const float*)d_in[7];
  const float* eib  = (const float*)d_in[8];
  const float* eow  = (const float*)d_in[9];
  const float* eob  = (const float*)d_in[10];
  const float* f1w  = (const float*)d_in[11];
  const float* f1b  = (const float*)d_in[12];
  const float* f2w  = (const float*)d_in[13];
  const float* f2b  = (const float*)d_in[14];
  const float* n1w  = (const float*)d_in[15];
  const float* n1b  = (const float*)d_in[16];
  const float* n2w  = (const float*)d_in[17];
  const float* n2b  = (const float*)d_in[18];
  const float* tlw  = (const float*)d_in[19];
  const float* tlb  = (const float*)d_in[20];
  const float* thw  = (const float*)d_in[21];
  const float* thb  = (const float*)d_in[22];
  const float* pq   = (const float*)d_in[23];
  const float* paiw = (const float*)d_in[24];
  const float* paib = (const float*)d_in[25];
  const float* paow = (const float*)d_in[26];
  const float* paob = (const float*)d_in[27];
  const float* pnw  = (const float*)d_in[28];
  const float* pnb  = (const float*)d_in[29];

  const int NROW = BB * CC;  // 16384
  const size_t MB = 1048576;
  char* base = (char*)d_ws;
  float* x    = (float*)(base);              // [0,16M)   fp32 residual
  float* resb = (float*)(base + 16 * MB);    // [16M,32M) fp32 gemm out
  u16* xb     = (u16*)(base + 32 * MB);      // [32M,40M) bf16 residual copy
  char* pool  = base + 40 * MB;              // [40M,72M)
  u16* qkvb   = (u16*)pool;                  //   qkv 24MB (encoder)
  u16* atto   = (u16*)(pool + 24 * MB);      //   attn out 8MB (encoder)
  u16* h1     = (u16*)pool;                  //   ff hidden 32MB (encoder)
  u16* ch     = (u16*)pool;                  //   clause hidden 32MB (final)
  u16* vtb    = (u16*)(base + 72 * MB);      // [72M,80M) encoder V^T (encoder phase only)
  u16* vb     = (u16*)(base + 72 * MB);      // [72M,104M) prefix V (final phase)
  u16* wbf    = (u16*)(base + 104 * MB);     // [104M,~118.6M) bf16 weights
  u16* kb     = (u16*)base;                  // final phase: overlays x+resb (dead)
  u16* tln    = xb;                          // final phase: overlays xb (dead)
  u16* qh     = (u16*)(base + 120 * MB);
  u16* prefo  = qh + 32768;
  float* prefres = (float*)(base + 122 * MB);
  float* prefout = (float*)(base + 124 * MB);

  u16* eiw_b  = wbf + 0;
  u16* eow_b  = wbf + 786432;
  u16* f1w_b  = wbf + 1048576;
  u16* f2w_b  = wbf + 2097152;
  u16* thw_b  = wbf + 3145728;
  u16* paiw_b = wbf + 3407872;
  u16* paow_b = wbf + 6553600;
  u16* pqb    = wbf + 7602176;

  dim3 blk(256);
  cvt_kernel<<<7440, blk, 0, stream>>>(eiw, eow, f1w, f2w, thw, paiw, paow, pq, wbf);
  embed_kernel<<<NROW, blk, 0, stream>>>(vi, si, mk, ve, se, lpe, cpe, x, xb);
  for (int i = 0; i < NLAY; ++i) {
    gemm_kernel<<<dim3(768/128, NROW/64), blk, 0, stream>>>(
        xb, eiw_b + (size_t)i*768*DD, eib + i*768, nullptr, qkvb, NROW, 768, DD, 0);
    reshape_v_kernel<<<dim3(4, 8, BB), blk, 0, stream>>>(qkvb, vtb);
    attn_enc2_kernel<<<dim3(4, 8, BB), blk, 0, stream>>>(qkvb, vtb, atto);
    gemm_kernel<<<dim3(256/128, NROW/64), blk, 0, stream>>>(
        atto, eow_b + (size_t)i*DD*DD, eob + i*DD, x, resb, NROW, DD, DD, 2);
    ln_kernel<<<NROW, blk, 0, stream>>>(resb, n1w + i*DD, n1b + i*DD, x, xb, DD);
    gemm_kernel<<<dim3(1024/128, NROW/64), blk, 0, stream>>>(
        xb, f1w_b + (size_t)i*HH*DD, f1b + i*HH, nullptr, h1, NROW, HH, DD, 1);
    gemm_kernel<<<dim3(256/128, NROW/64), blk, 0, stream>>>(
        h1, f2w_b + (size_t)i*DD*HH, f2b + i*DD, x, resb, NROW, DD, HH, 2);
    ln_kernel<<<NROW, blk, 0, stream>>>(resb, n2w + i*DD, n2b + i*DD, x, xb, DD);
  }
  ln_kernel<<<NROW, blk, 0, stream>>>(x, tlw, tlb, nullptr, tln, DD);
  gemm_kernel<<<dim3(1024/128, NROW/64), blk, 0, stream>>>(
      tln, thw_b, thb, nullptr, ch, NROW, HH, DD, 0);
  gemm_kernel<<<dim3(1024/128, NROW/64), blk, 0, stream>>>(
      ch, paiw_b + (size_t)HH*HH, paib + HH, nullptr, kb, NROW, HH, HH, 0);
  gemm_kernel<<<dim3(1024/128, NROW/64), blk, 0, stream>>>(
      ch, paiw_b + (size_t)2*HH*HH, paib + 2*HH, nullptr, vb, NROW, HH, HH, 0);
  gemm_kernel<<<dim3(1024/128, 1), blk, 0, stream>>>(
      pqb, paiw_b, paib, nullptr, qh, PP, HH, HH, 0);
  attn_pref_kernel<<<dim3(8, BB), blk, 0, stream>>>(qh, kb, vb, prefo);
  fillres_kernel<<<2048, blk, 0, stream>>>(pq, prefres);
  gemm_kernel<<<dim3(1024/128, (BB*PP)/64), blk, 0, stream>>>(
      prefo, paow_b, paob, prefres, prefout, BB*PP, HH, HH, 2);
  ln_kernel<<<BB*PP, blk, 0, stream>>>(prefout, pnw, pnb, (float*)d_out, nullptr, HH);
}

// Round 4
// 1173.782 us; speedup vs baseline: 7.5803x; 1.0522x over previous
//
#include <hip/hip_runtime.h>
#include <hip/hip_bf16.h>

typedef unsigned short u16;
typedef unsigned int u32;
typedef __attribute__((ext_vector_type(8))) short short8;
typedef __attribute__((ext_vector_type(4))) float floatx4;

#define BB 32
#define CC 512
#define LL 16
#define DD 256
#define HH 1024
#define PP 16
#define NLAY 4

__device__ __forceinline__ float bf2f(u16 u) {
  u32 x = ((u32)u) << 16; float f; __builtin_memcpy(&f, &x, 4); return f;
}
__device__ __forceinline__ u16 f2bf(float f) {
  __hip_bfloat16 h = __float2bfloat16(f);
  u16 r; __builtin_memcpy(&r, &h, 2); return r;
}
__device__ __forceinline__ void gload_lds16(const u16* g, u16* l) {
  __builtin_amdgcn_global_load_lds(
      (const __attribute__((address_space(1))) void*)g,
      (__attribute__((address_space(3))) void*)l, 16, 0, 0);
}

// ---------------- fp32 -> bf16 weight conversion (one launch, 8 segments) ----------------
__global__ __launch_bounds__(256) void cvt_kernel(
    const float* __restrict__ s0, const float* __restrict__ s1,
    const float* __restrict__ s2, const float* __restrict__ s3,
    const float* __restrict__ s4, const float* __restrict__ s5,
    const float* __restrict__ s6, const float* __restrict__ s7,
    u16* __restrict__ dst)
{
  const float* srcs[8] = {s0, s1, s2, s3, s4, s5, s6, s7};
  const int pfx[8] = {786432, 1048576, 2097152, 3145728, 3407872, 6553600, 7602176, 7618560};
  int e = (blockIdx.x * 256 + threadIdx.x) * 4;
  int seg = 0;
  while (e >= pfx[seg]) seg++;
  int start = seg ? pfx[seg - 1] : 0;
  float4 f = *(const float4*)(srcs[seg] + (e - start));
  u16 o[4] = {f2bf(f.x), f2bf(f.y), f2bf(f.z), f2bf(f.w)};
  *(uint2*)(dst + e) = *(const uint2*)o;
}

// ---------------- embed + masked mean pool ----------------
__global__ __launch_bounds__(256) void embed_kernel(
    const int* __restrict__ vi, const int* __restrict__ si, const int* __restrict__ mk,
    const float* __restrict__ ve, const float* __restrict__ se,
    const float* __restrict__ lpe, const float* __restrict__ cpe,
    float* __restrict__ x, u16* __restrict__ xb)
{
  int bc = blockIdx.x;
  int c = bc & (CC - 1);
  int d = threadIdx.x;
  int base = bc * LL;
  float acc = 0.f; int cnt = 0;
  #pragma unroll
  for (int l = 0; l < LL; ++l) {
    if (mk[base + l]) {
      int v = vi[base + l], s = si[base + l];
      acc += ve[v * DD + d] + se[s * DD + d] + lpe[l * DD + d];
      cnt++;
    }
  }
  float r = acc / (float)cnt + cpe[c * DD + d];
  size_t o = (size_t)bc * DD + d;
  x[o] = r; xb[o] = f2bf(r);
}

// ---------------- MFMA GEMM v2: 128x128 tile, global_load_lds staging, XOR-swizzled LDS ----
// out[M,N] = A[M,K](bf16) @ W[N,K]^T(bf16) + bias(f32). M,N mult of 128, K mult of 64.
// flags: bit0 = exact gelu, bit1 = fp32 output (else bf16)
// LDS chunk layout: chunk c (16B) of a 128x8-chunk tile stored at c' = row*8 + (chunk^(row&7)).
// Staging picks global chunk (c&7)^(r&7) per lane so frag ds_read_b128 is conflict-free.
__global__ __launch_bounds__(256) void gemm128_kernel(
    const u16* __restrict__ A, const u16* __restrict__ W, const float* __restrict__ bias,
    const float* __restrict__ res, void* __restrict__ out,
    int M, int N, int K, int flags)
{
  __shared__ __align__(16) u16 As[128 * 64];
  __shared__ __align__(16) u16 Bs[128 * 64];
  int t = threadIdx.x;
  int lane = t & 63, w = t >> 6;
  int wm = w & 1, wn = w >> 1;
  int bn0 = blockIdx.x * 128, bm0 = blockIdx.y * 128;
  int mrow = lane & 15, quad = lane >> 4;

  const u16* gA[4]; const u16* gB[4];
  u16* lA[4]; u16* lB[4];
  #pragma unroll
  for (int it = 0; it < 4; ++it) {
    int c = w * 256 + it * 64 + lane;
    int r = c >> 3;
    int gc = (c & 7) ^ (r & 7);
    gA[it] = A + (size_t)(bm0 + r) * K + gc * 8;
    gB[it] = W + (size_t)(bn0 + r) * K + gc * 8;
    lA[it] = As + (w * 256 + it * 64) * 8;  // wave-uniform; HW adds lane*16B
    lB[it] = Bs + (w * 256 + it * 64) * 8;
  }
  floatx4 acc[4][4];
  #pragma unroll
  for (int i = 0; i < 4; ++i)
    #pragma unroll
    for (int j = 0; j < 4; ++j)
      acc[i][j] = (floatx4){0.f, 0.f, 0.f, 0.f};
  int sw0 = ((0 * 4 + quad) ^ (mrow & 7)) * 8;
  int sw1 = ((1 * 4 + quad) ^ (mrow & 7)) * 8;

  for (int k0 = 0; k0 < K; k0 += 64) {
    __syncthreads();
    #pragma unroll
    for (int it = 0; it < 4; ++it) { gload_lds16(gA[it], lA[it]); gA[it] += 64; }
    #pragma unroll
    for (int it = 0; it < 4; ++it) { gload_lds16(gB[it], lB[it]); gB[it] += 64; }
    __syncthreads();
    #pragma unroll
    for (int ks = 0; ks < 2; ++ks) {
      int sw = ks ? sw1 : sw0;
      short8 af[4], bfr[4];
      #pragma unroll
      for (int mi = 0; mi < 4; ++mi)
        af[mi] = *(const short8*)&As[(wm * 64 + mi * 16 + mrow) * 64 + sw];
      #pragma unroll
      for (int nj = 0; nj < 4; ++nj)
        bfr[nj] = *(const short8*)&Bs[(wn * 64 + nj * 16 + mrow) * 64 + sw];
      #pragma unroll
      for (int mi = 0; mi < 4; ++mi)
        #pragma unroll
        for (int nj = 0; nj < 4; ++nj)
          acc[mi][nj] = __builtin_amdgcn_mfma_f32_16x16x32_bf16(af[mi], bfr[nj], acc[mi][nj], 0, 0, 0);
    }
  }
  bool do_gelu = (flags & 1) != 0, of32 = (flags & 2) != 0;
  #pragma unroll
  for (int nj = 0; nj < 4; ++nj) {
    int gn = bn0 + wn * 64 + nj * 16 + mrow;
    float bv = bias[gn];
    #pragma unroll
    for (int mi = 0; mi < 4; ++mi) {
      #pragma unroll
      for (int r = 0; r < 4; ++r) {
        int gm = bm0 + wm * 64 + mi * 16 + quad * 4 + r;
        float v = acc[mi][nj][r] + bv;
        if (do_gelu) v = 0.5f * v * (1.f + erff(v * 0.70710678118654752f));
        if (res) v += res[(size_t)gm * N + gn];
        if (of32) ((float*)out)[(size_t)gm * N + gn] = v;
        else      ((u16*)out)[(size_t)gm * N + gn] = f2bf(v);
      }
    }
  }
}

// ---------------- small-M MFMA GEMM (M<=64 path, kept for pq projection) ----------------
__global__ __launch_bounds__(256) void gemm_kernel(
    const u16* __restrict__ A, const u16* __restrict__ W, const float* __restrict__ bias,
    const float* __restrict__ res, void* __restrict__ out,
    int M, int N, int K, int flags)
{
  __shared__ __align__(16) u16 As[64 * 64];
  __shared__ __align__(16) u16 Bs[128 * 64];
  int t = threadIdx.x;
  int lane = t & 63, wv = t >> 6;
  int wm = wv & 1, wn = wv >> 1;
  int bn0 = blockIdx.x * 128, bm0 = blockIdx.y * 64;
  int lr = t >> 2, lc = (t & 3) * 16;
  bool aok = (bm0 + lr) < M;
  const u16* Ap  = A + (size_t)(bm0 + lr) * K + lc;
  const u16* Wp0 = W + (size_t)(bn0 + lr) * K + lc;
  const u16* Wp1 = W + (size_t)(bn0 + 64 + lr) * K + lc;
  floatx4 acc[2][4];
  #pragma unroll
  for (int i = 0; i < 2; ++i)
    #pragma unroll
    for (int j = 0; j < 4; ++j)
      acc[i][j] = (floatx4){0.f, 0.f, 0.f, 0.f};
  int mr = lane & 15, qq = lane >> 4;
  for (int k0 = 0; k0 < K; k0 += 64) {
    uint4 a0 = {0,0,0,0}, a1 = {0,0,0,0};
    if (aok) { a0 = *(const uint4*)Ap; a1 = *(const uint4*)(Ap + 8); }
    uint4 w00 = *(const uint4*)Wp0, w01 = *(const uint4*)(Wp0 + 8);
    uint4 w10 = *(const uint4*)Wp1, w11 = *(const uint4*)(Wp1 + 8);
    Ap += 64; Wp0 += 64; Wp1 += 64;
    __syncthreads();
    *(uint4*)&As[lr * 64 + lc] = a0;         *(uint4*)&As[lr * 64 + lc + 8] = a1;
    *(uint4*)&Bs[lr * 64 + lc] = w00;        *(uint4*)&Bs[lr * 64 + lc + 8] = w01;
    *(uint4*)&Bs[(64 + lr) * 64 + lc] = w10; *(uint4*)&Bs[(64 + lr) * 64 + lc + 8] = w11;
    __syncthreads();
    #pragma unroll
    for (int ks = 0; ks < 2; ++ks) {
      short8 af[2], bfr[4];
      #pragma unroll
      for (int i = 0; i < 2; ++i)
        af[i] = *(const short8*)&As[(wm * 32 + i * 16 + mr) * 64 + ks * 32 + qq * 8];
      #pragma unroll
      for (int j = 0; j < 4; ++j)
        bfr[j] = *(const short8*)&Bs[(wn * 64 + j * 16 + mr) * 64 + ks * 32 + qq * 8];
      #pragma unroll
      for (int i = 0; i < 2; ++i)
        #pragma unroll
        for (int j = 0; j < 4; ++j)
          acc[i][j] = __builtin_amdgcn_mfma_f32_16x16x32_bf16(af[i], bfr[j], acc[i][j], 0, 0, 0);
    }
  }
  bool do_gelu = (flags & 1) != 0, of32 = (flags & 2) != 0;
  #pragma unroll
  for (int j = 0; j < 4; ++j) {
    int gn = bn0 + wn * 64 + j * 16 + mr;
    float bv = bias[gn];
    #pragma unroll
    for (int i = 0; i < 2; ++i) {
      #pragma unroll
      for (int r = 0; r < 4; ++r) {
        int gm = bm0 + wm * 32 + i * 16 + qq * 4 + r;
        if (gm < M) {
          float v = acc[i][j][r] + bv;
          if (do_gelu) v = 0.5f * v * (1.f + erff(v * 0.70710678118654752f));
          if (res) v += res[(size_t)gm * N + gn];
          if (of32) ((float*)out)[(size_t)gm * N + gn] = v;
          else      ((u16*)out)[(size_t)gm * N + gn] = f2bf(v);
        }
      }
    }
  }
}

// ---------------- LayerNorm: one wave per row, 4 rows/block ----------------
template<int D>
__global__ __launch_bounds__(256) void lnw_kernel(
    const float* __restrict__ in, const float* __restrict__ w, const float* __restrict__ b,
    float* __restrict__ outf, u16* __restrict__ outb)
{
  constexpr int NV = D / 64;
  int lane = threadIdx.x & 63, wv = threadIdx.x >> 6;
  int row = blockIdx.x * 4 + wv;
  const float* xr = in + (size_t)row * D;
  float v[NV];
  float s = 0.f, s2 = 0.f;
  #pragma unroll
  for (int i = 0; i < NV; ++i) {
    v[i] = xr[lane + i * 64];
    s += v[i]; s2 += v[i] * v[i];
  }
  #pragma unroll
  for (int off = 32; off > 0; off >>= 1) { s += __shfl_xor(s, off); s2 += __shfl_xor(s2, off); }
  float mean = s / (float)D;
  float var = s2 / (float)D - mean * mean;
  float inv = rsqrtf(var + 1e-5f);
  #pragma unroll
  for (int i = 0; i < NV; ++i) {
    int col = lane + i * 64;
    float y = (v[i] - mean) * inv * w[col] + b[col];
    size_t o = (size_t)row * D + col;
    if (outf) outf[o] = y;
    if (outb) outb[o] = f2bf(y);
  }
}

// ---------------- V reshape: qkv[row][512+h*32+d] -> vt[bh][d][jt*128 + perm(jl)] ----------------
// perm(jl) = (jl&15)*8 + (jl>>4)
__global__ __launch_bounds__(256) void reshape_v_kernel(
    const u16* __restrict__ qkv, u16* __restrict__ vt)
{
  __shared__ __align__(16) u16 T[32 * 136];
  int jt = blockIdx.x, h = blockIdx.y, b = blockIdx.z;
  int t = threadIdx.x;
  int d0 = (t & 3) * 8;
  #pragma unroll
  for (int rep = 0; rep < 2; ++rep) {
    int jl = (t >> 2) + rep * 64;
    uint4 vv = *(const uint4*)(qkv + (size_t)(b * CC + jt * 128 + jl) * 768 + 512 + h * 32 + d0);
    u16 tmp[8]; *(uint4*)tmp = vv;
    int jp = (jl & 15) * 8 + (jl >> 4);
    #pragma unroll
    for (int i = 0; i < 8; ++i) T[(d0 + i) * 136 + jp] = tmp[i];
  }
  __syncthreads();
  int bh = b * 8 + h;
  int d = t >> 3;
  #pragma unroll
  for (int rep = 0; rep < 2; ++rep) {
    int jp = (t & 7) * 8 + rep * 64;
    uint4 vv = *(const uint4*)&T[d * 136 + jp];
    *(uint4*)(vt + (size_t)bh * 16384 + d * 512 + jt * 128 + jp) = vv;
  }
}

// ---------------- encoder self-attention: MFMA flash-style ----------------
__global__ __launch_bounds__(256) void attn_enc2_kernel(
    const u16* __restrict__ qkv, const u16* __restrict__ vt, u16* __restrict__ out)
{
  __shared__ __align__(16) u16 Ks[128 * 40];
  __shared__ __align__(16) u16 Vt[32 * 136];
  __shared__ __align__(16) u16 Pl[4 * 32 * 136];
  int qt = blockIdx.x, h = blockIdx.y, b = blockIdx.z;
  int t = threadIdx.x, lane = t & 63, w = t >> 6;
  int mrow = lane & 15, quad = lane >> 4;
  int bh = b * 8 + h;
  int q0 = qt * 128 + w * 32;
  short8 qf[2];
  #pragma unroll
  for (int mi = 0; mi < 2; ++mi)
    qf[mi] = *(const short8*)(qkv + (size_t)(b * CC + q0 + mi * 16 + mrow) * 768 + h * 32 + quad * 8);
  floatx4 o[2][2];
  #pragma unroll
  for (int mi = 0; mi < 2; ++mi)
    #pragma unroll
    for (int di = 0; di < 2; ++di) o[mi][di] = (floatx4){0.f, 0.f, 0.f, 0.f};
  float lst[2][4] = {{0.f,0.f,0.f,0.f},{0.f,0.f,0.f,0.f}};
  const float sc = 0.17677669529663687f * 1.4426950408889634f;
  const floatx4 zf = (floatx4){0.f, 0.f, 0.f, 0.f};
  for (int jt = 0; jt < 4; ++jt) {
    if (jt) __syncthreads();
    {
      int j = t >> 1, half = t & 1;
      uint4 kk = *(const uint4*)(qkv + (size_t)(b * CC + jt * 128 + j) * 768 + 256 + h * 32 + half * 8);
      *(uint4*)&Ks[j * 40 + half * 8] = kk;
    }
    {
      int d = t >> 3;
      #pragma unroll
      for (int rep = 0; rep < 2; ++rep) {
        int jp = (t & 7) * 8 + rep * 64;
        uint4 vv = *(const uint4*)(vt + (size_t)bh * 16384 + d * 512 + jt * 128 + jp);
        *(uint4*)&Vt[d * 136 + jp] = vv;
      }
    }
    __syncthreads();
    floatx4 s[2][8];
    #pragma unroll
    for (int nj = 0; nj < 8; ++nj) {
      short8 bf = *(const short8*)&Ks[(nj * 16 + mrow) * 40 + quad * 8];
      s[0][nj] = __builtin_amdgcn_mfma_f32_16x16x32_bf16(qf[0], bf, zf, 0, 0, 0);
      s[1][nj] = __builtin_amdgcn_mfma_f32_16x16x32_bf16(qf[1], bf, zf, 0, 0, 0);
    }
    #pragma unroll
    for (int mi = 0; mi < 2; ++mi) {
      #pragma unroll
      for (int r = 0; r < 4; ++r) {
        float ps = 0.f; u16 hv[8];
        #pragma unroll
        for (int nj = 0; nj < 8; ++nj) {
          float p = exp2f(s[mi][nj][r] * sc);
          ps += p; hv[nj] = f2bf(p);
        }
        lst[mi][r] += ps;
        *(uint4*)&Pl[(w * 32 + mi * 16 + quad * 4 + r) * 136 + mrow * 8] = *(uint4*)hv;
      }
    }
    #pragma unroll
    for (int ks = 0; ks < 4; ++ks) {
      short8 a0 = *(const short8*)&Pl[(w * 32 + mrow) * 136 + ks * 32 + quad * 8];
      short8 a1 = *(const short8*)&Pl[(w * 32 + 16 + mrow) * 136 + ks * 32 + quad * 8];
      short8 b0 = *(const short8*)&Vt[mrow * 136 + ks * 32 + quad * 8];
      short8 b1 = *(const short8*)&Vt[(16 + mrow) * 136 + ks * 32 + quad * 8];
      o[0][0] = __builtin_amdgcn_mfma_f32_16x16x32_bf16(a0, b0, o[0][0], 0, 0, 0);
      o[0][1] = __builtin_amdgcn_mfma_f32_16x16x32_bf16(a0, b1, o[0][1], 0, 0, 0);
      o[1][0] = __builtin_amdgcn_mfma_f32_16x16x32_bf16(a1, b0, o[1][0], 0, 0, 0);
      o[1][1] = __builtin_amdgcn_mfma_f32_16x16x32_bf16(a1, b1, o[1][1], 0, 0, 0);
    }
  }
  #pragma unroll
  for (int mi = 0; mi < 2; ++mi) {
    #pragma unroll
    for (int r = 0; r < 4; ++r) {
      float l = lst[mi][r];
      l += __shfl_xor(l, 1); l += __shfl_xor(l, 2);
      l += __shfl_xor(l, 4); l += __shfl_xor(l, 8);
      float inv = 1.f / l;
      int row = b * CC + q0 + mi * 16 + quad * 4 + r;
      #pragma unroll
      for (int di = 0; di < 2; ++di)
        out[(size_t)row * DD + h * 32 + di * 16 + mrow] = f2bf(o[mi][di][r] * inv);
    }
  }
}

// ---------------- prefix cross-attention: qh[16,H] vs fused kv[B*C,2H], dh=128 ----------------
__global__ __launch_bounds__(256) void attn_pref_kernel(
    const u16* __restrict__ qh, const u16* __restrict__ kv, u16* __restrict__ out)
{
  __shared__ float qs[16 * 128];
  __shared__ float prow[16 * 512];
  int h = blockIdx.x, b = blockIdx.y;
  int t = threadIdx.x, lane = t & 63, w = t >> 6;
  for (int idx = t; idx < 2048; idx += 256) {
    int r = idx >> 7, d = idx & 127;
    qs[idx] = bf2f(qh[r * HH + h * 128 + d]);
  }
  __syncthreads();
  float a[8][4];
  #pragma unroll
  for (int tt = 0; tt < 8; ++tt)
    #pragma unroll
    for (int r = 0; r < 4; ++r) a[tt][r] = 0.f;
  for (int dd = 0; dd < 128; dd += 8) {
    float qr[4][8];
    #pragma unroll
    for (int r = 0; r < 4; ++r)
      #pragma unroll
      for (int i = 0; i < 8; ++i) qr[r][i] = qs[(w * 4 + r) * 128 + dd + i];
    #pragma unroll
    for (int tt = 0; tt < 8; ++tt) {
      int j = tt * 64 + lane;
      const u16* kp = kv + ((size_t)(b * CC + j)) * 2048 + h * 128 + dd;
      u16 tk[8]; *(uint4*)tk = *(const uint4*)kp;
      #pragma unroll
      for (int i = 0; i < 8; ++i) {
        float kf = bf2f(tk[i]);
        #pragma unroll
        for (int r = 0; r < 4; ++r) a[tt][r] += qr[r][i] * kf;
      }
    }
  }
  for (int r = 0; r < 4; ++r) {
    float m = -1e30f;
    #pragma unroll
    for (int tt = 0; tt < 8; ++tt) m = fmaxf(m, a[tt][r] * 0.08838834764831845f);
    #pragma unroll
    for (int off = 32; off > 0; off >>= 1) m = fmaxf(m, __shfl_xor(m, off));
    float l = 0.f; float pe[8];
    #pragma unroll
    for (int tt = 0; tt < 8; ++tt) { pe[tt] = __expf(a[tt][r] * 0.08838834764831845f - m); l += pe[tt]; }
    #pragma unroll
    for (int off = 32; off > 0; off >>= 1) l += __shfl_xor(l, off);
    float inv = 1.f / l;
    #pragma unroll
    for (int tt = 0; tt < 8; ++tt) prow[(w * 4 + r) * 512 + tt * 64 + lane] = pe[tt] * inv;
  }
  int dl = lane * 2;
  float ox[4] = {0,0,0,0}, oy[4] = {0,0,0,0};
  for (int j = 0; j < 512; ++j) {
    const u16* vp = kv + ((size_t)(b * CC + j)) * 2048 + 1024 + h * 128 + dl;
    u32 vv = *(const u32*)vp;
    float vx = bf2f((u16)(vv & 0xffff)), vy = bf2f((u16)(vv >> 16));
    #pragma unroll
    for (int r = 0; r < 4; ++r) {
      float pe = prow[(w * 4 + r) * 512 + j];
      ox[r] += pe * vx; oy[r] += pe * vy;
    }
  }
  #pragma unroll
  for (int r = 0; r < 4; ++r) {
    size_t o = ((size_t)(b * PP + w * 4 + r)) * HH + h * 128 + dl;
    u32 pk = (u32)f2bf(ox[r]) | ((u32)f2bf(oy[r]) << 16);
    *(u32*)(out + o) = pk;
  }
}

// residual for prefix output: broadcast pq (fp32) over batch
__global__ __launch_bounds__(256) void fillres_kernel(const float* __restrict__ pq, float* __restrict__ res)
{
  int i = blockIdx.x * 256 + threadIdx.x;
  int pr = (i >> 10) & 15; int chn = i & 1023;
  res[i] = pq[pr * HH + chn];
}

extern "C" void kernel_launch(void* const* d_in, const int* in_sizes, int n_in,
                              void* d_out, int out_size, void* d_ws, size_t ws_size,
                              hipStream_t stream)
{
  const int* vi = (const int*)d_in[0];
  const int* si = (const int*)d_in[1];
  const int* mk = (const int*)d_in[2];
  const float* ve   = (const float*)d_in[3];
  const float* se   = (const float*)d_in[4];
  const float* lpe  = (const float*)d_in[5];
  const float* cpe  = (const float*)d_in[6];
  const float* eiw  = (const float*)d_in[7];
  const float* eib  = (const float*)d_in[8];
  const float* eow  = (const float*)d_in[9];
  const float* eob  = (const float*)d_in[10];
  const float* f1w  = (const float*)d_in[11];
  const float* f1b  = (const float*)d_in[12];
  const float* f2w  = (const float*)d_in[13];
  const float* f2b  = (const float*)d_in[14];
  const float* n1w  = (const float*)d_in[15];
  const float* n1b  = (const float*)d_in[16];
  const float* n2w  = (const float*)d_in[17];
  const float* n2b  = (const float*)d_in[18];
  const float* tlw  = (const float*)d_in[19];
  const float* tlb  = (const float*)d_in[20];
  const float* thw  = (const float*)d_in[21];
  const float* thb  = (const float*)d_in[22];
  const float* pq   = (const float*)d_in[23];
  const float* paiw = (const float*)d_in[24];
  const float* paib = (const float*)d_in[25];
  const float* paow = (const float*)d_in[26];
  const float* paob = (const float*)d_in[27];
  const float* pnw  = (const float*)d_in[28];
  const float* pnb  = (const float*)d_in[29];

  const int NROW = BB * CC;  // 16384
  const size_t MB = 1048576;
  char* base = (char*)d_ws;
  // encoder phase:
  float* x    = (float*)(base);              // [0,16M)
  float* resb = (float*)(base + 16 * MB);    // [16M,32M)
  u16* xb     = (u16*)(base + 32 * MB);      // [32M,40M)
  u16* qkvb   = (u16*)(base + 40 * MB);      // [40M,64M)
  u16* atto   = (u16*)(base + 64 * MB);      // [64M,72M)
  u16* h1     = (u16*)(base + 40 * MB);      // [40M,72M) (qkvb/atto dead)
  u16* vtb    = (u16*)(base + 72 * MB);      // [72M,80M)
  u16* wbf    = (u16*)(base + 104 * MB);     // [104M,~118.6M)
  // final phase:
  u16* ch     = (u16*)base;                  // [0,32M)   (x/resb dead)
  u16* tln    = xb;                          // [32M,40M)
  u16* kvb    = (u16*)(base + 40 * MB);      // [40M,104M) fused K|V, row stride 2048
  u16* qh     = (u16*)(base + 120 * MB);
  u16* prefo  = qh + 32768;
  float* prefres = (float*)(base + 122 * MB);
  float* prefout = (float*)(base + 124 * MB);

  u16* eiw_b  = wbf + 0;
  u16* eow_b  = wbf + 786432;
  u16* f1w_b  = wbf + 1048576;
  u16* f2w_b  = wbf + 2097152;
  u16* thw_b  = wbf + 3145728;
  u16* paiw_b = wbf + 3407872;
  u16* paow_b = wbf + 6553600;
  u16* pqb    = wbf + 7602176;

  dim3 blk(256);
  cvt_kernel<<<7440, blk, 0, stream>>>(eiw, eow, f1w, f2w, thw, paiw, paow, pq, wbf);
  embed_kernel<<<NROW, blk, 0, stream>>>(vi, si, mk, ve, se, lpe, cpe, x, xb);
  for (int i = 0; i < NLAY; ++i) {
    gemm128_kernel<<<dim3(768/128, NROW/128), blk, 0, stream>>>(
        xb, eiw_b + (size_t)i*768*DD, eib + i*768, nullptr, qkvb, NROW, 768, DD, 0);
    reshape_v_kernel<<<dim3(4, 8, BB), blk, 0, stream>>>(qkvb, vtb);
    attn_enc2_kernel<<<dim3(4, 8, BB), blk, 0, stream>>>(qkvb, vtb, atto);
    gemm128_kernel<<<dim3(256/128, NROW/128), blk, 0, stream>>>(
        atto, eow_b + (size_t)i*DD*DD, eob + i*DD, x, resb, NROW, DD, DD, 2);
    lnw_kernel<256><<<NROW/4, blk, 0, stream>>>(resb, n1w + i*DD, n1b + i*DD, x, xb);
    gemm128_kernel<<<dim3(1024/128, NROW/128), blk, 0, stream>>>(
        xb, f1w_b + (size_t)i*HH*DD, f1b + i*HH, nullptr, h1, NROW, HH, DD, 1);
    gemm128_kernel<<<dim3(256/128, NROW/128), blk, 0, stream>>>(
        h1, f2w_b + (size_t)i*DD*HH, f2b + i*DD, x, resb, NROW, DD, HH, 2);
    lnw_kernel<256><<<NROW/4, blk, 0, stream>>>(resb, n2w + i*DD, n2b + i*DD, x, xb);
  }
  lnw_kernel<256><<<NROW/4, blk, 0, stream>>>(x, tlw, tlb, nullptr, tln);
  gemm128_kernel<<<dim3(1024/128, NROW/128), blk, 0, stream>>>(
      tln, thw_b, thb, nullptr, ch, NROW, HH, DD, 0);
  gemm128_kernel<<<dim3(2048/128, NROW/128), blk, 0, stream>>>(
      ch, paiw_b + (size_t)HH*HH, paib + HH, nullptr, kvb, NROW, 2048, HH, 0);
  gemm_kernel<<<dim3(1024/128, 1), blk, 0, stream>>>(
      pqb, paiw_b, paib, nullptr, qh, PP, HH, HH, 0);
  attn_pref_kernel<<<dim3(8, BB), blk, 0, stream>>>(qh, kvb, prefo);
  fillres_kernel<<<2048, blk, 0, stream>>>(pq, prefres);
  gemm128_kernel<<<dim3(1024/128, (BB*PP)/128), blk, 0, stream>>>(
      prefo, paow_b, paob, prefres, prefout, BB*PP, HH, HH, 2);
  lnw_kernel<1024><<<(BB*PP)/4, blk, 0, stream>>>(prefout, pnw, pnb, (float*)d_out, nullptr);
}

// Round 5
// 940.206 us; speedup vs baseline: 9.4634x; 1.2484x over previous
//
#include <hip/hip_runtime.h>
#include <hip/hip_bf16.h>

typedef unsigned short u16;
typedef unsigned int u32;
typedef __attribute__((ext_vector_type(8))) short short8;
typedef __attribute__((ext_vector_type(4))) float floatx4;

#define BB 32
#define CC 512
#define LL 16
#define DD 256
#define HH 1024
#define PP 16
#define NLAY 4

__device__ __forceinline__ float bf2f(u16 u) {
  u32 x = ((u32)u) << 16; float f; __builtin_memcpy(&f, &x, 4); return f;
}
__device__ __forceinline__ u16 f2bf(float f) {
  __hip_bfloat16 h = __float2bfloat16(f);
  u16 r; __builtin_memcpy(&r, &h, 2); return r;
}
__device__ __forceinline__ void gload_lds16(const u16* g, u16* l) {
  __builtin_amdgcn_global_load_lds(
      (const __attribute__((address_space(1))) void*)g,
      (__attribute__((address_space(3))) void*)l, 16, 0, 0);
}

// ---------------- fp32 -> bf16 weight conversion ----------------
__global__ __launch_bounds__(256) void cvt_kernel(
    const float* __restrict__ s0, const float* __restrict__ s1,
    const float* __restrict__ s2, const float* __restrict__ s3,
    const float* __restrict__ s4, const float* __restrict__ s5,
    const float* __restrict__ s6, const float* __restrict__ s7,
    u16* __restrict__ dst)
{
  const float* srcs[8] = {s0, s1, s2, s3, s4, s5, s6, s7};
  const int pfx[8] = {786432, 1048576, 2097152, 3145728, 3407872, 6553600, 7602176, 7618560};
  int e = (blockIdx.x * 256 + threadIdx.x) * 4;
  int seg = 0;
  while (e >= pfx[seg]) seg++;
  int start = seg ? pfx[seg - 1] : 0;
  float4 f = *(const float4*)(srcs[seg] + (e - start));
  u16 o[4] = {f2bf(f.x), f2bf(f.y), f2bf(f.z), f2bf(f.w)};
  *(uint2*)(dst + e) = *(const uint2*)o;
}

// ---------------- embed + masked mean pool ----------------
__global__ __launch_bounds__(256) void embed_kernel(
    const int* __restrict__ vi, const int* __restrict__ si, const int* __restrict__ mk,
    const float* __restrict__ ve, const float* __restrict__ se,
    const float* __restrict__ lpe, const float* __restrict__ cpe,
    float* __restrict__ x, u16* __restrict__ xb)
{
  int bc = blockIdx.x;
  int c = bc & (CC - 1);
  int d = threadIdx.x;
  int base = bc * LL;
  float acc = 0.f; int cnt = 0;
  #pragma unroll
  for (int l = 0; l < LL; ++l) {
    if (mk[base + l]) {
      int v = vi[base + l], s = si[base + l];
      acc += ve[v * DD + d] + se[s * DD + d] + lpe[l * DD + d];
      cnt++;
    }
  }
  float r = acc / (float)cnt + cpe[c * DD + d];
  size_t o = (size_t)bc * DD + d;
  x[o] = r; xb[o] = f2bf(r);
}

// ---------------- wide-N GEMM: 32 rows x NC cols per block ----------------
// out[M,N] = A[M,K] @ W[N,K]^T + bias. Waves: 2m x 2n (16 rows x NC/2 cols each).
// LN=true (requires NC==256, gridDim.x==1): v += res; y = LN(v)*gam+bet -> outx(f32)+outxb(bf16).
// else: optional GELU, bf16 out at row stride N.
template<int NC, bool GELU, bool LN>
__global__ __launch_bounds__(256) void gwide_kernel(
    const u16* __restrict__ A, const u16* __restrict__ W, const float* __restrict__ bias,
    const float* __restrict__ res, const float* __restrict__ gam, const float* __restrict__ bet,
    u16* __restrict__ outb, float* __restrict__ outx, u16* __restrict__ outxb,
    int N, int K)
{
  constexpr int NT = NC / 32;   // n-tiles per wave
  constexpr int NW = NC / 32;   // W staging instrs per thread
  __shared__ __align__(16) u16 As[32 * 64];
  __shared__ __align__(16) u16 Ws[NC * 64];
  __shared__ float sred[32][2][2];
  int t = threadIdx.x, lane = t & 63, w = t >> 6;
  int wm = w & 1, wn = w >> 1;
  int mrow = lane & 15, quad = lane >> 4;
  int bn0 = blockIdx.x * NC, bm0 = blockIdx.y * 32;

  int rA = t >> 3, gcA = (t & 7) ^ (rA & 7);
  const u16* gAp = A + (size_t)(bm0 + rA) * K + gcA * 8;
  u16* lAp = As + (w * 64) * 8;
  const u16* gWp[NW]; u16* lWp[NW];
  #pragma unroll
  for (int i = 0; i < NW; ++i) {
    int c = i * 256 + t;
    int r = c >> 3, gc = (c & 7) ^ (r & 7);
    gWp[i] = W + (size_t)(bn0 + r) * K + gc * 8;
    lWp[i] = Ws + (i * 256 + w * 64) * 8;
  }
  floatx4 acc[NT];
  #pragma unroll
  for (int nt = 0; nt < NT; ++nt) acc[nt] = (floatx4){0.f, 0.f, 0.f, 0.f};

  for (int k0 = 0; k0 < K; k0 += 64) {
    __syncthreads();
    gload_lds16(gAp, lAp); gAp += 64;
    #pragma unroll
    for (int i = 0; i < NW; ++i) { gload_lds16(gWp[i], lWp[i]); gWp[i] += 64; }
    __syncthreads();
    #pragma unroll
    for (int ks = 0; ks < 2; ++ks) {
      int sw = ((ks * 4 + quad) ^ (mrow & 7)) * 8;
      short8 af = *(const short8*)&As[(wm * 16 + mrow) * 64 + sw];
      #pragma unroll
      for (int nt = 0; nt < NT; ++nt) {
        int rw = wn * (NC / 2) + nt * 16 + mrow;
        short8 bf = *(const short8*)&Ws[rw * 64 + sw];
        acc[nt] = __builtin_amdgcn_mfma_f32_16x16x32_bf16(af, bf, acc[nt], 0, 0, 0);
      }
    }
  }

  if constexpr (LN) {
    // v = acc + bias + res; stats per row; y = (v-mean)*inv*gam+bet -> outx/outxb (stride NC)
    float val[NT][4];
    float bv[NT];
    #pragma unroll
    for (int nt = 0; nt < NT; ++nt) bv[nt] = bias[wn * (NC / 2) + nt * 16 + mrow];
    #pragma unroll
    for (int r = 0; r < 4; ++r) {
      int gm = bm0 + wm * 16 + quad * 4 + r;
      float sr = 0.f, s2r = 0.f;
      #pragma unroll
      for (int nt = 0; nt < NT; ++nt) {
        int gn = wn * (NC / 2) + nt * 16 + mrow;
        float v = acc[nt][r] + bv[nt] + res[(size_t)gm * NC + gn];
        val[nt][r] = v; sr += v; s2r += v * v;
      }
      sr += __shfl_xor(sr, 1); s2r += __shfl_xor(s2r, 1);
      sr += __shfl_xor(sr, 2); s2r += __shfl_xor(s2r, 2);
      sr += __shfl_xor(sr, 4); s2r += __shfl_xor(s2r, 4);
      sr += __shfl_xor(sr, 8); s2r += __shfl_xor(s2r, 8);
      if (mrow == 0) { sred[wm * 16 + quad * 4 + r][wn][0] = sr; sred[wm * 16 + quad * 4 + r][wn][1] = s2r; }
    }
    __syncthreads();
    #pragma unroll
    for (int r = 0; r < 4; ++r) {
      int lrow = wm * 16 + quad * 4 + r;
      int gm = bm0 + lrow;
      float S = sred[lrow][0][0] + sred[lrow][1][0];
      float S2 = sred[lrow][0][1] + sred[lrow][1][1];
      float mean = S / (float)NC;
      float var = S2 / (float)NC - mean * mean;
      float inv = rsqrtf(var + 1e-5f);
      #pragma unroll
      for (int nt = 0; nt < NT; ++nt) {
        int gn = wn * (NC / 2) + nt * 16 + mrow;
        float y = (val[nt][r] - mean) * inv * gam[gn] + bet[gn];
        size_t o = (size_t)gm * NC + gn;
        outx[o] = y; outxb[o] = f2bf(y);
      }
    }
  } else {
    #pragma unroll
    for (int nt = 0; nt < NT; ++nt) {
      int gn = bn0 + wn * (NC / 2) + nt * 16 + mrow;
      float bv = bias[gn];
      #pragma unroll
      for (int r = 0; r < 4; ++r) {
        int gm = bm0 + wm * 16 + quad * 4 + r;
        float v = acc[nt][r] + bv;
        if (GELU) v = 0.5f * v * (1.f + erff(v * 0.70710678118654752f));
        outb[(size_t)gm * N + gn] = f2bf(v);
      }
    }
  }
}

// ---------------- MFMA GEMM 128x128 (kept for KV / out-proj) ----------------
__global__ __launch_bounds__(256) void gemm128_kernel(
    const u16* __restrict__ A, const u16* __restrict__ W, const float* __restrict__ bias,
    const float* __restrict__ res, void* __restrict__ out,
    int M, int N, int K, int flags)
{
  __shared__ __align__(16) u16 As[128 * 64];
  __shared__ __align__(16) u16 Bs[128 * 64];
  int t = threadIdx.x;
  int lane = t & 63, w = t >> 6;
  int wm = w & 1, wn = w >> 1;
  int bn0 = blockIdx.x * 128, bm0 = blockIdx.y * 128;
  int mrow = lane & 15, quad = lane >> 4;

  const u16* gA[4]; const u16* gB[4];
  u16* lA[4]; u16* lB[4];
  #pragma unroll
  for (int it = 0; it < 4; ++it) {
    int c = w * 256 + it * 64 + lane;
    int r = c >> 3;
    int gc = (c & 7) ^ (r & 7);
    gA[it] = A + (size_t)(bm0 + r) * K + gc * 8;
    gB[it] = W + (size_t)(bn0 + r) * K + gc * 8;
    lA[it] = As + (w * 256 + it * 64) * 8;
    lB[it] = Bs + (w * 256 + it * 64) * 8;
  }
  floatx4 acc[4][4];
  #pragma unroll
  for (int i = 0; i < 4; ++i)
    #pragma unroll
    for (int j = 0; j < 4; ++j)
      acc[i][j] = (floatx4){0.f, 0.f, 0.f, 0.f};
  int sw0 = ((0 * 4 + quad) ^ (mrow & 7)) * 8;
  int sw1 = ((1 * 4 + quad) ^ (mrow & 7)) * 8;

  for (int k0 = 0; k0 < K; k0 += 64) {
    __syncthreads();
    #pragma unroll
    for (int it = 0; it < 4; ++it) { gload_lds16(gA[it], lA[it]); gA[it] += 64; }
    #pragma unroll
    for (int it = 0; it < 4; ++it) { gload_lds16(gB[it], lB[it]); gB[it] += 64; }
    __syncthreads();
    #pragma unroll
    for (int ks = 0; ks < 2; ++ks) {
      int sw = ks ? sw1 : sw0;
      short8 af[4], bfr[4];
      #pragma unroll
      for (int mi = 0; mi < 4; ++mi)
        af[mi] = *(const short8*)&As[(wm * 64 + mi * 16 + mrow) * 64 + sw];
      #pragma unroll
      for (int nj = 0; nj < 4; ++nj)
        bfr[nj] = *(const short8*)&Bs[(wn * 64 + nj * 16 + mrow) * 64 + sw];
      #pragma unroll
      for (int mi = 0; mi < 4; ++mi)
        #pragma unroll
        for (int nj = 0; nj < 4; ++nj)
          acc[mi][nj] = __builtin_amdgcn_mfma_f32_16x16x32_bf16(af[mi], bfr[nj], acc[mi][nj], 0, 0, 0);
    }
  }
  bool do_gelu = (flags & 1) != 0, of32 = (flags & 2) != 0;
  #pragma unroll
  for (int nj = 0; nj < 4; ++nj) {
    int gn = bn0 + wn * 64 + nj * 16 + mrow;
    float bv = bias[gn];
    #pragma unroll
    for (int mi = 0; mi < 4; ++mi) {
      #pragma unroll
      for (int r = 0; r < 4; ++r) {
        int gm = bm0 + wm * 64 + mi * 16 + quad * 4 + r;
        float v = acc[mi][nj][r] + bv;
        if (do_gelu) v = 0.5f * v * (1.f + erff(v * 0.70710678118654752f));
        if (res) v += res[(size_t)gm * N + gn];
        if (of32) ((float*)out)[(size_t)gm * N + gn] = v;
        else      ((u16*)out)[(size_t)gm * N + gn] = f2bf(v);
      }
    }
  }
}

// ---------------- small-M MFMA GEMM (pq projection) ----------------
__global__ __launch_bounds__(256) void gemm_kernel(
    const u16* __restrict__ A, const u16* __restrict__ W, const float* __restrict__ bias,
    const float* __restrict__ res, void* __restrict__ out,
    int M, int N, int K, int flags)
{
  __shared__ __align__(16) u16 As[64 * 64];
  __shared__ __align__(16) u16 Bs[128 * 64];
  int t = threadIdx.x;
  int lane = t & 63, wv = t >> 6;
  int wm = wv & 1, wn = wv >> 1;
  int bn0 = blockIdx.x * 128, bm0 = blockIdx.y * 64;
  int lr = t >> 2, lc = (t & 3) * 16;
  bool aok = (bm0 + lr) < M;
  const u16* Ap  = A + (size_t)(bm0 + lr) * K + lc;
  const u16* Wp0 = W + (size_t)(bn0 + lr) * K + lc;
  const u16* Wp1 = W + (size_t)(bn0 + 64 + lr) * K + lc;
  floatx4 acc[2][4];
  #pragma unroll
  for (int i = 0; i < 2; ++i)
    #pragma unroll
    for (int j = 0; j < 4; ++j)
      acc[i][j] = (floatx4){0.f, 0.f, 0.f, 0.f};
  int mr = lane & 15, qq = lane >> 4;
  for (int k0 = 0; k0 < K; k0 += 64) {
    uint4 a0 = {0,0,0,0}, a1 = {0,0,0,0};
    if (aok) { a0 = *(const uint4*)Ap; a1 = *(const uint4*)(Ap + 8); }
    uint4 w00 = *(const uint4*)Wp0, w01 = *(const uint4*)(Wp0 + 8);
    uint4 w10 = *(const uint4*)Wp1, w11 = *(const uint4*)(Wp1 + 8);
    Ap += 64; Wp0 += 64; Wp1 += 64;
    __syncthreads();
    *(uint4*)&As[lr * 64 + lc] = a0;         *(uint4*)&As[lr * 64 + lc + 8] = a1;
    *(uint4*)&Bs[lr * 64 + lc] = w00;        *(uint4*)&Bs[lr * 64 + lc + 8] = w01;
    *(uint4*)&Bs[(64 + lr) * 64 + lc] = w10; *(uint4*)&Bs[(64 + lr) * 64 + lc + 8] = w11;
    __syncthreads();
    #pragma unroll
    for (int ks = 0; ks < 2; ++ks) {
      short8 af[2], bfr[4];
      #pragma unroll
      for (int i = 0; i < 2; ++i)
        af[i] = *(const short8*)&As[(wm * 32 + i * 16 + mr) * 64 + ks * 32 + qq * 8];
      #pragma unroll
      for (int j = 0; j < 4; ++j)
        bfr[j] = *(const short8*)&Bs[(wn * 64 + j * 16 + mr) * 64 + ks * 32 + qq * 8];
      #pragma unroll
      for (int i = 0; i < 2; ++i)
        #pragma unroll
        for (int j = 0; j < 4; ++j)
          acc[i][j] = __builtin_amdgcn_mfma_f32_16x16x32_bf16(af[i], bfr[j], acc[i][j], 0, 0, 0);
    }
  }
  #pragma unroll
  for (int j = 0; j < 4; ++j) {
    int gn = bn0 + wn * 64 + j * 16 + mr;
    float bv = bias[gn];
    #pragma unroll
    for (int i = 0; i < 2; ++i) {
      #pragma unroll
      for (int r = 0; r < 4; ++r) {
        int gm = bm0 + wm * 32 + i * 16 + qq * 4 + r;
        if (gm < M) {
          float v = acc[i][j][r] + bv;
          ((u16*)out)[(size_t)gm * N + gn] = f2bf(v);
        }
      }
    }
  }
}

// ---------------- LayerNorm: one wave per row, 4 rows/block ----------------
template<int D>
__global__ __launch_bounds__(256) void lnw_kernel(
    const float* __restrict__ in, const float* __restrict__ w, const float* __restrict__ b,
    float* __restrict__ outf, u16* __restrict__ outb)
{
  constexpr int NV = D / 64;
  int lane = threadIdx.x & 63, wv = threadIdx.x >> 6;
  int row = blockIdx.x * 4 + wv;
  const float* xr = in + (size_t)row * D;
  float v[NV];
  float s = 0.f, s2 = 0.f;
  #pragma unroll
  for (int i = 0; i < NV; ++i) {
    v[i] = xr[lane + i * 64];
    s += v[i]; s2 += v[i] * v[i];
  }
  #pragma unroll
  for (int off = 32; off > 0; off >>= 1) { s += __shfl_xor(s, off); s2 += __shfl_xor(s2, off); }
  float mean = s / (float)D;
  float var = s2 / (float)D - mean * mean;
  float inv = rsqrtf(var + 1e-5f);
  #pragma unroll
  for (int i = 0; i < NV; ++i) {
    int col = lane + i * 64;
    float y = (v[i] - mean) * inv * w[col] + b[col];
    size_t o = (size_t)row * D + col;
    if (outf) outf[o] = y;
    if (outb) outb[o] = f2bf(y);
  }
}

// ---------------- V reshape for encoder attention ----------------
__global__ __launch_bounds__(256) void reshape_v_kernel(
    const u16* __restrict__ qkv, u16* __restrict__ vt)
{
  __shared__ __align__(16) u16 T[32 * 136];
  int jt = blockIdx.x, h = blockIdx.y, b = blockIdx.z;
  int t = threadIdx.x;
  int d0 = (t & 3) * 8;
  #pragma unroll
  for (int rep = 0; rep < 2; ++rep) {
    int jl = (t >> 2) + rep * 64;
    uint4 vv = *(const uint4*)(qkv + (size_t)(b * CC + jt * 128 + jl) * 768 + 512 + h * 32 + d0);
    u16 tmp[8]; *(uint4*)tmp = vv;
    int jp = (jl & 15) * 8 + (jl >> 4);
    #pragma unroll
    for (int i = 0; i < 8; ++i) T[(d0 + i) * 136 + jp] = tmp[i];
  }
  __syncthreads();
  int bh = b * 8 + h;
  int d = t >> 3;
  #pragma unroll
  for (int rep = 0; rep < 2; ++rep) {
    int jp = (t & 7) * 8 + rep * 64;
    uint4 vv = *(const uint4*)&T[d * 136 + jp];
    *(uint4*)(vt + (size_t)bh * 16384 + d * 512 + jt * 128 + jp) = vv;
  }
}

// ---------------- encoder self-attention: MFMA flash-style ----------------
__global__ __launch_bounds__(256) void attn_enc2_kernel(
    const u16* __restrict__ qkv, const u16* __restrict__ vt, u16* __restrict__ out)
{
  __shared__ __align__(16) u16 Ks[128 * 40];
  __shared__ __align__(16) u16 Vt[32 * 136];
  __shared__ __align__(16) u16 Pl[4 * 32 * 136];
  int qt = blockIdx.x, h = blockIdx.y, b = blockIdx.z;
  int t = threadIdx.x, lane = t & 63, w = t >> 6;
  int mrow = lane & 15, quad = lane >> 4;
  int bh = b * 8 + h;
  int q0 = qt * 128 + w * 32;
  short8 qf[2];
  #pragma unroll
  for (int mi = 0; mi < 2; ++mi)
    qf[mi] = *(const short8*)(qkv + (size_t)(b * CC + q0 + mi * 16 + mrow) * 768 + h * 32 + quad * 8);
  floatx4 o[2][2];
  #pragma unroll
  for (int mi = 0; mi < 2; ++mi)
    #pragma unroll
    for (int di = 0; di < 2; ++di) o[mi][di] = (floatx4){0.f, 0.f, 0.f, 0.f};
  float lst[2][4] = {{0.f,0.f,0.f,0.f},{0.f,0.f,0.f,0.f}};
  const float sc = 0.17677669529663687f * 1.4426950408889634f;
  const floatx4 zf = (floatx4){0.f, 0.f, 0.f, 0.f};
  for (int jt = 0; jt < 4; ++jt) {
    if (jt) __syncthreads();
    {
      int j = t >> 1, half = t & 1;
      uint4 kk = *(const uint4*)(qkv + (size_t)(b * CC + jt * 128 + j) * 768 + 256 + h * 32 + half * 8);
      *(uint4*)&Ks[j * 40 + half * 8] = kk;
    }
    {
      int d = t >> 3;
      #pragma unroll
      for (int rep = 0; rep < 2; ++rep) {
        int jp = (t & 7) * 8 + rep * 64;
        uint4 vv = *(const uint4*)(vt + (size_t)bh * 16384 + d * 512 + jt * 128 + jp);
        *(uint4*)&Vt[d * 136 + jp] = vv;
      }
    }
    __syncthreads();
    floatx4 s[2][8];
    #pragma unroll
    for (int nj = 0; nj < 8; ++nj) {
      short8 bf = *(const short8*)&Ks[(nj * 16 + mrow) * 40 + quad * 8];
      s[0][nj] = __builtin_amdgcn_mfma_f32_16x16x32_bf16(qf[0], bf, zf, 0, 0, 0);
      s[1][nj] = __builtin_amdgcn_mfma_f32_16x16x32_bf16(qf[1], bf, zf, 0, 0, 0);
    }
    #pragma unroll
    for (int mi = 0; mi < 2; ++mi) {
      #pragma unroll
      for (int r = 0; r < 4; ++r) {
        float ps = 0.f; u16 hv[8];
        #pragma unroll
        for (int nj = 0; nj < 8; ++nj) {
          float p = exp2f(s[mi][nj][r] * sc);
          ps += p; hv[nj] = f2bf(p);
        }
        lst[mi][r] += ps;
        *(uint4*)&Pl[(w * 32 + mi * 16 + quad * 4 + r) * 136 + mrow * 8] = *(uint4*)hv;
      }
    }
    #pragma unroll
    for (int ks = 0; ks < 4; ++ks) {
      short8 a0 = *(const short8*)&Pl[(w * 32 + mrow) * 136 + ks * 32 + quad * 8];
      short8 a1 = *(const short8*)&Pl[(w * 32 + 16 + mrow) * 136 + ks * 32 + quad * 8];
      short8 b0 = *(const short8*)&Vt[mrow * 136 + ks * 32 + quad * 8];
      short8 b1 = *(const short8*)&Vt[(16 + mrow) * 136 + ks * 32 + quad * 8];
      o[0][0] = __builtin_amdgcn_mfma_f32_16x16x32_bf16(a0, b0, o[0][0], 0, 0, 0);
      o[0][1] = __builtin_amdgcn_mfma_f32_16x16x32_bf16(a0, b1, o[0][1], 0, 0, 0);
      o[1][0] = __builtin_amdgcn_mfma_f32_16x16x32_bf16(a1, b0, o[1][0], 0, 0, 0);
      o[1][1] = __builtin_amdgcn_mfma_f32_16x16x32_bf16(a1, b1, o[1][1], 0, 0, 0);
    }
  }
  #pragma unroll
  for (int mi = 0; mi < 2; ++mi) {
    #pragma unroll
    for (int r = 0; r < 4; ++r) {
      float l = lst[mi][r];
      l += __shfl_xor(l, 1); l += __shfl_xor(l, 2);
      l += __shfl_xor(l, 4); l += __shfl_xor(l, 8);
      float inv = 1.f / l;
      int row = b * CC + q0 + mi * 16 + quad * 4 + r;
      #pragma unroll
      for (int di = 0; di < 2; ++di)
        out[(size_t)row * DD + h * 32 + di * 16 + mrow] = f2bf(o[mi][di][r] * inv);
    }
  }
}

// ---------------- prefix cross-attention ----------------
__global__ __launch_bounds__(256) void attn_pref_kernel(
    const u16* __restrict__ qh, const u16* __restrict__ kv, u16* __restrict__ out)
{
  __shared__ float qs[16 * 128];
  __shared__ float prow[16 * 512];
  int h = blockIdx.x, b = blockIdx.y;
  int t = threadIdx.x, lane = t & 63, w = t >> 6;
  for (int idx = t; idx < 2048; idx += 256) {
    int r = idx >> 7, d = idx & 127;
    qs[idx] = bf2f(qh[r * HH + h * 128 + d]);
  }
  __syncthreads();
  float a[8][4];
  #pragma unroll
  for (int tt = 0; tt < 8; ++tt)
    #pragma unroll
    for (int r = 0; r < 4; ++r) a[tt][r] = 0.f;
  for (int dd = 0; dd < 128; dd += 8) {
    float qr[4][8];
    #pragma unroll
    for (int r = 0; r < 4; ++r)
      #pragma unroll
      for (int i = 0; i < 8; ++i) qr[r][i] = qs[(w * 4 + r) * 128 + dd + i];
    #pragma unroll
    for (int tt = 0; tt < 8; ++tt) {
      int j = tt * 64 + lane;
      const u16* kp = kv + ((size_t)(b * CC + j)) * 2048 + h * 128 + dd;
      u16 tk[8]; *(uint4*)tk = *(const uint4*)kp;
      #pragma unroll
      for (int i = 0; i < 8; ++i) {
        float kf = bf2f(tk[i]);
        #pragma unroll
        for (int r = 0; r < 4; ++r) a[tt][r] += qr[r][i] * kf;
      }
    }
  }
  for (int r = 0; r < 4; ++r) {
    float m = -1e30f;
    #pragma unroll
    for (int tt = 0; tt < 8; ++tt) m = fmaxf(m, a[tt][r] * 0.08838834764831845f);
    #pragma unroll
    for (int off = 32; off > 0; off >>= 1) m = fmaxf(m, __shfl_xor(m, off));
    float l = 0.f; float pe[8];
    #pragma unroll
    for (int tt = 0; tt < 8; ++tt) { pe[tt] = __expf(a[tt][r] * 0.08838834764831845f - m); l += pe[tt]; }
    #pragma unroll
    for (int off = 32; off > 0; off >>= 1) l += __shfl_xor(l, off);
    float inv = 1.f / l;
    #pragma unroll
    for (int tt = 0; tt < 8; ++tt) prow[(w * 4 + r) * 512 + tt * 64 + lane] = pe[tt] * inv;
  }
  int dl = lane * 2;
  float ox[4] = {0,0,0,0}, oy[4] = {0,0,0,0};
  for (int j = 0; j < 512; ++j) {
    const u16* vp = kv + ((size_t)(b * CC + j)) * 2048 + 1024 + h * 128 + dl;
    u32 vv = *(const u32*)vp;
    float vx = bf2f((u16)(vv & 0xffff)), vy = bf2f((u16)(vv >> 16));
    #pragma unroll
    for (int r = 0; r < 4; ++r) {
      float pe = prow[(w * 4 + r) * 512 + j];
      ox[r] += pe * vx; oy[r] += pe * vy;
    }
  }
  #pragma unroll
  for (int r = 0; r < 4; ++r) {
    size_t o = ((size_t)(b * PP + w * 4 + r)) * HH + h * 128 + dl;
    u32 pk = (u32)f2bf(ox[r]) | ((u32)f2bf(oy[r]) << 16);
    *(u32*)(out + o) = pk;
  }
}

__global__ __launch_bounds__(256) void fillres_kernel(const float* __restrict__ pq, float* __restrict__ res)
{
  int i = blockIdx.x * 256 + threadIdx.x;
  int pr = (i >> 10) & 15; int chn = i & 1023;
  res[i] = pq[pr * HH + chn];
}

extern "C" void kernel_launch(void* const* d_in, const int* in_sizes, int n_in,
                              void* d_out, int out_size, void* d_ws, size_t ws_size,
                              hipStream_t stream)
{
  const int* vi = (const int*)d_in[0];
  const int* si = (const int*)d_in[1];
  const int* mk = (const int*)d_in[2];
  const float* ve   = (const float*)d_in[3];
  const float* se   = (const float*)d_in[4];
  const float* lpe  = (const float*)d_in[5];
  const float* cpe  = (const float*)d_in[6];
  const float* eiw  = (const float*)d_in[7];
  const float* eib  = (const float*)d_in[8];
  const float* eow  = (const float*)d_in[9];
  const float* eob  = (const float*)d_in[10];
  const float* f1w  = (const float*)d_in[11];
  const float* f1b  = (const float*)d_in[12];
  const float* f2w  = (const float*)d_in[13];
  const float* f2b  = (const float*)d_in[14];
  const float* n1w  = (const float*)d_in[15];
  const float* n1b  = (const float*)d_in[16];
  const float* n2w  = (const float*)d_in[17];
  const float* n2b  = (const float*)d_in[18];
  const float* tlw  = (const float*)d_in[19];
  const float* tlb  = (const float*)d_in[20];
  const float* thw  = (const float*)d_in[21];
  const float* thb  = (const float*)d_in[22];
  const float* pq   = (const float*)d_in[23];
  const float* paiw = (const float*)d_in[24];
  const float* paib = (const float*)d_in[25];
  const float* paow = (const float*)d_in[26];
  const float* paob = (const float*)d_in[27];
  const float* pnw  = (const float*)d_in[28];
  const float* pnb  = (const float*)d_in[29];

  const int NROW = BB * CC;  // 16384
  const size_t MB = 1048576;
  char* base = (char*)d_ws;
  // encoder phase:
  float* x    = (float*)(base);              // [0,16M)
  u16* xb     = (u16*)(base + 32 * MB);      // [32M,40M)
  u16* qkvb   = (u16*)(base + 40 * MB);      // [40M,64M)
  u16* atto   = (u16*)(base + 64 * MB);      // [64M,72M)
  u16* h1     = (u16*)(base + 40 * MB);      // [40M,72M) (qkvb/atto dead when used)
  u16* vtb    = (u16*)(base + 72 * MB);      // [72M,80M)
  u16* wbf    = (u16*)(base + 104 * MB);     // [104M,~118.6M)
  // final phase:
  u16* ch     = (u16*)base;                  // [0,32M)   (x dead after tln)
  u16* tln    = xb;                          // [32M,40M)
  u16* kvb    = (u16*)(base + 40 * MB);      // [40M,104M)
  u16* qh     = (u16*)(base + 120 * MB);
  u16* prefo  = qh + 32768;
  float* prefres = (float*)(base + 122 * MB);
  float* prefout = (float*)(base + 124 * MB);

  u16* eiw_b  = wbf + 0;
  u16* eow_b  = wbf + 786432;
  u16* f1w_b  = wbf + 1048576;
  u16* f2w_b  = wbf + 2097152;
  u16* thw_b  = wbf + 3145728;
  u16* paiw_b = wbf + 3407872;
  u16* paow_b = wbf + 6553600;
  u16* pqb    = wbf + 7602176;

  dim3 blk(256);
  cvt_kernel<<<7440, blk, 0, stream>>>(eiw, eow, f1w, f2w, thw, paiw, paow, pq, wbf);
  embed_kernel<<<NROW, blk, 0, stream>>>(vi, si, mk, ve, se, lpe, cpe, x, xb);
  for (int i = 0; i < NLAY; ++i) {
    // QKV: N=768 as 2 col-blocks of 384
    gwide_kernel<384, false, false><<<dim3(2, NROW/32), blk, 0, stream>>>(
        xb, eiw_b + (size_t)i*768*DD, eib + i*768, nullptr, nullptr, nullptr,
        qkvb, nullptr, nullptr, 768, DD);
    reshape_v_kernel<<<dim3(4, 8, BB), blk, 0, stream>>>(qkvb, vtb);
    attn_enc2_kernel<<<dim3(4, 8, BB), blk, 0, stream>>>(qkvb, vtb, atto);
    // attn-out + residual + LN1 fused
    gwide_kernel<256, false, true><<<dim3(1, NROW/32), blk, 0, stream>>>(
        atto, eow_b + (size_t)i*DD*DD, eob + i*DD, x, n1w + i*DD, n1b + i*DD,
        nullptr, x, xb, DD, DD);
    // FF1 + gelu: N=1024 as 4 col-blocks of 256
    gwide_kernel<256, true, false><<<dim3(4, NROW/32), blk, 0, stream>>>(
        xb, f1w_b + (size_t)i*HH*DD, f1b + i*HH, nullptr, nullptr, nullptr,
        h1, nullptr, nullptr, HH, DD);
    // FF2 + residual + LN2 fused
    gwide_kernel<256, false, true><<<dim3(1, NROW/32), blk, 0, stream>>>(
        h1, f2w_b + (size_t)i*DD*HH, f2b + i*DD, x, n2w + i*DD, n2b + i*DD,
        nullptr, x, xb, DD, HH);
  }
  lnw_kernel<256><<<NROW/4, blk, 0, stream>>>(x, tlw, tlb, nullptr, tln);
  // to_hidden: N=1024 as 4 col-blocks of 256
  gwide_kernel<256, false, false><<<dim3(4, NROW/32), blk, 0, stream>>>(
      tln, thw_b, thb, nullptr, nullptr, nullptr, ch, nullptr, nullptr, HH, DD);
  // fused prefix K|V projection
  gemm128_kernel<<<dim3(2048/128, NROW/128), blk, 0, stream>>>(
      ch, paiw_b + (size_t)HH*HH, paib + HH, nullptr, kvb, NROW, 2048, HH, 0);
  gemm_kernel<<<dim3(1024/128, 1), blk, 0, stream>>>(
      pqb, paiw_b, paib, nullptr, qh, PP, HH, HH, 0);
  attn_pref_kernel<<<dim3(8, BB), blk, 0, stream>>>(qh, kvb, prefo);
  fillres_kernel<<<2048, blk, 0, stream>>>(pq, prefres);
  gemm128_kernel<<<dim3(1024/128, (BB*PP)/128), blk, 0, stream>>>(
      prefo, paow_b, paob, prefres, prefout, BB*PP, HH, HH, 2);
  lnw_kernel<1024><<<(BB*PP)/4, blk, 0, stream>>>(prefout, pnw, pnb, (float*)d_out, nullptr);
}

// Round 6
// 854.467 us; speedup vs baseline: 10.4130x; 1.1003x over previous
//
#include <hip/hip_runtime.h>
#include <hip/hip_bf16.h>

typedef unsigned short u16;
typedef unsigned int u32;
typedef __attribute__((ext_vector_type(8))) short short8;
typedef __attribute__((ext_vector_type(4))) float floatx4;

#define BB 32
#define CC 512
#define LL 16
#define DD 256
#define HH 1024
#define PP 16
#define NLAY 4

__device__ __forceinline__ float bf2f(u16 u) {
  u32 x = ((u32)u) << 16; float f; __builtin_memcpy(&f, &x, 4); return f;
}
__device__ __forceinline__ u16 f2bf(float f) {
  __hip_bfloat16 h = __float2bfloat16(f);
  u16 r; __builtin_memcpy(&r, &h, 2); return r;
}
__device__ __forceinline__ void gload_lds16(const u16* g, u16* l) {
  __builtin_amdgcn_global_load_lds(
      (const __attribute__((address_space(1))) void*)g,
      (__attribute__((address_space(3))) void*)l, 16, 0, 0);
}

// ---------------- fp32 -> bf16 weight conversion ----------------
__global__ __launch_bounds__(256) void cvt_kernel(
    const float* __restrict__ s0, const float* __restrict__ s1,
    const float* __restrict__ s2, const float* __restrict__ s3,
    const float* __restrict__ s4, const float* __restrict__ s5,
    const float* __restrict__ s6, const float* __restrict__ s7,
    u16* __restrict__ dst)
{
  const float* srcs[8] = {s0, s1, s2, s3, s4, s5, s6, s7};
  const int pfx[8] = {786432, 1048576, 2097152, 3145728, 3407872, 6553600, 7602176, 7618560};
  int e = (blockIdx.x * 256 + threadIdx.x) * 4;
  int seg = 0;
  while (e >= pfx[seg]) seg++;
  int start = seg ? pfx[seg - 1] : 0;
  float4 f = *(const float4*)(srcs[seg] + (e - start));
  u16 o[4] = {f2bf(f.x), f2bf(f.y), f2bf(f.z), f2bf(f.w)};
  *(uint2*)(dst + e) = *(const uint2*)o;
}

// ---------------- embed + masked mean pool ----------------
__global__ __launch_bounds__(256) void embed_kernel(
    const int* __restrict__ vi, const int* __restrict__ si, const int* __restrict__ mk,
    const float* __restrict__ ve, const float* __restrict__ se,
    const float* __restrict__ lpe, const float* __restrict__ cpe,
    float* __restrict__ x, u16* __restrict__ xb)
{
  int bc = blockIdx.x;
  int c = bc & (CC - 1);
  int d = threadIdx.x;
  int base = bc * LL;
  float acc = 0.f; int cnt = 0;
  #pragma unroll
  for (int l = 0; l < LL; ++l) {
    if (mk[base + l]) {
      int v = vi[base + l], s = si[base + l];
      acc += ve[v * DD + d] + se[s * DD + d] + lpe[l * DD + d];
      cnt++;
    }
  }
  float r = acc / (float)cnt + cpe[c * DD + d];
  size_t o = (size_t)bc * DD + d;
  x[o] = r; xb[o] = f2bf(r);
}

// ---------------- wide-N GEMM: 32 rows x NC cols per block ----------------
template<int NC, bool GELU, bool LN>
__global__ __launch_bounds__(256) void gwide_kernel(
    const u16* __restrict__ A, const u16* __restrict__ W, const float* __restrict__ bias,
    const float* __restrict__ res, const float* __restrict__ gam, const float* __restrict__ bet,
    u16* __restrict__ outb, float* __restrict__ outx, u16* __restrict__ outxb,
    int N, int K)
{
  constexpr int NT = NC / 32;
  constexpr int NW = NC / 32;
  __shared__ __align__(16) u16 As[32 * 64];
  __shared__ __align__(16) u16 Ws[NC * 64];
  __shared__ float sred[32][2][2];
  int t = threadIdx.x, lane = t & 63, w = t >> 6;
  int wm = w & 1, wn = w >> 1;
  int mrow = lane & 15, quad = lane >> 4;
  int bn0 = blockIdx.x * NC, bm0 = blockIdx.y * 32;

  int rA = t >> 3, gcA = (t & 7) ^ (rA & 7);
  const u16* gAp = A + (size_t)(bm0 + rA) * K + gcA * 8;
  u16* lAp = As + (w * 64) * 8;
  const u16* gWp[NW]; u16* lWp[NW];
  #pragma unroll
  for (int i = 0; i < NW; ++i) {
    int c = i * 256 + t;
    int r = c >> 3, gc = (c & 7) ^ (r & 7);
    gWp[i] = W + (size_t)(bn0 + r) * K + gc * 8;
    lWp[i] = Ws + (i * 256 + w * 64) * 8;
  }
  floatx4 acc[NT];
  #pragma unroll
  for (int nt = 0; nt < NT; ++nt) acc[nt] = (floatx4){0.f, 0.f, 0.f, 0.f};

  for (int k0 = 0; k0 < K; k0 += 64) {
    __syncthreads();
    gload_lds16(gAp, lAp); gAp += 64;
    #pragma unroll
    for (int i = 0; i < NW; ++i) { gload_lds16(gWp[i], lWp[i]); gWp[i] += 64; }
    __syncthreads();
    #pragma unroll
    for (int ks = 0; ks < 2; ++ks) {
      int sw = ((ks * 4 + quad) ^ (mrow & 7)) * 8;
      short8 af = *(const short8*)&As[(wm * 16 + mrow) * 64 + sw];
      #pragma unroll
      for (int nt = 0; nt < NT; ++nt) {
        int rw = wn * (NC / 2) + nt * 16 + mrow;
        short8 bf = *(const short8*)&Ws[rw * 64 + sw];
        acc[nt] = __builtin_amdgcn_mfma_f32_16x16x32_bf16(af, bf, acc[nt], 0, 0, 0);
      }
    }
  }

  if constexpr (LN) {
    float val[NT][4];
    float bv[NT];
    #pragma unroll
    for (int nt = 0; nt < NT; ++nt) bv[nt] = bias[wn * (NC / 2) + nt * 16 + mrow];
    #pragma unroll
    for (int r = 0; r < 4; ++r) {
      int gm = bm0 + wm * 16 + quad * 4 + r;
      float sr = 0.f, s2r = 0.f;
      #pragma unroll
      for (int nt = 0; nt < NT; ++nt) {
        int gn = wn * (NC / 2) + nt * 16 + mrow;
        float v = acc[nt][r] + bv[nt] + res[(size_t)gm * NC + gn];
        val[nt][r] = v; sr += v; s2r += v * v;
      }
      sr += __shfl_xor(sr, 1); s2r += __shfl_xor(s2r, 1);
      sr += __shfl_xor(sr, 2); s2r += __shfl_xor(s2r, 2);
      sr += __shfl_xor(sr, 4); s2r += __shfl_xor(s2r, 4);
      sr += __shfl_xor(sr, 8); s2r += __shfl_xor(s2r, 8);
      if (mrow == 0) { sred[wm * 16 + quad * 4 + r][wn][0] = sr; sred[wm * 16 + quad * 4 + r][wn][1] = s2r; }
    }
    __syncthreads();
    #pragma unroll
    for (int r = 0; r < 4; ++r) {
      int lrow = wm * 16 + quad * 4 + r;
      int gm = bm0 + lrow;
      float S = sred[lrow][0][0] + sred[lrow][1][0];
      float S2 = sred[lrow][0][1] + sred[lrow][1][1];
      float mean = S / (float)NC;
      float var = S2 / (float)NC - mean * mean;
      float inv = rsqrtf(var + 1e-5f);
      #pragma unroll
      for (int nt = 0; nt < NT; ++nt) {
        int gn = wn * (NC / 2) + nt * 16 + mrow;
        float y = (val[nt][r] - mean) * inv * gam[gn] + bet[gn];
        size_t o = (size_t)gm * NC + gn;
        outx[o] = y; outxb[o] = f2bf(y);
      }
    }
  } else {
    #pragma unroll
    for (int nt = 0; nt < NT; ++nt) {
      int gn = bn0 + wn * (NC / 2) + nt * 16 + mrow;
      float bv = bias[gn];
      #pragma unroll
      for (int r = 0; r < 4; ++r) {
        int gm = bm0 + wm * 16 + quad * 4 + r;
        float v = acc[nt][r] + bv;
        if (GELU) v = 0.5f * v * (1.f + erff(v * 0.70710678118654752f));
        outb[(size_t)gm * N + gn] = f2bf(v);
      }
    }
  }
}

// ---------------- KV GEMM, XCD-swizzled, V written transposed+permuted ----------------
// A[16384,1024] @ W[2048,1024]^T + bias. 128x128 tiles, 1D grid 2048.
// Swizzle: XCD(id%8) = 2*(row%4) + (col%2) -> A-tile shared by an XCD pair,
// per-XCD W working set = 8 tiles (2MB, L2-resident).
// cols 0..7  -> K half, row-major kb[row][1024]
// cols 8..15 -> V half, transposed to vtp[(b*8+h)][d][jt*128 + perm(jl)], perm(jl)=(jl&15)*8+(jl>>4)
__global__ __launch_bounds__(256) void gemm128s_kernel(
    const u16* __restrict__ A, const u16* __restrict__ W, const float* __restrict__ bias,
    u16* __restrict__ kb, u16* __restrict__ vtp, int K)
{
  __shared__ __align__(16) u16 SH[128 * 136];   // staging (32KB) / V-transpose tile (34.8KB)
  u16* As = SH;
  u16* Bs = SH + 8192;
  int t = threadIdx.x, lane = t & 63, w = t >> 6;
  int wm = w & 1, wn = w >> 1;
  int mrow = lane & 15, quad = lane >> 4;
  int id = blockIdx.x;
  int g = id >> 6, w6 = id & 63;
  int r4 = (w6 & 7) >> 1;
  int c = ((w6 >> 3) << 1) | (w6 & 1);
  int bm0 = (g * 4 + r4) * 128;
  int bn0 = c * 128;

  const u16* gA[4]; const u16* gB[4];
  u16* lA[4]; u16* lB[4];
  #pragma unroll
  for (int it = 0; it < 4; ++it) {
    int cc = w * 256 + it * 64 + lane;
    int r = cc >> 3;
    int gc = (cc & 7) ^ (r & 7);
    gA[it] = A + (size_t)(bm0 + r) * K + gc * 8;
    gB[it] = W + (size_t)(bn0 + r) * K + gc * 8;
    lA[it] = As + (w * 256 + it * 64) * 8;
    lB[it] = Bs + (w * 256 + it * 64) * 8;
  }
  floatx4 acc[4][4];
  #pragma unroll
  for (int i = 0; i < 4; ++i)
    #pragma unroll
    for (int j = 0; j < 4; ++j)
      acc[i][j] = (floatx4){0.f, 0.f, 0.f, 0.f};
  int sw0 = ((0 * 4 + quad) ^ (mrow & 7)) * 8;
  int sw1 = ((1 * 4 + quad) ^ (mrow & 7)) * 8;

  for (int k0 = 0; k0 < K; k0 += 64) {
    __syncthreads();
    #pragma unroll
    for (int it = 0; it < 4; ++it) { gload_lds16(gA[it], lA[it]); gA[it] += 64; }
    #pragma unroll
    for (int it = 0; it < 4; ++it) { gload_lds16(gB[it], lB[it]); gB[it] += 64; }
    __syncthreads();
    #pragma unroll
    for (int ks = 0; ks < 2; ++ks) {
      int sw = ks ? sw1 : sw0;
      short8 af[4], bfr[4];
      #pragma unroll
      for (int mi = 0; mi < 4; ++mi)
        af[mi] = *(const short8*)&As[(wm * 64 + mi * 16 + mrow) * 64 + sw];
      #pragma unroll
      for (int nj = 0; nj < 4; ++nj)
        bfr[nj] = *(const short8*)&Bs[(wn * 64 + nj * 16 + mrow) * 64 + sw];
      #pragma unroll
      for (int mi = 0; mi < 4; ++mi)
        #pragma unroll
        for (int nj = 0; nj < 4; ++nj)
          acc[mi][nj] = __builtin_amdgcn_mfma_f32_16x16x32_bf16(af[mi], bfr[nj], acc[mi][nj], 0, 0, 0);
    }
  }

  if (c < 8) {
    // K half -> kb, row stride 1024
    #pragma unroll
    for (int nj = 0; nj < 4; ++nj) {
      int gn = bn0 + wn * 64 + nj * 16 + mrow;
      float bv = bias[gn];
      #pragma unroll
      for (int mi = 0; mi < 4; ++mi)
        #pragma unroll
        for (int r = 0; r < 4; ++r) {
          int gm = bm0 + wm * 64 + mi * 16 + quad * 4 + r;
          kb[(size_t)gm * 1024 + gn] = f2bf(acc[mi][nj][r] + bv);
        }
    }
  } else {
    int h = c - 8;
    int b = bm0 >> 9, jt = (bm0 >> 7) & 3;
    __syncthreads();  // done with As/Bs staging reads
    #pragma unroll
    for (int nj = 0; nj < 4; ++nj) {
      int dl = wn * 64 + nj * 16 + mrow;
      float bv = bias[bn0 + dl];
      #pragma unroll
      for (int mi = 0; mi < 4; ++mi) {
        int jp = (quad * 4) * 8 + wm * 4 + mi;  // + r*8 added below
        #pragma unroll
        for (int r = 0; r < 4; ++r)
          SH[dl * 136 + jp + r * 8] = f2bf(acc[mi][nj][r] + bv);
      }
    }
    __syncthreads();
    size_t basev = ((size_t)(b * 8 + h) * 128) * 512 + jt * 128;
    #pragma unroll
    for (int i = 0; i < 8; ++i) {
      int idx = t + i * 256;
      int d = idx >> 4, jc4 = (idx & 15) * 8;
      uint4 v = *(const uint4*)&SH[d * 136 + jc4];
      *(uint4*)(vtp + basev + (size_t)d * 512 + jc4) = v;
    }
  }
}

// ---------------- MFMA GEMM 128x128 (out-proj; flags: 1=gelu, 2=f32 out, 4=pq-broadcast res) ----
__global__ __launch_bounds__(256) void gemm128_kernel(
    const u16* __restrict__ A, const u16* __restrict__ W, const float* __restrict__ bias,
    const float* __restrict__ res, void* __restrict__ out,
    int M, int N, int K, int flags)
{
  __shared__ __align__(16) u16 As[128 * 64];
  __shared__ __align__(16) u16 Bs[128 * 64];
  int t = threadIdx.x;
  int lane = t & 63, w = t >> 6;
  int wm = w & 1, wn = w >> 1;
  int bn0 = blockIdx.x * 128, bm0 = blockIdx.y * 128;
  int mrow = lane & 15, quad = lane >> 4;

  const u16* gA[4]; const u16* gB[4];
  u16* lA[4]; u16* lB[4];
  #pragma unroll
  for (int it = 0; it < 4; ++it) {
    int c = w * 256 + it * 64 + lane;
    int r = c >> 3;
    int gc = (c & 7) ^ (r & 7);
    gA[it] = A + (size_t)(bm0 + r) * K + gc * 8;
    gB[it] = W + (size_t)(bn0 + r) * K + gc * 8;
    lA[it] = As + (w * 256 + it * 64) * 8;
    lB[it] = Bs + (w * 256 + it * 64) * 8;
  }
  floatx4 acc[4][4];
  #pragma unroll
  for (int i = 0; i < 4; ++i)
    #pragma unroll
    for (int j = 0; j < 4; ++j)
      acc[i][j] = (floatx4){0.f, 0.f, 0.f, 0.f};
  int sw0 = ((0 * 4 + quad) ^ (mrow & 7)) * 8;
  int sw1 = ((1 * 4 + quad) ^ (mrow & 7)) * 8;

  for (int k0 = 0; k0 < K; k0 += 64) {
    __syncthreads();
    #pragma unroll
    for (int it = 0; it < 4; ++it) { gload_lds16(gA[it], lA[it]); gA[it] += 64; }
    #pragma unroll
    for (int it = 0; it < 4; ++it) { gload_lds16(gB[it], lB[it]); gB[it] += 64; }
    __syncthreads();
    #pragma unroll
    for (int ks = 0; ks < 2; ++ks) {
      int sw = ks ? sw1 : sw0;
      short8 af[4], bfr[4];
      #pragma unroll
      for (int mi = 0; mi < 4; ++mi)
        af[mi] = *(const short8*)&As[(wm * 64 + mi * 16 + mrow) * 64 + sw];
      #pragma unroll
      for (int nj = 0; nj < 4; ++nj)
        bfr[nj] = *(const short8*)&Bs[(wn * 64 + nj * 16 + mrow) * 64 + sw];
      #pragma unroll
      for (int mi = 0; mi < 4; ++mi)
        #pragma unroll
        for (int nj = 0; nj < 4; ++nj)
          acc[mi][nj] = __builtin_amdgcn_mfma_f32_16x16x32_bf16(af[mi], bfr[nj], acc[mi][nj], 0, 0, 0);
    }
  }
  bool do_gelu = (flags & 1) != 0, of32 = (flags & 2) != 0;
  #pragma unroll
  for (int nj = 0; nj < 4; ++nj) {
    int gn = bn0 + wn * 64 + nj * 16 + mrow;
    float bv = bias[gn];
    #pragma unroll
    for (int mi = 0; mi < 4; ++mi) {
      #pragma unroll
      for (int r = 0; r < 4; ++r) {
        int gm = bm0 + wm * 64 + mi * 16 + quad * 4 + r;
        float v = acc[mi][nj][r] + bv;
        if (do_gelu) v = 0.5f * v * (1.f + erff(v * 0.70710678118654752f));
        if (flags & 4) v += res[(size_t)(gm & 15) * N + gn];
        else if (res) v += res[(size_t)gm * N + gn];
        if (of32) ((float*)out)[(size_t)gm * N + gn] = v;
        else      ((u16*)out)[(size_t)gm * N + gn] = f2bf(v);
      }
    }
  }
}

// ---------------- small-M MFMA GEMM (pq projection) ----------------
__global__ __launch_bounds__(256) void gemm_kernel(
    const u16* __restrict__ A, const u16* __restrict__ W, const float* __restrict__ bias,
    const float* __restrict__ res, void* __restrict__ out,
    int M, int N, int K, int flags)
{
  __shared__ __align__(16) u16 As[64 * 64];
  __shared__ __align__(16) u16 Bs[128 * 64];
  int t = threadIdx.x;
  int lane = t & 63, wv = t >> 6;
  int wm = wv & 1, wn = wv >> 1;
  int bn0 = blockIdx.x * 128, bm0 = blockIdx.y * 64;
  int lr = t >> 2, lc = (t & 3) * 16;
  bool aok = (bm0 + lr) < M;
  const u16* Ap  = A + (size_t)(bm0 + lr) * K + lc;
  const u16* Wp0 = W + (size_t)(bn0 + lr) * K + lc;
  const u16* Wp1 = W + (size_t)(bn0 + 64 + lr) * K + lc;
  floatx4 acc[2][4];
  #pragma unroll
  for (int i = 0; i < 2; ++i)
    #pragma unroll
    for (int j = 0; j < 4; ++j)
      acc[i][j] = (floatx4){0.f, 0.f, 0.f, 0.f};
  int mr = lane & 15, qq = lane >> 4;
  for (int k0 = 0; k0 < K; k0 += 64) {
    uint4 a0 = {0,0,0,0}, a1 = {0,0,0,0};
    if (aok) { a0 = *(const uint4*)Ap; a1 = *(const uint4*)(Ap + 8); }
    uint4 w00 = *(const uint4*)Wp0, w01 = *(const uint4*)(Wp0 + 8);
    uint4 w10 = *(const uint4*)Wp1, w11 = *(const uint4*)(Wp1 + 8);
    Ap += 64; Wp0 += 64; Wp1 += 64;
    __syncthreads();
    *(uint4*)&As[lr * 64 + lc] = a0;         *(uint4*)&As[lr * 64 + lc + 8] = a1;
    *(uint4*)&Bs[lr * 64 + lc] = w00;        *(uint4*)&Bs[lr * 64 + lc + 8] = w01;
    *(uint4*)&Bs[(64 + lr) * 64 + lc] = w10; *(uint4*)&Bs[(64 + lr) * 64 + lc + 8] = w11;
    __syncthreads();
    #pragma unroll
    for (int ks = 0; ks < 2; ++ks) {
      short8 af[2], bfr[4];
      #pragma unroll
      for (int i = 0; i < 2; ++i)
        af[i] = *(const short8*)&As[(wm * 32 + i * 16 + mr) * 64 + ks * 32 + qq * 8];
      #pragma unroll
      for (int j = 0; j < 4; ++j)
        bfr[j] = *(const short8*)&Bs[(wn * 64 + j * 16 + mr) * 64 + ks * 32 + qq * 8];
      #pragma unroll
      for (int i = 0; i < 2; ++i)
        #pragma unroll
        for (int j = 0; j < 4; ++j)
          acc[i][j] = __builtin_amdgcn_mfma_f32_16x16x32_bf16(af[i], bfr[j], acc[i][j], 0, 0, 0);
    }
  }
  #pragma unroll
  for (int j = 0; j < 4; ++j) {
    int gn = bn0 + wn * 64 + j * 16 + mr;
    float bv = bias[gn];
    #pragma unroll
    for (int i = 0; i < 2; ++i) {
      #pragma unroll
      for (int r = 0; r < 4; ++r) {
        int gm = bm0 + wm * 32 + i * 16 + qq * 4 + r;
        if (gm < M) {
          float v = acc[i][j][r] + bv;
          ((u16*)out)[(size_t)gm * N + gn] = f2bf(v);
        }
      }
    }
  }
}

// ---------------- LayerNorm: one wave per row, 4 rows/block ----------------
template<int D>
__global__ __launch_bounds__(256) void lnw_kernel(
    const float* __restrict__ in, const float* __restrict__ w, const float* __restrict__ b,
    float* __restrict__ outf, u16* __restrict__ outb)
{
  constexpr int NV = D / 64;
  int lane = threadIdx.x & 63, wv = threadIdx.x >> 6;
  int row = blockIdx.x * 4 + wv;
  const float* xr = in + (size_t)row * D;
  float v[NV];
  float s = 0.f, s2 = 0.f;
  #pragma unroll
  for (int i = 0; i < NV; ++i) {
    v[i] = xr[lane + i * 64];
    s += v[i]; s2 += v[i] * v[i];
  }
  #pragma unroll
  for (int off = 32; off > 0; off >>= 1) { s += __shfl_xor(s, off); s2 += __shfl_xor(s2, off); }
  float mean = s / (float)D;
  float var = s2 / (float)D - mean * mean;
  float inv = rsqrtf(var + 1e-5f);
  #pragma unroll
  for (int i = 0; i < NV; ++i) {
    int col = lane + i * 64;
    float y = (v[i] - mean) * inv * w[col] + b[col];
    size_t o = (size_t)row * D + col;
    if (outf) outf[o] = y;
    if (outb) outb[o] = f2bf(y);
  }
}

// ---------------- V reshape for encoder attention ----------------
__global__ __launch_bounds__(256) void reshape_v_kernel(
    const u16* __restrict__ qkv, u16* __restrict__ vt)
{
  __shared__ __align__(16) u16 T[32 * 136];
  int jt = blockIdx.x, h = blockIdx.y, b = blockIdx.z;
  int t = threadIdx.x;
  int d0 = (t & 3) * 8;
  #pragma unroll
  for (int rep = 0; rep < 2; ++rep) {
    int jl = (t >> 2) + rep * 64;
    uint4 vv = *(const uint4*)(qkv + (size_t)(b * CC + jt * 128 + jl) * 768 + 512 + h * 32 + d0);
    u16 tmp[8]; *(uint4*)tmp = vv;
    int jp = (jl & 15) * 8 + (jl >> 4);
    #pragma unroll
    for (int i = 0; i < 8; ++i) T[(d0 + i) * 136 + jp] = tmp[i];
  }
  __syncthreads();
  int bh = b * 8 + h;
  int d = t >> 3;
  #pragma unroll
  for (int rep = 0; rep < 2; ++rep) {
    int jp = (t & 7) * 8 + rep * 64;
    uint4 vv = *(const uint4*)&T[d * 136 + jp];
    *(uint4*)(vt + (size_t)bh * 16384 + d * 512 + jt * 128 + jp) = vv;
  }
}

// ---------------- encoder self-attention: MFMA flash-style ----------------
__global__ __launch_bounds__(256) void attn_enc2_kernel(
    const u16* __restrict__ qkv, const u16* __restrict__ vt, u16* __restrict__ out)
{
  __shared__ __align__(16) u16 Ks[128 * 40];
  __shared__ __align__(16) u16 Vt[32 * 136];
  __shared__ __align__(16) u16 Pl[4 * 32 * 136];
  int qt = blockIdx.x, h = blockIdx.y, b = blockIdx.z;
  int t = threadIdx.x, lane = t & 63, w = t >> 6;
  int mrow = lane & 15, quad = lane >> 4;
  int bh = b * 8 + h;
  int q0 = qt * 128 + w * 32;
  short8 qf[2];
  #pragma unroll
  for (int mi = 0; mi < 2; ++mi)
    qf[mi] = *(const short8*)(qkv + (size_t)(b * CC + q0 + mi * 16 + mrow) * 768 + h * 32 + quad * 8);
  floatx4 o[2][2];
  #pragma unroll
  for (int mi = 0; mi < 2; ++mi)
    #pragma unroll
    for (int di = 0; di < 2; ++di) o[mi][di] = (floatx4){0.f, 0.f, 0.f, 0.f};
  float lst[2][4] = {{0.f,0.f,0.f,0.f},{0.f,0.f,0.f,0.f}};
  const float sc = 0.17677669529663687f * 1.4426950408889634f;
  const floatx4 zf = (floatx4){0.f, 0.f, 0.f, 0.f};
  for (int jt = 0; jt < 4; ++jt) {
    if (jt) __syncthreads();
    {
      int j = t >> 1, half = t & 1;
      uint4 kk = *(const uint4*)(qkv + (size_t)(b * CC + jt * 128 + j) * 768 + 256 + h * 32 + half * 8);
      *(uint4*)&Ks[j * 40 + half * 8] = kk;
    }
    {
      int d = t >> 3;
      #pragma unroll
      for (int rep = 0; rep < 2; ++rep) {
        int jp = (t & 7) * 8 + rep * 64;
        uint4 vv = *(const uint4*)(vt + (size_t)bh * 16384 + d * 512 + jt * 128 + jp);
        *(uint4*)&Vt[d * 136 + jp] = vv;
      }
    }
    __syncthreads();
    floatx4 s[2][8];
    #pragma unroll
    for (int nj = 0; nj < 8; ++nj) {
      short8 bf = *(const short8*)&Ks[(nj * 16 + mrow) * 40 + quad * 8];
      s[0][nj] = __builtin_amdgcn_mfma_f32_16x16x32_bf16(qf[0], bf, zf, 0, 0, 0);
      s[1][nj] = __builtin_amdgcn_mfma_f32_16x16x32_bf16(qf[1], bf, zf, 0, 0, 0);
    }
    #pragma unroll
    for (int mi = 0; mi < 2; ++mi) {
      #pragma unroll
      for (int r = 0; r < 4; ++r) {
        float ps = 0.f; u16 hv[8];
        #pragma unroll
        for (int nj = 0; nj < 8; ++nj) {
          float p = exp2f(s[mi][nj][r] * sc);
          ps += p; hv[nj] = f2bf(p);
        }
        lst[mi][r] += ps;
        *(uint4*)&Pl[(w * 32 + mi * 16 + quad * 4 + r) * 136 + mrow * 8] = *(uint4*)hv;
      }
    }
    #pragma unroll
    for (int ks = 0; ks < 4; ++ks) {
      short8 a0 = *(const short8*)&Pl[(w * 32 + mrow) * 136 + ks * 32 + quad * 8];
      short8 a1 = *(const short8*)&Pl[(w * 32 + 16 + mrow) * 136 + ks * 32 + quad * 8];
      short8 b0 = *(const short8*)&Vt[mrow * 136 + ks * 32 + quad * 8];
      short8 b1 = *(const short8*)&Vt[(16 + mrow) * 136 + ks * 32 + quad * 8];
      o[0][0] = __builtin_amdgcn_mfma_f32_16x16x32_bf16(a0, b0, o[0][0], 0, 0, 0);
      o[0][1] = __builtin_amdgcn_mfma_f32_16x16x32_bf16(a0, b1, o[0][1], 0, 0, 0);
      o[1][0] = __builtin_amdgcn_mfma_f32_16x16x32_bf16(a1, b0, o[1][0], 0, 0, 0);
      o[1][1] = __builtin_amdgcn_mfma_f32_16x16x32_bf16(a1, b1, o[1][1], 0, 0, 0);
    }
  }
  #pragma unroll
  for (int mi = 0; mi < 2; ++mi) {
    #pragma unroll
    for (int r = 0; r < 4; ++r) {
      float l = lst[mi][r];
      l += __shfl_xor(l, 1); l += __shfl_xor(l, 2);
      l += __shfl_xor(l, 4); l += __shfl_xor(l, 8);
      float inv = 1.f / l;
      int row = b * CC + q0 + mi * 16 + quad * 4 + r;
      #pragma unroll
      for (int di = 0; di < 2; ++di)
        out[(size_t)row * DD + h * 32 + di * 16 + mrow] = f2bf(o[mi][di][r] * inv);
    }
  }
}

// ---------------- prefix cross-attention v2: MFMA ----------------
// grid (8 h, 32 b); wave w handles j-chunk w*128..+128. dh=128 (4 k-steps).
// Q A-frags and K/V B-frags loaded straight from global; P via LDS k-perm (matches vtp layout).
__global__ __launch_bounds__(256) void attn_pref2_kernel(
    const u16* __restrict__ qh, const u16* __restrict__ kb, const u16* __restrict__ vtp,
    u16* __restrict__ out)
{
  __shared__ __align__(16) u16 Pl[4 * 16 * 136];   // 17.4 KB
  __shared__ float Ored[4 * 16 * 128];             // 32 KB
  __shared__ float Lred[4 * 16];
  int h = blockIdx.x, b = blockIdx.y;
  int t = threadIdx.x, lane = t & 63, w = t >> 6;
  int mrow = lane & 15, quad = lane >> 4;
  const float sc = 0.08838834764831845f * 1.4426950408889634f;  // (1/sqrt(128))*log2e
  const floatx4 zf = (floatx4){0.f, 0.f, 0.f, 0.f};
  short8 qf[4];
  #pragma unroll
  for (int ks = 0; ks < 4; ++ks)
    qf[ks] = *(const short8*)(qh + mrow * HH + h * 128 + ks * 32 + quad * 8);
  // QK^T for my 128-col chunk
  const u16* kbase = kb + ((size_t)(b * CC + w * 128)) * 1024 + h * 128;
  floatx4 s[8];
  #pragma unroll
  for (int nj = 0; nj < 8; ++nj) {
    floatx4 a = zf;
    #pragma unroll
    for (int ks = 0; ks < 4; ++ks) {
      short8 kf = *(const short8*)(kbase + (size_t)(nj * 16 + mrow) * 1024 + ks * 32 + quad * 8);
      a = __builtin_amdgcn_mfma_f32_16x16x32_bf16(qf[ks], kf, a, 0, 0, 0);
    }
    s[nj] = a;
  }
  // exp2 (no max-sub: |scaled scores| << 1), pack P with k-perm, row-sum partials
  #pragma unroll
  for (int r = 0; r < 4; ++r) {
    float ps = 0.f; u16 hv[8];
    #pragma unroll
    for (int nj = 0; nj < 8; ++nj) {
      float p = exp2f(s[nj][r] * sc);
      ps += p; hv[nj] = f2bf(p);
    }
    ps += __shfl_xor(ps, 1); ps += __shfl_xor(ps, 2);
    ps += __shfl_xor(ps, 4); ps += __shfl_xor(ps, 8);
    if (mrow == 0) Lred[w * 16 + quad * 4 + r] = ps;
    *(uint4*)&Pl[(w * 16 + quad * 4 + r) * 136 + mrow * 8] = *(uint4*)hv;
  }
  // PV partial over my chunk
  short8 pa[4];
  #pragma unroll
  for (int ks = 0; ks < 4; ++ks)
    pa[ks] = *(const short8*)&Pl[(w * 16 + mrow) * 136 + ks * 32 + quad * 8];
  const u16* vbase = vtp + ((size_t)(b * 8 + h) * 128) * 512 + w * 128;
  floatx4 o[8];
  #pragma unroll
  for (int nd = 0; nd < 8; ++nd) o[nd] = zf;
  #pragma unroll
  for (int nd = 0; nd < 8; ++nd) {
    #pragma unroll
    for (int ks = 0; ks < 4; ++ks) {
      short8 vf = *(const short8*)(vbase + (size_t)(nd * 16 + mrow) * 512 + ks * 32 + quad * 8);
      o[nd] = __builtin_amdgcn_mfma_f32_16x16x32_bf16(pa[ks], vf, o[nd], 0, 0, 0);
    }
  }
  #pragma unroll
  for (int nd = 0; nd < 8; ++nd)
    #pragma unroll
    for (int r = 0; r < 4; ++r)
      Ored[(w * 16 + quad * 4 + r) * 128 + nd * 16 + mrow] = o[nd][r];
  __syncthreads();
  // combine 4 wave-partials, normalize, write bf16
  int row = t >> 4, d0 = (t & 15) * 8;
  float l = Lred[row] + Lred[16 + row] + Lred[32 + row] + Lred[48 + row];
  float inv = 1.f / l;
  u16 ov[8];
  #pragma unroll
  for (int i = 0; i < 8; ++i) {
    int d = d0 + i;
    float sum = Ored[row * 128 + d] + Ored[(16 + row) * 128 + d]
              + Ored[(32 + row) * 128 + d] + Ored[(48 + row) * 128 + d];
    ov[i] = f2bf(sum * inv);
  }
  *(uint4*)(out + ((size_t)(b * PP + row)) * HH + h * 128 + d0) = *(const uint4*)ov;
}

extern "C" void kernel_launch(void* const* d_in, const int* in_sizes, int n_in,
                              void* d_out, int out_size, void* d_ws, size_t ws_size,
                              hipStream_t stream)
{
  const int* vi = (const int*)d_in[0];
  const int* si = (const int*)d_in[1];
  const int* mk = (const int*)d_in[2];
  const float* ve   = (const float*)d_in[3];
  const float* se   = (const float*)d_in[4];
  const float* lpe  = (const float*)d_in[5];
  const float* cpe  = (const float*)d_in[6];
  const float* eiw  = (const float*)d_in[7];
  const float* eib  = (const float*)d_in[8];
  const float* eow  = (const float*)d_in[9];
  const float* eob  = (const float*)d_in[10];
  const float* f1w  = (const float*)d_in[11];
  const float* f1b  = (const float*)d_in[12];
  const float* f2w  = (const float*)d_in[13];
  const float* f2b  = (const float*)d_in[14];
  const float* n1w  = (const float*)d_in[15];
  const float* n1b  = (const float*)d_in[16];
  const float* n2w  = (const float*)d_in[17];
  const float* n2b  = (const float*)d_in[18];
  const float* tlw  = (const float*)d_in[19];
  const float* tlb  = (const float*)d_in[20];
  const float* thw  = (const float*)d_in[21];
  const float* thb  = (const float*)d_in[22];
  const float* pq   = (const float*)d_in[23];
  const float* paiw = (const float*)d_in[24];
  const float* paib = (const float*)d_in[25];
  const float* paow = (const float*)d_in[26];
  const float* paob = (const float*)d_in[27];
  const float* pnw  = (const float*)d_in[28];
  const float* pnb  = (const float*)d_in[29];

  const int NROW = BB * CC;  // 16384
  const size_t MB = 1048576;
  char* base = (char*)d_ws;
  // encoder phase:
  float* x    = (float*)(base);              // [0,16M)
  u16* xb     = (u16*)(base + 32 * MB);      // [32M,40M)
  u16* qkvb   = (u16*)(base + 40 * MB);      // [40M,64M)
  u16* atto   = (u16*)(base + 64 * MB);      // [64M,72M)
  u16* h1     = (u16*)(base + 40 * MB);      // [40M,72M)
  u16* vtb    = (u16*)(base + 72 * MB);      // [72M,80M)
  u16* wbf    = (u16*)(base + 104 * MB);     // [104M,~118.6M)
  // final phase:
  u16* ch     = (u16*)base;                  // [0,32M)
  u16* tln    = xb;                          // [32M,40M)
  u16* kb     = (u16*)(base + 40 * MB);      // [40M,72M)  prefix K, stride 1024
  u16* vtp    = (u16*)(base + 72 * MB);      // [72M,104M) prefix V^T permuted
  u16* qh     = (u16*)(base + 120 * MB);
  u16* prefo  = qh + 32768;
  float* prefout = (float*)(base + 124 * MB);

  u16* eiw_b  = wbf + 0;
  u16* eow_b  = wbf + 786432;
  u16* f1w_b  = wbf + 1048576;
  u16* f2w_b  = wbf + 2097152;
  u16* thw_b  = wbf + 3145728;
  u16* paiw_b = wbf + 3407872;
  u16* paow_b = wbf + 6553600;
  u16* pqb    = wbf + 7602176;

  dim3 blk(256);
  cvt_kernel<<<7440, blk, 0, stream>>>(eiw, eow, f1w, f2w, thw, paiw, paow, pq, wbf);
  embed_kernel<<<NROW, blk, 0, stream>>>(vi, si, mk, ve, se, lpe, cpe, x, xb);
  for (int i = 0; i < NLAY; ++i) {
    gwide_kernel<384, false, false><<<dim3(2, NROW/32), blk, 0, stream>>>(
        xb, eiw_b + (size_t)i*768*DD, eib + i*768, nullptr, nullptr, nullptr,
        qkvb, nullptr, nullptr, 768, DD);
    reshape_v_kernel<<<dim3(4, 8, BB), blk, 0, stream>>>(qkvb, vtb);
    attn_enc2_kernel<<<dim3(4, 8, BB), blk, 0, stream>>>(qkvb, vtb, atto);
    gwide_kernel<256, false, true><<<dim3(1, NROW/32), blk, 0, stream>>>(
        atto, eow_b + (size_t)i*DD*DD, eob + i*DD, x, n1w + i*DD, n1b + i*DD,
        nullptr, x, xb, DD, DD);
    gwide_kernel<256, true, false><<<dim3(4, NROW/32), blk, 0, stream>>>(
        xb, f1w_b + (size_t)i*HH*DD, f1b + i*HH, nullptr, nullptr, nullptr,
        h1, nullptr, nullptr, HH, DD);
    gwide_kernel<256, false, true><<<dim3(1, NROW/32), blk, 0, stream>>>(
        h1, f2w_b + (size_t)i*DD*HH, f2b + i*DD, x, n2w + i*DD, n2b + i*DD,
        nullptr, x, xb, DD, HH);
  }
  lnw_kernel<256><<<NROW/4, blk, 0, stream>>>(x, tlw, tlb, nullptr, tln);
  gwide_kernel<256, false, false><<<dim3(4, NROW/32), blk, 0, stream>>>(
      tln, thw_b, thb, nullptr, nullptr, nullptr, ch, nullptr, nullptr, HH, DD);
  // fused prefix K|V projection, XCD-swizzled, V transposed in-epilogue
  gemm128s_kernel<<<2048, blk, 0, stream>>>(
      ch, paiw_b + (size_t)HH*HH, paib + HH, kb, vtp, HH);
  gemm_kernel<<<dim3(1024/128, 1), blk, 0, stream>>>(
      pqb, paiw_b, paib, nullptr, qh, PP, HH, HH, 0);
  attn_pref2_kernel<<<dim3(8, BB), blk, 0, stream>>>(qh, kb, vtp, prefo);
  gemm128_kernel<<<dim3(1024/128, (BB*PP)/128), blk, 0, stream>>>(
      prefo, paow_b, paob, pq, prefout, BB*PP, HH, HH, 2 | 4);
  lnw_kernel<1024><<<(BB*PP)/4, blk, 0, stream>>>(prefout, pnw, pnb, (float*)d_out, nullptr);
}

// Round 7
// 849.944 us; speedup vs baseline: 10.4684x; 1.0053x over previous
//
#include <hip/hip_runtime.h>
#include <hip/hip_bf16.h>

typedef unsigned short u16;
typedef unsigned int u32;
typedef __attribute__((ext_vector_type(8))) short short8;
typedef __attribute__((ext_vector_type(4))) float floatx4;

#define BB 32
#define CC 512
#define LL 16
#define DD 256
#define HH 1024
#define PP 16
#define NLAY 4

__device__ __forceinline__ float bf2f(u16 u) {
  u32 x = ((u32)u) << 16; float f; __builtin_memcpy(&f, &x, 4); return f;
}
__device__ __forceinline__ u16 f2bf(float f) {
  __hip_bfloat16 h = __float2bfloat16(f);
  u16 r; __builtin_memcpy(&r, &h, 2); return r;
}
__device__ __forceinline__ void gload_lds16(const u16* g, u16* l) {
  __builtin_amdgcn_global_load_lds(
      (const __attribute__((address_space(1))) void*)g,
      (__attribute__((address_space(3))) void*)l, 16, 0, 0);
}

// ---------------- fp32 -> bf16 conversion: 8 weight tensors + 4 embedding tables ----------------
__global__ __launch_bounds__(256) void cvt_kernel(
    const float* __restrict__ s0, const float* __restrict__ s1,
    const float* __restrict__ s2, const float* __restrict__ s3,
    const float* __restrict__ s4, const float* __restrict__ s5,
    const float* __restrict__ s6, const float* __restrict__ s7,
    const float* __restrict__ s8, const float* __restrict__ s9,
    const float* __restrict__ s10, const float* __restrict__ s11,
    u16* __restrict__ dst)
{
  const float* srcs[12] = {s0, s1, s2, s3, s4, s5, s6, s7, s8, s9, s10, s11};
  const int pfx[12] = {786432, 1048576, 2097152, 3145728, 3407872, 6553600, 7602176,
                       7618560, 7749888, 7750656, 7754752, 7885824};
  int e = (blockIdx.x * 256 + threadIdx.x) * 4;
  int seg = 0;
  while (e >= pfx[seg]) seg++;
  int start = seg ? pfx[seg - 1] : 0;
  float4 f = *(const float4*)(srcs[seg] + (e - start));
  u16 o[4] = {f2bf(f.x), f2bf(f.y), f2bf(f.z), f2bf(f.w)};
  *(uint2*)(dst + e) = *(const uint2*)o;
}

// ---------------- embed + masked mean pool (bf16 tables) ----------------
__global__ __launch_bounds__(256) void embed_kernel(
    const int* __restrict__ vi, const int* __restrict__ si, const int* __restrict__ mk,
    const u16* __restrict__ veb, const u16* __restrict__ seb,
    const u16* __restrict__ lpeb, const u16* __restrict__ cpeb,
    u16* __restrict__ xb)
{
  int bc = blockIdx.x;
  int c = bc & (CC - 1);
  int d = threadIdx.x;
  int base = bc * LL;
  float acc = 0.f; int cnt = 0;
  #pragma unroll
  for (int l = 0; l < LL; ++l) {
    if (mk[base + l]) {
      int v = vi[base + l], s = si[base + l];
      acc += bf2f(veb[v * DD + d]) + bf2f(seb[s * DD + d]) + bf2f(lpeb[l * DD + d]);
      cnt++;
    }
  }
  float r = acc / (float)cnt + bf2f(cpeb[c * DD + d]);
  xb[(size_t)bc * DD + d] = f2bf(r);
}

// ---------------- wide-N GEMM: 32 rows x NC cols per block ----------------
// LN=true (NC==256, grid.x==1): v = acc+bias+res(bf16); y = LN(v); DLN: z = LN2(y); out bf16.
// else: optional GELU, bf16 out stride N.
template<int NC, bool GELU, bool LN, bool DLN>
__global__ __launch_bounds__(256) void gwide_kernel(
    const u16* __restrict__ A, const u16* __restrict__ W, const float* __restrict__ bias,
    const u16* __restrict__ resb, const float* __restrict__ gam, const float* __restrict__ bet,
    const float* __restrict__ gam2, const float* __restrict__ bet2,
    u16* __restrict__ out, int N, int K)
{
  constexpr int NT = NC / 32;
  __shared__ __align__(16) u16 As[32 * 64];
  __shared__ __align__(16) u16 Ws[NC * 64];
  __shared__ float sred[32][2][2];
  __shared__ float sred2[32][2][2];
  int t = threadIdx.x, lane = t & 63, w = t >> 6;
  int wm = w & 1, wn = w >> 1;
  int mrow = lane & 15, quad = lane >> 4;
  int bn0 = blockIdx.x * NC, bm0 = blockIdx.y * 32;

  int rA = t >> 3, gcA = (t & 7) ^ (rA & 7);
  const u16* gAp = A + (size_t)(bm0 + rA) * K + gcA * 8;
  u16* lAp = As + (w * 64) * 8;
  const u16* gW0 = W + (size_t)(bn0 + rA) * K + gcA * 8;
  u16* lW0 = Ws + (w * 64) * 8;

  floatx4 acc[NT];
  #pragma unroll
  for (int nt = 0; nt < NT; ++nt) acc[nt] = (floatx4){0.f, 0.f, 0.f, 0.f};

  for (int k0 = 0; k0 < K; k0 += 64) {
    __syncthreads();
    gload_lds16(gAp, lAp); gAp += 64;
    #pragma unroll
    for (int i = 0; i < NT; ++i)
      gload_lds16(gW0 + (size_t)i * 32 * K, lW0 + i * 2048);
    gW0 += 64;
    __syncthreads();
    #pragma unroll
    for (int ks = 0; ks < 2; ++ks) {
      int sw = ((ks * 4 + quad) ^ (mrow & 7)) * 8;
      short8 af = *(const short8*)&As[(wm * 16 + mrow) * 64 + sw];
      #pragma unroll
      for (int nt = 0; nt < NT; ++nt) {
        int rw = wn * (NC / 2) + nt * 16 + mrow;
        short8 bf = *(const short8*)&Ws[rw * 64 + sw];
        acc[nt] = __builtin_amdgcn_mfma_f32_16x16x32_bf16(af, bf, acc[nt], 0, 0, 0);
      }
    }
  }

  if constexpr (LN) {
    float val[NT][4];
    float bv[NT];
    #pragma unroll
    for (int nt = 0; nt < NT; ++nt) bv[nt] = bias[wn * 128 + nt * 16 + mrow];
    #pragma unroll
    for (int r = 0; r < 4; ++r) {
      int gm = bm0 + wm * 16 + quad * 4 + r;
      float sr = 0.f, s2r = 0.f;
      #pragma unroll
      for (int nt = 0; nt < NT; ++nt) {
        int gn = wn * 128 + nt * 16 + mrow;
        float v = acc[nt][r] + bv[nt] + bf2f(resb[(size_t)gm * 256 + gn]);
        val[nt][r] = v; sr += v; s2r += v * v;
      }
      sr += __shfl_xor(sr, 1); s2r += __shfl_xor(s2r, 1);
      sr += __shfl_xor(sr, 2); s2r += __shfl_xor(s2r, 2);
      sr += __shfl_xor(sr, 4); s2r += __shfl_xor(s2r, 4);
      sr += __shfl_xor(sr, 8); s2r += __shfl_xor(s2r, 8);
      if (mrow == 0) { sred[wm * 16 + quad * 4 + r][wn][0] = sr; sred[wm * 16 + quad * 4 + r][wn][1] = s2r; }
    }
    __syncthreads();
    #pragma unroll
    for (int r = 0; r < 4; ++r) {
      int lrow = wm * 16 + quad * 4 + r;
      float S = sred[lrow][0][0] + sred[lrow][1][0];
      float S2 = sred[lrow][0][1] + sred[lrow][1][1];
      float mean = S * (1.f / 256.f);
      float var = S2 * (1.f / 256.f) - mean * mean;
      float inv = rsqrtf(var + 1e-5f);
      float sr2 = 0.f, s2r2 = 0.f;
      #pragma unroll
      for (int nt = 0; nt < NT; ++nt) {
        int gn = wn * 128 + nt * 16 + mrow;
        float y = (val[nt][r] - mean) * inv * gam[gn] + bet[gn];
        val[nt][r] = y;
        if constexpr (DLN) { sr2 += y; s2r2 += y * y; }
        else out[(size_t)(bm0 + lrow) * 256 + gn] = f2bf(y);
      }
      if constexpr (DLN) {
        sr2 += __shfl_xor(sr2, 1); s2r2 += __shfl_xor(s2r2, 1);
        sr2 += __shfl_xor(sr2, 2); s2r2 += __shfl_xor(s2r2, 2);
        sr2 += __shfl_xor(sr2, 4); s2r2 += __shfl_xor(s2r2, 4);
        sr2 += __shfl_xor(sr2, 8); s2r2 += __shfl_xor(s2r2, 8);
        if (mrow == 0) { sred2[lrow][wn][0] = sr2; sred2[lrow][wn][1] = s2r2; }
      }
    }
    if constexpr (DLN) {
      __syncthreads();
      #pragma unroll
      for (int r = 0; r < 4; ++r) {
        int lrow = wm * 16 + quad * 4 + r;
        float S = sred2[lrow][0][0] + sred2[lrow][1][0];
        float S2 = sred2[lrow][0][1] + sred2[lrow][1][1];
        float mean = S * (1.f / 256.f);
        float var = S2 * (1.f / 256.f) - mean * mean;
        float inv = rsqrtf(var + 1e-5f);
        #pragma unroll
        for (int nt = 0; nt < NT; ++nt) {
          int gn = wn * 128 + nt * 16 + mrow;
          float z = (val[nt][r] - mean) * inv * gam2[gn] + bet2[gn];
          out[(size_t)(bm0 + lrow) * 256 + gn] = f2bf(z);
        }
      }
    }
  } else {
    #pragma unroll
    for (int nt = 0; nt < NT; ++nt) {
      int gn = bn0 + wn * (NC / 2) + nt * 16 + mrow;
      float bv = bias[gn];
      #pragma unroll
      for (int r = 0; r < 4; ++r) {
        int gm = bm0 + wm * 16 + quad * 4 + r;
        float v = acc[nt][r] + bv;
        if (GELU) v = 0.5f * v * (1.f + erff(v * 0.70710678118654752f));
        out[(size_t)gm * N + gn] = f2bf(v);
      }
    }
  }
}

// ---------------- KV GEMM, XCD-swizzled, V written transposed+permuted ----------------
__global__ __launch_bounds__(256) void gemm128s_kernel(
    const u16* __restrict__ A, const u16* __restrict__ W, const float* __restrict__ bias,
    u16* __restrict__ kb, u16* __restrict__ vtp, int K)
{
  __shared__ __align__(16) u16 SH[128 * 136];
  u16* As = SH;
  u16* Bs = SH + 8192;
  int t = threadIdx.x, lane = t & 63, w = t >> 6;
  int wm = w & 1, wn = w >> 1;
  int mrow = lane & 15, quad = lane >> 4;
  int id = blockIdx.x;
  int g = id >> 6, w6 = id & 63;
  int r4 = (w6 & 7) >> 1;
  int c = ((w6 >> 3) << 1) | (w6 & 1);
  int bm0 = (g * 4 + r4) * 128;
  int bn0 = c * 128;

  const u16* gA[4]; const u16* gB[4];
  u16* lA[4]; u16* lB[4];
  #pragma unroll
  for (int it = 0; it < 4; ++it) {
    int cc = w * 256 + it * 64 + lane;
    int r = cc >> 3;
    int gc = (cc & 7) ^ (r & 7);
    gA[it] = A + (size_t)(bm0 + r) * K + gc * 8;
    gB[it] = W + (size_t)(bn0 + r) * K + gc * 8;
    lA[it] = As + (w * 256 + it * 64) * 8;
    lB[it] = Bs + (w * 256 + it * 64) * 8;
  }
  floatx4 acc[4][4];
  #pragma unroll
  for (int i = 0; i < 4; ++i)
    #pragma unroll
    for (int j = 0; j < 4; ++j)
      acc[i][j] = (floatx4){0.f, 0.f, 0.f, 0.f};
  int sw0 = ((0 * 4 + quad) ^ (mrow & 7)) * 8;
  int sw1 = ((1 * 4 + quad) ^ (mrow & 7)) * 8;

  for (int k0 = 0; k0 < K; k0 += 64) {
    __syncthreads();
    #pragma unroll
    for (int it = 0; it < 4; ++it) { gload_lds16(gA[it], lA[it]); gA[it] += 64; }
    #pragma unroll
    for (int it = 0; it < 4; ++it) { gload_lds16(gB[it], lB[it]); gB[it] += 64; }
    __syncthreads();
    #pragma unroll
    for (int ks = 0; ks < 2; ++ks) {
      int sw = ks ? sw1 : sw0;
      short8 af[4], bfr[4];
      #pragma unroll
      for (int mi = 0; mi < 4; ++mi)
        af[mi] = *(const short8*)&As[(wm * 64 + mi * 16 + mrow) * 64 + sw];
      #pragma unroll
      for (int nj = 0; nj < 4; ++nj)
        bfr[nj] = *(const short8*)&Bs[(wn * 64 + nj * 16 + mrow) * 64 + sw];
      #pragma unroll
      for (int mi = 0; mi < 4; ++mi)
        #pragma unroll
        for (int nj = 0; nj < 4; ++nj)
          acc[mi][nj] = __builtin_amdgcn_mfma_f32_16x16x32_bf16(af[mi], bfr[nj], acc[mi][nj], 0, 0, 0);
    }
  }

  if (c < 8) {
    #pragma unroll
    for (int nj = 0; nj < 4; ++nj) {
      int gn = bn0 + wn * 64 + nj * 16 + mrow;
      float bv = bias[gn];
      #pragma unroll
      for (int mi = 0; mi < 4; ++mi)
        #pragma unroll
        for (int r = 0; r < 4; ++r) {
          int gm = bm0 + wm * 64 + mi * 16 + quad * 4 + r;
          kb[(size_t)gm * 1024 + gn] = f2bf(acc[mi][nj][r] + bv);
        }
    }
  } else {
    int h = c - 8;
    int b = bm0 >> 9, jt = (bm0 >> 7) & 3;
    __syncthreads();
    #pragma unroll
    for (int nj = 0; nj < 4; ++nj) {
      int dl = wn * 64 + nj * 16 + mrow;
      float bv = bias[bn0 + dl];
      #pragma unroll
      for (int mi = 0; mi < 4; ++mi) {
        int jp = (quad * 4) * 8 + wm * 4 + mi;
        #pragma unroll
        for (int r = 0; r < 4; ++r)
          SH[dl * 136 + jp + r * 8] = f2bf(acc[mi][nj][r] + bv);
      }
    }
    __syncthreads();
    size_t basev = ((size_t)(b * 8 + h) * 128) * 512 + jt * 128;
    #pragma unroll
    for (int i = 0; i < 8; ++i) {
      int idx = t + i * 256;
      int d = idx >> 4, jc4 = (idx & 15) * 8;
      uint4 v = *(const uint4*)&SH[d * 136 + jc4];
      *(uint4*)(vtp + basev + (size_t)d * 512 + jc4) = v;
    }
  }
}

// ---------------- MFMA GEMM 128x128 (out-proj; flags: 1=gelu, 2=f32 out, 4=pq-broadcast res) ----
__global__ __launch_bounds__(256) void gemm128_kernel(
    const u16* __restrict__ A, const u16* __restrict__ W, const float* __restrict__ bias,
    const float* __restrict__ res, void* __restrict__ out,
    int M, int N, int K, int flags)
{
  __shared__ __align__(16) u16 As[128 * 64];
  __shared__ __align__(16) u16 Bs[128 * 64];
  int t = threadIdx.x;
  int lane = t & 63, w = t >> 6;
  int wm = w & 1, wn = w >> 1;
  int bn0 = blockIdx.x * 128, bm0 = blockIdx.y * 128;
  int mrow = lane & 15, quad = lane >> 4;

  const u16* gA[4]; const u16* gB[4];
  u16* lA[4]; u16* lB[4];
  #pragma unroll
  for (int it = 0; it < 4; ++it) {
    int c = w * 256 + it * 64 + lane;
    int r = c >> 3;
    int gc = (c & 7) ^ (r & 7);
    gA[it] = A + (size_t)(bm0 + r) * K + gc * 8;
    gB[it] = W + (size_t)(bn0 + r) * K + gc * 8;
    lA[it] = As + (w * 256 + it * 64) * 8;
    lB[it] = Bs + (w * 256 + it * 64) * 8;
  }
  floatx4 acc[4][4];
  #pragma unroll
  for (int i = 0; i < 4; ++i)
    #pragma unroll
    for (int j = 0; j < 4; ++j)
      acc[i][j] = (floatx4){0.f, 0.f, 0.f, 0.f};
  int sw0 = ((0 * 4 + quad) ^ (mrow & 7)) * 8;
  int sw1 = ((1 * 4 + quad) ^ (mrow & 7)) * 8;

  for (int k0 = 0; k0 < K; k0 += 64) {
    __syncthreads();
    #pragma unroll
    for (int it = 0; it < 4; ++it) { gload_lds16(gA[it], lA[it]); gA[it] += 64; }
    #pragma unroll
    for (int it = 0; it < 4; ++it) { gload_lds16(gB[it], lB[it]); gB[it] += 64; }
    __syncthreads();
    #pragma unroll
    for (int ks = 0; ks < 2; ++ks) {
      int sw = ks ? sw1 : sw0;
      short8 af[4], bfr[4];
      #pragma unroll
      for (int mi = 0; mi < 4; ++mi)
        af[mi] = *(const short8*)&As[(wm * 64 + mi * 16 + mrow) * 64 + sw];
      #pragma unroll
      for (int nj = 0; nj < 4; ++nj)
        bfr[nj] = *(const short8*)&Bs[(wn * 64 + nj * 16 + mrow) * 64 + sw];
      #pragma unroll
      for (int mi = 0; mi < 4; ++mi)
        #pragma unroll
        for (int nj = 0; nj < 4; ++nj)
          acc[mi][nj] = __builtin_amdgcn_mfma_f32_16x16x32_bf16(af[mi], bfr[nj], acc[mi][nj], 0, 0, 0);
    }
  }
  bool do_gelu = (flags & 1) != 0, of32 = (flags & 2) != 0;
  #pragma unroll
  for (int nj = 0; nj < 4; ++nj) {
    int gn = bn0 + wn * 64 + nj * 16 + mrow;
    float bv = bias[gn];
    #pragma unroll
    for (int mi = 0; mi < 4; ++mi) {
      #pragma unroll
      for (int r = 0; r < 4; ++r) {
        int gm = bm0 + wm * 64 + mi * 16 + quad * 4 + r;
        float v = acc[mi][nj][r] + bv;
        if (do_gelu) v = 0.5f * v * (1.f + erff(v * 0.70710678118654752f));
        if (flags & 4) v += res[(size_t)(gm & 15) * N + gn];
        else if (res) v += res[(size_t)gm * N + gn];
        if (of32) ((float*)out)[(size_t)gm * N + gn] = v;
        else      ((u16*)out)[(size_t)gm * N + gn] = f2bf(v);
      }
    }
  }
}

// ---------------- small-M MFMA GEMM (pq projection) ----------------
__global__ __launch_bounds__(256) void gemm_kernel(
    const u16* __restrict__ A, const u16* __restrict__ W, const float* __restrict__ bias,
    const float* __restrict__ res, void* __restrict__ out,
    int M, int N, int K, int flags)
{
  __shared__ __align__(16) u16 As[64 * 64];
  __shared__ __align__(16) u16 Bs[128 * 64];
  int t = threadIdx.x;
  int lane = t & 63, wv = t >> 6;
  int wm = wv & 1, wn = wv >> 1;
  int bn0 = blockIdx.x * 128, bm0 = blockIdx.y * 64;
  int lr = t >> 2, lc = (t & 3) * 16;
  bool aok = (bm0 + lr) < M;
  const u16* Ap  = A + (size_t)(bm0 + lr) * K + lc;
  const u16* Wp0 = W + (size_t)(bn0 + lr) * K + lc;
  const u16* Wp1 = W + (size_t)(bn0 + 64 + lr) * K + lc;
  floatx4 acc[2][4];
  #pragma unroll
  for (int i = 0; i < 2; ++i)
    #pragma unroll
    for (int j = 0; j < 4; ++j)
      acc[i][j] = (floatx4){0.f, 0.f, 0.f, 0.f};
  int mr = lane & 15, qq = lane >> 4;
  for (int k0 = 0; k0 < K; k0 += 64) {
    uint4 a0 = {0,0,0,0}, a1 = {0,0,0,0};
    if (aok) { a0 = *(const uint4*)Ap; a1 = *(const uint4*)(Ap + 8); }
    uint4 w00 = *(const uint4*)Wp0, w01 = *(const uint4*)(Wp0 + 8);
    uint4 w10 = *(const uint4*)Wp1, w11 = *(const uint4*)(Wp1 + 8);
    Ap += 64; Wp0 += 64; Wp1 += 64;
    __syncthreads();
    *(uint4*)&As[lr * 64 + lc] = a0;         *(uint4*)&As[lr * 64 + lc + 8] = a1;
    *(uint4*)&Bs[lr * 64 + lc] = w00;        *(uint4*)&Bs[lr * 64 + lc + 8] = w01;
    *(uint4*)&Bs[(64 + lr) * 64 + lc] = w10; *(uint4*)&Bs[(64 + lr) * 64 + lc + 8] = w11;
    __syncthreads();
    #pragma unroll
    for (int ks = 0; ks < 2; ++ks) {
      short8 af[2], bfr[4];
      #pragma unroll
      for (int i = 0; i < 2; ++i)
        af[i] = *(const short8*)&As[(wm * 32 + i * 16 + mr) * 64 + ks * 32 + qq * 8];
      #pragma unroll
      for (int j = 0; j < 4; ++j)
        bfr[j] = *(const short8*)&Bs[(wn * 64 + j * 16 + mr) * 64 + ks * 32 + qq * 8];
      #pragma unroll
      for (int i = 0; i < 2; ++i)
        #pragma unroll
        for (int j = 0; j < 4; ++j)
          acc[i][j] = __builtin_amdgcn_mfma_f32_16x16x32_bf16(af[i], bfr[j], acc[i][j], 0, 0, 0);
    }
  }
  #pragma unroll
  for (int j = 0; j < 4; ++j) {
    int gn = bn0 + wn * 64 + j * 16 + mr;
    float bv = bias[gn];
    #pragma unroll
    for (int i = 0; i < 2; ++i) {
      #pragma unroll
      for (int r = 0; r < 4; ++r) {
        int gm = bm0 + wm * 32 + i * 16 + qq * 4 + r;
        if (gm < M) {
          float v = acc[i][j][r] + bv;
          ((u16*)out)[(size_t)gm * N + gn] = f2bf(v);
        }
      }
    }
  }
}

// ---------------- LayerNorm: one wave per row, 4 rows/block (final output) ----------------
template<int D>
__global__ __launch_bounds__(256) void lnw_kernel(
    const float* __restrict__ in, const float* __restrict__ w, const float* __restrict__ b,
    float* __restrict__ outf, u16* __restrict__ outb)
{
  constexpr int NV = D / 64;
  int lane = threadIdx.x & 63, wv = threadIdx.x >> 6;
  int row = blockIdx.x * 4 + wv;
  const float* xr = in + (size_t)row * D;
  float v[NV];
  float s = 0.f, s2 = 0.f;
  #pragma unroll
  for (int i = 0; i < NV; ++i) {
    v[i] = xr[lane + i * 64];
    s += v[i]; s2 += v[i] * v[i];
  }
  #pragma unroll
  for (int off = 32; off > 0; off >>= 1) { s += __shfl_xor(s, off); s2 += __shfl_xor(s2, off); }
  float mean = s / (float)D;
  float var = s2 / (float)D - mean * mean;
  float inv = rsqrtf(var + 1e-5f);
  #pragma unroll
  for (int i = 0; i < NV; ++i) {
    int col = lane + i * 64;
    float y = (v[i] - mean) * inv * w[col] + b[col];
    size_t o = (size_t)row * D + col;
    if (outf) outf[o] = y;
    if (outb) outb[o] = f2bf(y);
  }
}

// ---------------- V reshape for encoder attention ----------------
__global__ __launch_bounds__(256) void reshape_v_kernel(
    const u16* __restrict__ qkv, u16* __restrict__ vt)
{
  __shared__ __align__(16) u16 T[32 * 136];
  int jt = blockIdx.x, h = blockIdx.y, b = blockIdx.z;
  int t = threadIdx.x;
  int d0 = (t & 3) * 8;
  #pragma unroll
  for (int rep = 0; rep < 2; ++rep) {
    int jl = (t >> 2) + rep * 64;
    uint4 vv = *(const uint4*)(qkv + (size_t)(b * CC + jt * 128 + jl) * 768 + 512 + h * 32 + d0);
    u16 tmp[8]; *(uint4*)tmp = vv;
    int jp = (jl & 15) * 8 + (jl >> 4);
    #pragma unroll
    for (int i = 0; i < 8; ++i) T[(d0 + i) * 136 + jp] = tmp[i];
  }
  __syncthreads();
  int bh = b * 8 + h;
  int d = t >> 3;
  #pragma unroll
  for (int rep = 0; rep < 2; ++rep) {
    int jp = (t & 7) * 8 + rep * 64;
    uint4 vv = *(const uint4*)&T[d * 136 + jp];
    *(uint4*)(vt + (size_t)bh * 16384 + d * 512 + jt * 128 + jp) = vv;
  }
}

// ---------------- encoder self-attention: MFMA flash-style (K staging fixed: full 32 dims) ----
__global__ __launch_bounds__(256) void attn_enc2_kernel(
    const u16* __restrict__ qkv, const u16* __restrict__ vt, u16* __restrict__ out)
{
  __shared__ __align__(16) u16 Ks[128 * 40];
  __shared__ __align__(16) u16 Vt[32 * 136];
  __shared__ __align__(16) u16 Pl[4 * 32 * 136];
  int qt = blockIdx.x, h = blockIdx.y, b = blockIdx.z;
  int t = threadIdx.x, lane = t & 63, w = t >> 6;
  int mrow = lane & 15, quad = lane >> 4;
  int bh = b * 8 + h;
  int q0 = qt * 128 + w * 32;
  short8 qf[2];
  #pragma unroll
  for (int mi = 0; mi < 2; ++mi)
    qf[mi] = *(const short8*)(qkv + (size_t)(b * CC + q0 + mi * 16 + mrow) * 768 + h * 32 + quad * 8);
  floatx4 o[2][2];
  #pragma unroll
  for (int mi = 0; mi < 2; ++mi)
    #pragma unroll
    for (int di = 0; di < 2; ++di) o[mi][di] = (floatx4){0.f, 0.f, 0.f, 0.f};
  float lst[2][4] = {{0.f,0.f,0.f,0.f},{0.f,0.f,0.f,0.f}};
  const float sc = 0.17677669529663687f * 1.4426950408889634f;
  const floatx4 zf = (floatx4){0.f, 0.f, 0.f, 0.f};
  for (int jt = 0; jt < 4; ++jt) {
    if (jt) __syncthreads();
    #pragma unroll
    for (int rep = 0; rep < 2; ++rep) {  // K tile: 128 j x 32 d (full)
      int j = (t >> 2) + rep * 64;
      int q4 = (t & 3) * 8;
      uint4 kk = *(const uint4*)(qkv + (size_t)(b * CC + jt * 128 + j) * 768 + 256 + h * 32 + q4);
      *(uint4*)&Ks[j * 40 + q4] = kk;
    }
    {
      int d = t >> 3;
      #pragma unroll
      for (int rep = 0; rep < 2; ++rep) {
        int jp = (t & 7) * 8 + rep * 64;
        uint4 vv = *(const uint4*)(vt + (size_t)bh * 16384 + d * 512 + jt * 128 + jp);
        *(uint4*)&Vt[d * 136 + jp] = vv;
      }
    }
    __syncthreads();
    floatx4 s[2][8];
    #pragma unroll
    for (int nj = 0; nj < 8; ++nj) {
      short8 bf = *(const short8*)&Ks[(nj * 16 + mrow) * 40 + quad * 8];
      s[0][nj] = __builtin_amdgcn_mfma_f32_16x16x32_bf16(qf[0], bf, zf, 0, 0, 0);
      s[1][nj] = __builtin_amdgcn_mfma_f32_16x16x32_bf16(qf[1], bf, zf, 0, 0, 0);
    }
    #pragma unroll
    for (int mi = 0; mi < 2; ++mi) {
      #pragma unroll
      for (int r = 0; r < 4; ++r) {
        float ps = 0.f; u16 hv[8];
        #pragma unroll
        for (int nj = 0; nj < 8; ++nj) {
          float p = exp2f(s[mi][nj][r] * sc);
          ps += p; hv[nj] = f2bf(p);
        }
        lst[mi][r] += ps;
        *(uint4*)&Pl[(w * 32 + mi * 16 + quad * 4 + r) * 136 + mrow * 8] = *(uint4*)hv;
      }
    }
    #pragma unroll
    for (int ks = 0; ks < 4; ++ks) {
      short8 a0 = *(const short8*)&Pl[(w * 32 + mrow) * 136 + ks * 32 + quad * 8];
      short8 a1 = *(const short8*)&Pl[(w * 32 + 16 + mrow) * 136 + ks * 32 + quad * 8];
      short8 b0 = *(const short8*)&Vt[mrow * 136 + ks * 32 + quad * 8];
      short8 b1 = *(const short8*)&Vt[(16 + mrow) * 136 + ks * 32 + quad * 8];
      o[0][0] = __builtin_amdgcn_mfma_f32_16x16x32_bf16(a0, b0, o[0][0], 0, 0, 0);
      o[0][1] = __builtin_amdgcn_mfma_f32_16x16x32_bf16(a0, b1, o[0][1], 0, 0, 0);
      o[1][0] = __builtin_amdgcn_mfma_f32_16x16x32_bf16(a1, b0, o[1][0], 0, 0, 0);
      o[1][1] = __builtin_amdgcn_mfma_f32_16x16x32_bf16(a1, b1, o[1][1], 0, 0, 0);
    }
  }
  #pragma unroll
  for (int mi = 0; mi < 2; ++mi) {
    #pragma unroll
    for (int r = 0; r < 4; ++r) {
      float l = lst[mi][r];
      l += __shfl_xor(l, 1); l += __shfl_xor(l, 2);
      l += __shfl_xor(l, 4); l += __shfl_xor(l, 8);
      float inv = 1.f / l;
      int row = b * CC + q0 + mi * 16 + quad * 4 + r;
      #pragma unroll
      for (int di = 0; di < 2; ++di)
        out[(size_t)row * DD + h * 32 + di * 16 + mrow] = f2bf(o[mi][di][r] * inv);
    }
  }
}

// ---------------- prefix cross-attention: MFMA ----------------
__global__ __launch_bounds__(256) void attn_pref2_kernel(
    const u16* __restrict__ qh, const u16* __restrict__ kb, const u16* __restrict__ vtp,
    u16* __restrict__ out)
{
  __shared__ __align__(16) u16 Pl[4 * 16 * 136];
  __shared__ float Ored[4 * 16 * 128];
  __shared__ float Lred[4 * 16];
  int h = blockIdx.x, b = blockIdx.y;
  int t = threadIdx.x, lane = t & 63, w = t >> 6;
  int mrow = lane & 15, quad = lane >> 4;
  const float sc = 0.08838834764831845f * 1.4426950408889634f;
  const floatx4 zf = (floatx4){0.f, 0.f, 0.f, 0.f};
  short8 qf[4];
  #pragma unroll
  for (int ks = 0; ks < 4; ++ks)
    qf[ks] = *(const short8*)(qh + mrow * HH + h * 128 + ks * 32 + quad * 8);
  const u16* kbase = kb + ((size_t)(b * CC + w * 128)) * 1024 + h * 128;
  floatx4 s[8];
  #pragma unroll
  for (int nj = 0; nj < 8; ++nj) {
    floatx4 a = zf;
    #pragma unroll
    for (int ks = 0; ks < 4; ++ks) {
      short8 kf = *(const short8*)(kbase + (size_t)(nj * 16 + mrow) * 1024 + ks * 32 + quad * 8);
      a = __builtin_amdgcn_mfma_f32_16x16x32_bf16(qf[ks], kf, a, 0, 0, 0);
    }
    s[nj] = a;
  }
  #pragma unroll
  for (int r = 0; r < 4; ++r) {
    float ps = 0.f; u16 hv[8];
    #pragma unroll
    for (int nj = 0; nj < 8; ++nj) {
      float p = exp2f(s[nj][r] * sc);
      ps += p; hv[nj] = f2bf(p);
    }
    ps += __shfl_xor(ps, 1); ps += __shfl_xor(ps, 2);
    ps += __shfl_xor(ps, 4); ps += __shfl_xor(ps, 8);
    if (mrow == 0) Lred[w * 16 + quad * 4 + r] = ps;
    *(uint4*)&Pl[(w * 16 + quad * 4 + r) * 136 + mrow * 8] = *(uint4*)hv;
  }
  short8 pa[4];
  #pragma unroll
  for (int ks = 0; ks < 4; ++ks)
    pa[ks] = *(const short8*)&Pl[(w * 16 + mrow) * 136 + ks * 32 + quad * 8];
  const u16* vbase = vtp + ((size_t)(b * 8 + h) * 128) * 512 + w * 128;
  floatx4 o[8];
  #pragma unroll
  for (int nd = 0; nd < 8; ++nd) o[nd] = zf;
  #pragma unroll
  for (int nd = 0; nd < 8; ++nd) {
    #pragma unroll
    for (int ks = 0; ks < 4; ++ks) {
      short8 vf = *(const short8*)(vbase + (size_t)(nd * 16 + mrow) * 512 + ks * 32 + quad * 8);
      o[nd] = __builtin_amdgcn_mfma_f32_16x16x32_bf16(pa[ks], vf, o[nd], 0, 0, 0);
    }
  }
  #pragma unroll
  for (int nd = 0; nd < 8; ++nd)
    #pragma unroll
    for (int r = 0; r < 4; ++r)
      Ored[(w * 16 + quad * 4 + r) * 128 + nd * 16 + mrow] = o[nd][r];
  __syncthreads();
  int row = t >> 4, d0 = (t & 15) * 8;
  float l = Lred[row] + Lred[16 + row] + Lred[32 + row] + Lred[48 + row];
  float inv = 1.f / l;
  u16 ov[8];
  #pragma unroll
  for (int i = 0; i < 8; ++i) {
    int d = d0 + i;
    float sum = Ored[row * 128 + d] + Ored[(16 + row) * 128 + d]
              + Ored[(32 + row) * 128 + d] + Ored[(48 + row) * 128 + d];
    ov[i] = f2bf(sum * inv);
  }
  *(uint4*)(out + ((size_t)(b * PP + row)) * HH + h * 128 + d0) = *(const uint4*)ov;
}

extern "C" void kernel_launch(void* const* d_in, const int* in_sizes, int n_in,
                              void* d_out, int out_size, void* d_ws, size_t ws_size,
                              hipStream_t stream)
{
  const int* vi = (const int*)d_in[0];
  const int* si = (const int*)d_in[1];
  const int* mk = (const int*)d_in[2];
  const float* ve   = (const float*)d_in[3];
  const float* se   = (const float*)d_in[4];
  const float* lpe  = (const float*)d_in[5];
  const float* cpe  = (const float*)d_in[6];
  const float* eiw  = (const float*)d_in[7];
  const float* eib  = (const float*)d_in[8];
  const float* eow  = (const float*)d_in[9];
  const float* eob  = (const float*)d_in[10];
  const float* f1w  = (const float*)d_in[11];
  const float* f1b  = (const float*)d_in[12];
  const float* f2w  = (const float*)d_in[13];
  const float* f2b  = (const float*)d_in[14];
  const float* n1w  = (const float*)d_in[15];
  const float* n1b  = (const float*)d_in[16];
  const float* n2w  = (const float*)d_in[17];
  const float* n2b  = (const float*)d_in[18];
  const float* tlw  = (const float*)d_in[19];
  const float* tlb  = (const float*)d_in[20];
  const float* thw  = (const float*)d_in[21];
  const float* thb  = (const float*)d_in[22];
  const float* pq   = (const float*)d_in[23];
  const float* paiw = (const float*)d_in[24];
  const float* paib = (const float*)d_in[25];
  const float* paow = (const float*)d_in[26];
  const float* paob = (const float*)d_in[27];
  const float* pnw  = (const float*)d_in[28];
  const float* pnb  = (const float*)d_in[29];

  const int NROW = BB * CC;  // 16384
  const size_t MB = 1048576;
  char* base = (char*)d_ws;
  // encoder phase:
  u16* xb   = (u16*)(base);                // [0,8M)   bf16 residual stream (post-LN)
  u16* qkvb = (u16*)(base + 8 * MB);       // [8M,32M)
  u16* atto = (u16*)(base + 32 * MB);      // [32M,40M)
  u16* h1   = (u16*)(base + 8 * MB);       // [8M,40M) (qkvb/atto dead)
  u16* vtb  = (u16*)(base + 40 * MB);      // [40M,48M)
  u16* tln  = (u16*)(base + 96 * MB);      // [96M,104M)
  // final phase:
  u16* ch   = (u16*)(base);                // [0,32M)   (xb/h1 dead)
  u16* kb   = (u16*)(base + 32 * MB);      // [32M,64M)
  u16* vtp  = (u16*)(base + 64 * MB);      // [64M,96M)
  u16* wbf  = (u16*)(base + 104 * MB);     // [104M,~119.8M)
  u16* qh    = (u16*)(base + 120 * MB);
  u16* prefo = qh + 32768;
  float* prefout = (float*)(base + 122 * MB);

  u16* eiw_b  = wbf + 0;
  u16* eow_b  = wbf + 786432;
  u16* f1w_b  = wbf + 1048576;
  u16* f2w_b  = wbf + 2097152;
  u16* thw_b  = wbf + 3145728;
  u16* paiw_b = wbf + 3407872;
  u16* paow_b = wbf + 6553600;
  u16* pqb    = wbf + 7602176;
  u16* veb    = wbf + 7618560;
  u16* seb    = wbf + 7749888;
  u16* lpeb   = wbf + 7750656;
  u16* cpeb   = wbf + 7754752;

  dim3 blk(256);
  cvt_kernel<<<7701, blk, 0, stream>>>(eiw, eow, f1w, f2w, thw, paiw, paow, pq,
                                       ve, se, lpe, cpe, wbf);
  embed_kernel<<<NROW, blk, 0, stream>>>(vi, si, mk, veb, seb, lpeb, cpeb, xb);
  for (int i = 0; i < NLAY; ++i) {
    gwide_kernel<384, false, false, false><<<dim3(2, NROW/32), blk, 0, stream>>>(
        xb, eiw_b + (size_t)i*768*DD, eib + i*768, nullptr, nullptr, nullptr, nullptr, nullptr,
        qkvb, 768, DD);
    reshape_v_kernel<<<dim3(4, 8, BB), blk, 0, stream>>>(qkvb, vtb);
    attn_enc2_kernel<<<dim3(4, 8, BB), blk, 0, stream>>>(qkvb, vtb, atto);
    gwide_kernel<256, false, true, false><<<dim3(1, NROW/32), blk, 0, stream>>>(
        atto, eow_b + (size_t)i*DD*DD, eob + i*DD, xb, n1w + i*DD, n1b + i*DD, nullptr, nullptr,
        xb, DD, DD);
    gwide_kernel<512, true, false, false><<<dim3(2, NROW/32), blk, 0, stream>>>(
        xb, f1w_b + (size_t)i*HH*DD, f1b + i*HH, nullptr, nullptr, nullptr, nullptr, nullptr,
        h1, HH, DD);
    if (i < NLAY - 1) {
      gwide_kernel<256, false, true, false><<<dim3(1, NROW/32), blk, 0, stream>>>(
          h1, f2w_b + (size_t)i*DD*HH, f2b + i*DD, xb, n2w + i*DD, n2b + i*DD, nullptr, nullptr,
          xb, DD, HH);
    } else {
      gwide_kernel<256, false, true, true><<<dim3(1, NROW/32), blk, 0, stream>>>(
          h1, f2w_b + (size_t)i*DD*HH, f2b + i*DD, xb, n2w + i*DD, n2b + i*DD, tlw, tlb,
          tln, DD, HH);
    }
  }
  gwide_kernel<512, false, false, false><<<dim3(2, NROW/32), blk, 0, stream>>>(
      tln, thw_b, thb, nullptr, nullptr, nullptr, nullptr, nullptr, ch, HH, DD);
  gemm128s_kernel<<<2048, blk, 0, stream>>>(
      ch, paiw_b + (size_t)HH*HH, paib + HH, kb, vtp, HH);
  gemm_kernel<<<dim3(1024/128, 1), blk, 0, stream>>>(
      pqb, paiw_b, paib, nullptr, qh, PP, HH, HH, 0);
  attn_pref2_kernel<<<dim3(8, BB), blk, 0, stream>>>(qh, kb, vtp, prefo);
  gemm128_kernel<<<dim3(1024/128, (BB*PP)/128), blk, 0, stream>>>(
      prefo, paow_b, paob, pq, prefout, BB*PP, HH, HH, 2 | 4);
  lnw_kernel<1024><<<(BB*PP)/4, blk, 0, stream>>>(prefout, pnw, pnb, (float*)d_out, nullptr);
}

// Round 8
// 816.282 us; speedup vs baseline: 10.9001x; 1.0412x over previous
//
#include <hip/hip_runtime.h>
#include <hip/hip_bf16.h>

typedef unsigned short u16;
typedef unsigned int u32;
typedef __attribute__((ext_vector_type(8))) short short8;
typedef __attribute__((ext_vector_type(4))) float floatx4;

#define BB 32
#define CC 512
#define LL 16
#define DD 256
#define HH 1024
#define PP 16
#define NLAY 4

__device__ __forceinline__ float bf2f(u16 u) {
  u32 x = ((u32)u) << 16; float f; __builtin_memcpy(&f, &x, 4); return f;
}
__device__ __forceinline__ u16 f2bf(float f) {
  __hip_bfloat16 h = __float2bfloat16(f);
  u16 r; __builtin_memcpy(&r, &h, 2); return r;
}
__device__ __forceinline__ void gload_lds16(const u16* g, u16* l) {
  __builtin_amdgcn_global_load_lds(
      (const __attribute__((address_space(1))) void*)g,
      (__attribute__((address_space(3))) void*)l, 16, 0, 0);
}

// ---------------- fp32 -> bf16 conversion: 8 weight tensors + 4 embedding tables ----------------
__global__ __launch_bounds__(256) void cvt_kernel(
    const float* __restrict__ s0, const float* __restrict__ s1,
    const float* __restrict__ s2, const float* __restrict__ s3,
    const float* __restrict__ s4, const float* __restrict__ s5,
    const float* __restrict__ s6, const float* __restrict__ s7,
    const float* __restrict__ s8, const float* __restrict__ s9,
    const float* __restrict__ s10, const float* __restrict__ s11,
    u16* __restrict__ dst)
{
  const float* srcs[12] = {s0, s1, s2, s3, s4, s5, s6, s7, s8, s9, s10, s11};
  const int pfx[12] = {786432, 1048576, 2097152, 3145728, 3407872, 6553600, 7602176,
                       7618560, 7749888, 7750656, 7754752, 7885824};
  int e = (blockIdx.x * 256 + threadIdx.x) * 4;
  int seg = 0;
  while (e >= pfx[seg]) seg++;
  int start = seg ? pfx[seg - 1] : 0;
  float4 f = *(const float4*)(srcs[seg] + (e - start));
  u16 o[4] = {f2bf(f.x), f2bf(f.y), f2bf(f.z), f2bf(f.w)};
  *(uint2*)(dst + e) = *(const uint2*)o;
}

// ---------------- embed + masked mean pool (bf16 tables, 2 clauses/block, u32 loads) --------
__global__ __launch_bounds__(256) void embed_kernel(
    const int* __restrict__ vi, const int* __restrict__ si, const int* __restrict__ mk,
    const u16* __restrict__ veb, const u16* __restrict__ seb,
    const u16* __restrict__ lpeb, const u16* __restrict__ cpeb,
    u16* __restrict__ xb)
{
  int t = threadIdx.x;
  int bc = blockIdx.x * 2 + (t >> 7);
  int c = bc & (CC - 1);
  int dl = (t & 127) * 2;
  int base = bc * LL;
  float a0 = 0.f, a1 = 0.f; int cnt = 0;
  #pragma unroll
  for (int l = 0; l < LL; ++l) {
    if (mk[base + l]) {
      int v = vi[base + l], s = si[base + l];
      u32 vv = *(const u32*)&veb[v * DD + dl];
      u32 sv = *(const u32*)&seb[s * DD + dl];
      u32 lv = *(const u32*)&lpeb[l * DD + dl];
      a0 += bf2f((u16)vv) + bf2f((u16)sv) + bf2f((u16)lv);
      a1 += bf2f((u16)(vv >> 16)) + bf2f((u16)(sv >> 16)) + bf2f((u16)(lv >> 16));
      cnt++;
    }
  }
  u32 cv = *(const u32*)&cpeb[c * DD + dl];
  float inv = 1.f / (float)cnt;
  u32 pk = (u32)f2bf(a0 * inv + bf2f((u16)cv)) | ((u32)f2bf(a1 * inv + bf2f((u16)(cv >> 16))) << 16);
  *(u32*)&xb[(size_t)bc * DD + dl] = pk;
}

// ---------------- wide-N GEMM: 32 rows x NC cols per block ----------------
// LN=true (NC==256, grid.x==1): v = acc+bias+res(bf16); y = LN(v); DLN: z = LN2(y); out bf16.
// else: optional GELU, bf16 out stride N.
template<int NC, bool GELU, bool LN, bool DLN>
__global__ __launch_bounds__(256) void gwide_kernel(
    const u16* __restrict__ A, const u16* __restrict__ W, const float* __restrict__ bias,
    const u16* __restrict__ resb, const float* __restrict__ gam, const float* __restrict__ bet,
    const float* __restrict__ gam2, const float* __restrict__ bet2,
    u16* __restrict__ out, int N, int K)
{
  constexpr int NT = NC / 32;
  __shared__ __align__(16) u16 As[32 * 64];
  __shared__ __align__(16) u16 Ws[NC * 64];
  __shared__ float sred[32][2][2];
  __shared__ float sred2[32][2][2];
  int t = threadIdx.x, lane = t & 63, w = t >> 6;
  int wm = w & 1, wn = w >> 1;
  int mrow = lane & 15, quad = lane >> 4;
  int bn0 = blockIdx.x * NC, bm0 = blockIdx.y * 32;

  int rA = t >> 3, gcA = (t & 7) ^ (rA & 7);
  const u16* gAp = A + (size_t)(bm0 + rA) * K + gcA * 8;
  u16* lAp = As + (w * 64) * 8;
  const u16* gW0 = W + (size_t)(bn0 + rA) * K + gcA * 8;
  u16* lW0 = Ws + (w * 64) * 8;

  floatx4 acc[NT];
  #pragma unroll
  for (int nt = 0; nt < NT; ++nt) acc[nt] = (floatx4){0.f, 0.f, 0.f, 0.f};

  for (int k0 = 0; k0 < K; k0 += 64) {
    __syncthreads();
    gload_lds16(gAp, lAp); gAp += 64;
    #pragma unroll
    for (int i = 0; i < NT; ++i)
      gload_lds16(gW0 + (size_t)i * 32 * K, lW0 + i * 2048);
    gW0 += 64;
    __syncthreads();
    #pragma unroll
    for (int ks = 0; ks < 2; ++ks) {
      int sw = ((ks * 4 + quad) ^ (mrow & 7)) * 8;
      short8 af = *(const short8*)&As[(wm * 16 + mrow) * 64 + sw];
      #pragma unroll
      for (int nt = 0; nt < NT; ++nt) {
        int rw = wn * (NC / 2) + nt * 16 + mrow;
        short8 bf = *(const short8*)&Ws[rw * 64 + sw];
        acc[nt] = __builtin_amdgcn_mfma_f32_16x16x32_bf16(af, bf, acc[nt], 0, 0, 0);
      }
    }
  }

  if constexpr (LN) {
    float val[NT][4];
    float bv[NT];
    #pragma unroll
    for (int nt = 0; nt < NT; ++nt) bv[nt] = bias[wn * 128 + nt * 16 + mrow];
    #pragma unroll
    for (int r = 0; r < 4; ++r) {
      int gm = bm0 + wm * 16 + quad * 4 + r;
      float sr = 0.f, s2r = 0.f;
      #pragma unroll
      for (int nt = 0; nt < NT; ++nt) {
        int gn = wn * 128 + nt * 16 + mrow;
        float v = acc[nt][r] + bv[nt] + bf2f(resb[(size_t)gm * 256 + gn]);
        val[nt][r] = v; sr += v; s2r += v * v;
      }
      sr += __shfl_xor(sr, 1); s2r += __shfl_xor(s2r, 1);
      sr += __shfl_xor(sr, 2); s2r += __shfl_xor(s2r, 2);
      sr += __shfl_xor(sr, 4); s2r += __shfl_xor(s2r, 4);
      sr += __shfl_xor(sr, 8); s2r += __shfl_xor(s2r, 8);
      if (mrow == 0) { sred[wm * 16 + quad * 4 + r][wn][0] = sr; sred[wm * 16 + quad * 4 + r][wn][1] = s2r; }
    }
    __syncthreads();
    #pragma unroll
    for (int r = 0; r < 4; ++r) {
      int lrow = wm * 16 + quad * 4 + r;
      float S = sred[lrow][0][0] + sred[lrow][1][0];
      float S2 = sred[lrow][0][1] + sred[lrow][1][1];
      float mean = S * (1.f / 256.f);
      float var = S2 * (1.f / 256.f) - mean * mean;
      float inv = rsqrtf(var + 1e-5f);
      float sr2 = 0.f, s2r2 = 0.f;
      #pragma unroll
      for (int nt = 0; nt < NT; ++nt) {
        int gn = wn * 128 + nt * 16 + mrow;
        float y = (val[nt][r] - mean) * inv * gam[gn] + bet[gn];
        val[nt][r] = y;
        if constexpr (DLN) { sr2 += y; s2r2 += y * y; }
        else out[(size_t)(bm0 + lrow) * 256 + gn] = f2bf(y);
      }
      if constexpr (DLN) {
        sr2 += __shfl_xor(sr2, 1); s2r2 += __shfl_xor(s2r2, 1);
        sr2 += __shfl_xor(sr2, 2); s2r2 += __shfl_xor(s2r2, 2);
        sr2 += __shfl_xor(sr2, 4); s2r2 += __shfl_xor(s2r2, 4);
        sr2 += __shfl_xor(sr2, 8); s2r2 += __shfl_xor(s2r2, 8);
        if (mrow == 0) { sred2[lrow][wn][0] = sr2; sred2[lrow][wn][1] = s2r2; }
      }
    }
    if constexpr (DLN) {
      __syncthreads();
      #pragma unroll
      for (int r = 0; r < 4; ++r) {
        int lrow = wm * 16 + quad * 4 + r;
        float S = sred2[lrow][0][0] + sred2[lrow][1][0];
        float S2 = sred2[lrow][0][1] + sred2[lrow][1][1];
        float mean = S * (1.f / 256.f);
        float var = S2 * (1.f / 256.f) - mean * mean;
        float inv = rsqrtf(var + 1e-5f);
        #pragma unroll
        for (int nt = 0; nt < NT; ++nt) {
          int gn = wn * 128 + nt * 16 + mrow;
          float z = (val[nt][r] - mean) * inv * gam2[gn] + bet2[gn];
          out[(size_t)(bm0 + lrow) * 256 + gn] = f2bf(z);
        }
      }
    }
  } else {
    #pragma unroll
    for (int nt = 0; nt < NT; ++nt) {
      int gn = bn0 + wn * (NC / 2) + nt * 16 + mrow;
      float bv = bias[gn];
      #pragma unroll
      for (int r = 0; r < 4; ++r) {
        int gm = bm0 + wm * 16 + quad * 4 + r;
        float v = acc[nt][r] + bv;
        if (GELU) v = 0.5f * v * (1.f + erff(v * 0.70710678118654752f));
        out[(size_t)gm * N + gn] = f2bf(v);
      }
    }
  }
}

// ---------------- KV GEMM, XCD-swizzled, V transposed in-epilogue; ids>=2048: qh tile ------
// ids 0..2047: A[16384,1024] @ W[2048,1024]^T; K half -> kb, V half -> vtp (transposed+permuted).
// ids 2048..2055: pqA[16,1024] @ Wq[1024,1024]^T -> qh (rows >=16 discarded; A over-read stays
// inside the wbf workspace buffer, values are finite bf16 garbage, masked on write).
__global__ __launch_bounds__(256) void gemm128s_kernel(
    const u16* __restrict__ A, const u16* __restrict__ W, const float* __restrict__ bias,
    u16* __restrict__ kb, u16* __restrict__ vtp,
    const u16* __restrict__ pqA, const u16* __restrict__ Wq, const float* __restrict__ biasq,
    u16* __restrict__ qh, int K)
{
  __shared__ __align__(16) u16 SH[128 * 136];
  u16* As = SH;
  u16* Bs = SH + 8192;
  int t = threadIdx.x, lane = t & 63, w = t >> 6;
  int wm = w & 1, wn = w >> 1;
  int mrow = lane & 15, quad = lane >> 4;
  int id = blockIdx.x;
  int c, bm0, bn0;
  const u16* Abase; const u16* Wbase;
  if (id < 2048) {
    int g = id >> 6, w6 = id & 63;
    int r4 = (w6 & 7) >> 1;
    c = ((w6 >> 3) << 1) | (w6 & 1);
    bm0 = (g * 4 + r4) * 128;
    bn0 = c * 128;
    Abase = A; Wbase = W;
  } else {
    c = -1; bm0 = 0; bn0 = (id - 2048) * 128;
    Abase = pqA; Wbase = Wq;
  }

  const u16* gA[4]; const u16* gB[4];
  u16* lA[4]; u16* lB[4];
  #pragma unroll
  for (int it = 0; it < 4; ++it) {
    int cc = w * 256 + it * 64 + lane;
    int r = cc >> 3;
    int gc = (cc & 7) ^ (r & 7);
    gA[it] = Abase + (size_t)(bm0 + r) * K + gc * 8;
    gB[it] = Wbase + (size_t)(bn0 + r) * K + gc * 8;
    lA[it] = As + (w * 256 + it * 64) * 8;
    lB[it] = Bs + (w * 256 + it * 64) * 8;
  }
  floatx4 acc[4][4];
  #pragma unroll
  for (int i = 0; i < 4; ++i)
    #pragma unroll
    for (int j = 0; j < 4; ++j)
      acc[i][j] = (floatx4){0.f, 0.f, 0.f, 0.f};
  int sw0 = ((0 * 4 + quad) ^ (mrow & 7)) * 8;
  int sw1 = ((1 * 4 + quad) ^ (mrow & 7)) * 8;

  for (int k0 = 0; k0 < K; k0 += 64) {
    __syncthreads();
    #pragma unroll
    for (int it = 0; it < 4; ++it) { gload_lds16(gA[it], lA[it]); gA[it] += 64; }
    #pragma unroll
    for (int it = 0; it < 4; ++it) { gload_lds16(gB[it], lB[it]); gB[it] += 64; }
    __syncthreads();
    #pragma unroll
    for (int ks = 0; ks < 2; ++ks) {
      int sw = ks ? sw1 : sw0;
      short8 af[4], bfr[4];
      #pragma unroll
      for (int mi = 0; mi < 4; ++mi)
        af[mi] = *(const short8*)&As[(wm * 64 + mi * 16 + mrow) * 64 + sw];
      #pragma unroll
      for (int nj = 0; nj < 4; ++nj)
        bfr[nj] = *(const short8*)&Bs[(wn * 64 + nj * 16 + mrow) * 64 + sw];
      #pragma unroll
      for (int mi = 0; mi < 4; ++mi)
        #pragma unroll
        for (int nj = 0; nj < 4; ++nj)
          acc[mi][nj] = __builtin_amdgcn_mfma_f32_16x16x32_bf16(af[mi], bfr[nj], acc[mi][nj], 0, 0, 0);
    }
  }

  if (c == -1) {
    // qh tile: only rows < 16 are real
    if (wm == 0) {
      #pragma unroll
      for (int nj = 0; nj < 4; ++nj) {
        int gn = bn0 + wn * 64 + nj * 16 + mrow;
        float bv = biasq[gn];
        #pragma unroll
        for (int r = 0; r < 4; ++r) {
          int gm = quad * 4 + r;  // mi=0 only
          qh[(size_t)gm * 1024 + gn] = f2bf(acc[0][nj][r] + bv);
        }
      }
    }
  } else if (c < 8) {
    #pragma unroll
    for (int nj = 0; nj < 4; ++nj) {
      int gn = bn0 + wn * 64 + nj * 16 + mrow;
      float bv = bias[gn];
      #pragma unroll
      for (int mi = 0; mi < 4; ++mi)
        #pragma unroll
        for (int r = 0; r < 4; ++r) {
          int gm = bm0 + wm * 64 + mi * 16 + quad * 4 + r;
          kb[(size_t)gm * 1024 + gn] = f2bf(acc[mi][nj][r] + bv);
        }
    }
  } else {
    int h = c - 8;
    int b = bm0 >> 9, jt = (bm0 >> 7) & 3;
    __syncthreads();
    #pragma unroll
    for (int nj = 0; nj < 4; ++nj) {
      int dl = wn * 64 + nj * 16 + mrow;
      float bv = bias[bn0 + dl];
      #pragma unroll
      for (int mi = 0; mi < 4; ++mi) {
        int jp = (quad * 4) * 8 + wm * 4 + mi;
        #pragma unroll
        for (int r = 0; r < 4; ++r)
          SH[dl * 136 + jp + r * 8] = f2bf(acc[mi][nj][r] + bv);
      }
    }
    __syncthreads();
    size_t basev = ((size_t)(b * 8 + h) * 128) * 512 + jt * 128;
    #pragma unroll
    for (int i = 0; i < 8; ++i) {
      int idx = t + i * 256;
      int d = idx >> 4, jc4 = (idx & 15) * 8;
      uint4 v = *(const uint4*)&SH[d * 136 + jc4];
      *(uint4*)(vtp + basev + (size_t)d * 512 + jc4) = v;
    }
  }
}

// ---------------- MFMA GEMM 128x128 (out-proj; flags: 1=gelu, 2=f32 out, 4=pq-broadcast res) ----
__global__ __launch_bounds__(256) void gemm128_kernel(
    const u16* __restrict__ A, const u16* __restrict__ W, const float* __restrict__ bias,
    const float* __restrict__ res, void* __restrict__ out,
    int M, int N, int K, int flags)
{
  __shared__ __align__(16) u16 As[128 * 64];
  __shared__ __align__(16) u16 Bs[128 * 64];
  int t = threadIdx.x;
  int lane = t & 63, w = t >> 6;
  int wm = w & 1, wn = w >> 1;
  int bn0 = blockIdx.x * 128, bm0 = blockIdx.y * 128;
  int mrow = lane & 15, quad = lane >> 4;

  const u16* gA[4]; const u16* gB[4];
  u16* lA[4]; u16* lB[4];
  #pragma unroll
  for (int it = 0; it < 4; ++it) {
    int c = w * 256 + it * 64 + lane;
    int r = c >> 3;
    int gc = (c & 7) ^ (r & 7);
    gA[it] = A + (size_t)(bm0 + r) * K + gc * 8;
    gB[it] = W + (size_t)(bn0 + r) * K + gc * 8;
    lA[it] = As + (w * 256 + it * 64) * 8;
    lB[it] = Bs + (w * 256 + it * 64) * 8;
  }
  floatx4 acc[4][4];
  #pragma unroll
  for (int i = 0; i < 4; ++i)
    #pragma unroll
    for (int j = 0; j < 4; ++j)
      acc[i][j] = (floatx4){0.f, 0.f, 0.f, 0.f};
  int sw0 = ((0 * 4 + quad) ^ (mrow & 7)) * 8;
  int sw1 = ((1 * 4 + quad) ^ (mrow & 7)) * 8;

  for (int k0 = 0; k0 < K; k0 += 64) {
    __syncthreads();
    #pragma unroll
    for (int it = 0; it < 4; ++it) { gload_lds16(gA[it], lA[it]); gA[it] += 64; }
    #pragma unroll
    for (int it = 0; it < 4; ++it) { gload_lds16(gB[it], lB[it]); gB[it] += 64; }
    __syncthreads();
    #pragma unroll
    for (int ks = 0; ks < 2; ++ks) {
      int sw = ks ? sw1 : sw0;
      short8 af[4], bfr[4];
      #pragma unroll
      for (int mi = 0; mi < 4; ++mi)
        af[mi] = *(const short8*)&As[(wm * 64 + mi * 16 + mrow) * 64 + sw];
      #pragma unroll
      for (int nj = 0; nj < 4; ++nj)
        bfr[nj] = *(const short8*)&Bs[(wn * 64 + nj * 16 + mrow) * 64 + sw];
      #pragma unroll
      for (int mi = 0; mi < 4; ++mi)
        #pragma unroll
        for (int nj = 0; nj < 4; ++nj)
          acc[mi][nj] = __builtin_amdgcn_mfma_f32_16x16x32_bf16(af[mi], bfr[nj], acc[mi][nj], 0, 0, 0);
    }
  }
  bool do_gelu = (flags & 1) != 0, of32 = (flags & 2) != 0;
  #pragma unroll
  for (int nj = 0; nj < 4; ++nj) {
    int gn = bn0 + wn * 64 + nj * 16 + mrow;
    float bv = bias[gn];
    #pragma unroll
    for (int mi = 0; mi < 4; ++mi) {
      #pragma unroll
      for (int r = 0; r < 4; ++r) {
        int gm = bm0 + wm * 64 + mi * 16 + quad * 4 + r;
        float v = acc[mi][nj][r] + bv;
        if (do_gelu) v = 0.5f * v * (1.f + erff(v * 0.70710678118654752f));
        if (flags & 4) v += res[(size_t)(gm & 15) * N + gn];
        else if (res) v += res[(size_t)gm * N + gn];
        if (of32) ((float*)out)[(size_t)gm * N + gn] = v;
        else      ((u16*)out)[(size_t)gm * N + gn] = f2bf(v);
      }
    }
  }
}

// ---------------- LayerNorm: one wave per row, 4 rows/block (final output) ----------------
template<int D>
__global__ __launch_bounds__(256) void lnw_kernel(
    const float* __restrict__ in, const float* __restrict__ w, const float* __restrict__ b,
    float* __restrict__ outf, u16* __restrict__ outb)
{
  constexpr int NV = D / 64;
  int lane = threadIdx.x & 63, wv = threadIdx.x >> 6;
  int row = blockIdx.x * 4 + wv;
  const float* xr = in + (size_t)row * D;
  float v[NV];
  float s = 0.f, s2 = 0.f;
  #pragma unroll
  for (int i = 0; i < NV; ++i) {
    v[i] = xr[lane + i * 64];
    s += v[i]; s2 += v[i] * v[i];
  }
  #pragma unroll
  for (int off = 32; off > 0; off >>= 1) { s += __shfl_xor(s, off); s2 += __shfl_xor(s2, off); }
  float mean = s / (float)D;
  float var = s2 / (float)D - mean * mean;
  float inv = rsqrtf(var + 1e-5f);
  #pragma unroll
  for (int i = 0; i < NV; ++i) {
    int col = lane + i * 64;
    float y = (v[i] - mean) * inv * w[col] + b[col];
    size_t o = (size_t)row * D + col;
    if (outf) outf[o] = y;
    if (outb) outb[o] = f2bf(y);
  }
}

// ---------------- encoder self-attention: MFMA flash-style, V transposed in-kernel ----------
__global__ __launch_bounds__(256) void attn_enc3_kernel(
    const u16* __restrict__ qkv, u16* __restrict__ out)
{
  __shared__ __align__(16) u16 Ks[128 * 40];
  __shared__ __align__(16) u16 Vt[32 * 136];
  __shared__ __align__(16) u16 Pl[4 * 32 * 136];
  int qt = blockIdx.x, h = blockIdx.y, b = blockIdx.z;
  int t = threadIdx.x, lane = t & 63, w = t >> 6;
  int mrow = lane & 15, quad = lane >> 4;
  int q0 = qt * 128 + w * 32;
  short8 qf[2];
  #pragma unroll
  for (int mi = 0; mi < 2; ++mi)
    qf[mi] = *(const short8*)(qkv + (size_t)(b * CC + q0 + mi * 16 + mrow) * 768 + h * 32 + quad * 8);
  floatx4 o[2][2];
  #pragma unroll
  for (int mi = 0; mi < 2; ++mi)
    #pragma unroll
    for (int di = 0; di < 2; ++di) o[mi][di] = (floatx4){0.f, 0.f, 0.f, 0.f};
  float lst[2][4] = {{0.f,0.f,0.f,0.f},{0.f,0.f,0.f,0.f}};
  const float sc = 0.17677669529663687f * 1.4426950408889634f;
  const floatx4 zf = (floatx4){0.f, 0.f, 0.f, 0.f};
  for (int jt = 0; jt < 4; ++jt) {
    if (jt) __syncthreads();
    #pragma unroll
    for (int rep = 0; rep < 2; ++rep) {  // K tile: 128 j x 32 d
      int j = (t >> 2) + rep * 64;
      int q4 = (t & 3) * 8;
      uint4 kk = *(const uint4*)(qkv + (size_t)(b * CC + jt * 128 + j) * 768 + 256 + h * 32 + q4);
      *(uint4*)&Ks[j * 40 + q4] = kk;
    }
    #pragma unroll
    for (int rep = 0; rep < 2; ++rep) {  // V tile: transpose+permute into Vt[d][jp]
      int jl = (t >> 2) + rep * 64;
      int d0 = (t & 3) * 8;
      uint4 vv = *(const uint4*)(qkv + (size_t)(b * CC + jt * 128 + jl) * 768 + 512 + h * 32 + d0);
      u16 tmp[8]; *(uint4*)tmp = vv;
      int jp = (jl & 15) * 8 + (jl >> 4);
      #pragma unroll
      for (int i = 0; i < 8; ++i) Vt[(d0 + i) * 136 + jp] = tmp[i];
    }
    __syncthreads();
    floatx4 s[2][8];
    #pragma unroll
    for (int nj = 0; nj < 8; ++nj) {
      short8 bf = *(const short8*)&Ks[(nj * 16 + mrow) * 40 + quad * 8];
      s[0][nj] = __builtin_amdgcn_mfma_f32_16x16x32_bf16(qf[0], bf, zf, 0, 0, 0);
      s[1][nj] = __builtin_amdgcn_mfma_f32_16x16x32_bf16(qf[1], bf, zf, 0, 0, 0);
    }
    #pragma unroll
    for (int mi = 0; mi < 2; ++mi) {
      #pragma unroll
      for (int r = 0; r < 4; ++r) {
        float ps = 0.f; u16 hv[8];
        #pragma unroll
        for (int nj = 0; nj < 8; ++nj) {
          float p = exp2f(s[mi][nj][r] * sc);
          ps += p; hv[nj] = f2bf(p);
        }
        lst[mi][r] += ps;
        *(uint4*)&Pl[(w * 32 + mi * 16 + quad * 4 + r) * 136 + mrow * 8] = *(uint4*)hv;
      }
    }
    #pragma unroll
    for (int ks = 0; ks < 4; ++ks) {
      short8 a0 = *(const short8*)&Pl[(w * 32 + mrow) * 136 + ks * 32 + quad * 8];
      short8 a1 = *(const short8*)&Pl[(w * 32 + 16 + mrow) * 136 + ks * 32 + quad * 8];
      short8 b0 = *(const short8*)&Vt[mrow * 136 + ks * 32 + quad * 8];
      short8 b1 = *(const short8*)&Vt[(16 + mrow) * 136 + ks * 32 + quad * 8];
      o[0][0] = __builtin_amdgcn_mfma_f32_16x16x32_bf16(a0, b0, o[0][0], 0, 0, 0);
      o[0][1] = __builtin_amdgcn_mfma_f32_16x16x32_bf16(a0, b1, o[0][1], 0, 0, 0);
      o[1][0] = __builtin_amdgcn_mfma_f32_16x16x32_bf16(a1, b0, o[1][0], 0, 0, 0);
      o[1][1] = __builtin_amdgcn_mfma_f32_16x16x32_bf16(a1, b1, o[1][1], 0, 0, 0);
    }
  }
  #pragma unroll
  for (int mi = 0; mi < 2; ++mi) {
    #pragma unroll
    for (int r = 0; r < 4; ++r) {
      float l = lst[mi][r];
      l += __shfl_xor(l, 1); l += __shfl_xor(l, 2);
      l += __shfl_xor(l, 4); l += __shfl_xor(l, 8);
      float inv = 1.f / l;
      int row = b * CC + q0 + mi * 16 + quad * 4 + r;
      #pragma unroll
      for (int di = 0; di < 2; ++di)
        out[(size_t)row * DD + h * 32 + di * 16 + mrow] = f2bf(o[mi][di][r] * inv);
    }
  }
}

// ---------------- prefix cross-attention: MFMA ----------------
__global__ __launch_bounds__(256) void attn_pref2_kernel(
    const u16* __restrict__ qh, const u16* __restrict__ kb, const u16* __restrict__ vtp,
    u16* __restrict__ out)
{
  __shared__ __align__(16) u16 Pl[4 * 16 * 136];
  __shared__ float Ored[4 * 16 * 128];
  __shared__ float Lred[4 * 16];
  int h = blockIdx.x, b = blockIdx.y;
  int t = threadIdx.x, lane = t & 63, w = t >> 6;
  int mrow = lane & 15, quad = lane >> 4;
  const float sc = 0.08838834764831845f * 1.4426950408889634f;
  const floatx4 zf = (floatx4){0.f, 0.f, 0.f, 0.f};
  short8 qf[4];
  #pragma unroll
  for (int ks = 0; ks < 4; ++ks)
    qf[ks] = *(const short8*)(qh + mrow * HH + h * 128 + ks * 32 + quad * 8);
  const u16* kbase = kb + ((size_t)(b * CC + w * 128)) * 1024 + h * 128;
  floatx4 s[8];
  #pragma unroll
  for (int nj = 0; nj < 8; ++nj) {
    floatx4 a = zf;
    #pragma unroll
    for (int ks = 0; ks < 4; ++ks) {
      short8 kf = *(const short8*)(kbase + (size_t)(nj * 16 + mrow) * 1024 + ks * 32 + quad * 8);
      a = __builtin_amdgcn_mfma_f32_16x16x32_bf16(qf[ks], kf, a, 0, 0, 0);
    }
    s[nj] = a;
  }
  #pragma unroll
  for (int r = 0; r < 4; ++r) {
    float ps = 0.f; u16 hv[8];
    #pragma unroll
    for (int nj = 0; nj < 8; ++nj) {
      float p = exp2f(s[nj][r] * sc);
      ps += p; hv[nj] = f2bf(p);
    }
    ps += __shfl_xor(ps, 1); ps += __shfl_xor(ps, 2);
    ps += __shfl_xor(ps, 4); ps += __shfl_xor(ps, 8);
    if (mrow == 0) Lred[w * 16 + quad * 4 + r] = ps;
    *(uint4*)&Pl[(w * 16 + quad * 4 + r) * 136 + mrow * 8] = *(uint4*)hv;
  }
  short8 pa[4];
  #pragma unroll
  for (int ks = 0; ks < 4; ++ks)
    pa[ks] = *(const short8*)&Pl[(w * 16 + mrow) * 136 + ks * 32 + quad * 8];
  const u16* vbase = vtp + ((size_t)(b * 8 + h) * 128) * 512 + w * 128;
  floatx4 o[8];
  #pragma unroll
  for (int nd = 0; nd < 8; ++nd) o[nd] = zf;
  #pragma unroll
  for (int nd = 0; nd < 8; ++nd) {
    #pragma unroll
    for (int ks = 0; ks < 4; ++ks) {
      short8 vf = *(const short8*)(vbase + (size_t)(nd * 16 + mrow) * 512 + ks * 32 + quad * 8);
      o[nd] = __builtin_amdgcn_mfma_f32_16x16x32_bf16(pa[ks], vf, o[nd], 0, 0, 0);
    }
  }
  #pragma unroll
  for (int nd = 0; nd < 8; ++nd)
    #pragma unroll
    for (int r = 0; r < 4; ++r)
      Ored[(w * 16 + quad * 4 + r) * 128 + nd * 16 + mrow] = o[nd][r];
  __syncthreads();
  int row = t >> 4, d0 = (t & 15) * 8;
  float l = Lred[row] + Lred[16 + row] + Lred[32 + row] + Lred[48 + row];
  float inv = 1.f / l;
  u16 ov[8];
  #pragma unroll
  for (int i = 0; i < 8; ++i) {
    int d = d0 + i;
    float sum = Ored[row * 128 + d] + Ored[(16 + row) * 128 + d]
              + Ored[(32 + row) * 128 + d] + Ored[(48 + row) * 128 + d];
    ov[i] = f2bf(sum * inv);
  }
  *(uint4*)(out + ((size_t)(b * PP + row)) * HH + h * 128 + d0) = *(const uint4*)ov;
}

extern "C" void kernel_launch(void* const* d_in, const int* in_sizes, int n_in,
                              void* d_out, int out_size, void* d_ws, size_t ws_size,
                              hipStream_t stream)
{
  const int* vi = (const int*)d_in[0];
  const int* si = (const int*)d_in[1];
  const int* mk = (const int*)d_in[2];
  const float* ve   = (const float*)d_in[3];
  const float* se   = (const float*)d_in[4];
  const float* lpe  = (const float*)d_in[5];
  const float* cpe  = (const float*)d_in[6];
  const float* eiw  = (const float*)d_in[7];
  const float* eib  = (const float*)d_in[8];
  const float* eow  = (const float*)d_in[9];
  const float* eob  = (const float*)d_in[10];
  const float* f1w  = (const float*)d_in[11];
  const float* f1b  = (const float*)d_in[12];
  const float* f2w  = (const float*)d_in[13];
  const float* f2b  = (const float*)d_in[14];
  const float* n1w  = (const float*)d_in[15];
  const float* n1b  = (const float*)d_in[16];
  const float* n2w  = (const float*)d_in[17];
  const float* n2b  = (const float*)d_in[18];
  const float* tlw  = (const float*)d_in[19];
  const float* tlb  = (const float*)d_in[20];
  const float* thw  = (const float*)d_in[21];
  const float* thb  = (const float*)d_in[22];
  const float* pq   = (const float*)d_in[23];
  const float* paiw = (const float*)d_in[24];
  const float* paib = (const float*)d_in[25];
  const float* paow = (const float*)d_in[26];
  const float* paob = (const float*)d_in[27];
  const float* pnw  = (const float*)d_in[28];
  const float* pnb  = (const float*)d_in[29];

  const int NROW = BB * CC;  // 16384
  const size_t MB = 1048576;
  char* base = (char*)d_ws;
  // encoder phase:
  u16* xb   = (u16*)(base);                // [0,8M)   bf16 residual stream (post-LN)
  u16* qkvb = (u16*)(base + 8 * MB);       // [8M,32M)
  u16* atto = (u16*)(base + 32 * MB);      // [32M,40M)
  u16* h1   = (u16*)(base + 8 * MB);       // [8M,40M) (qkvb/atto dead)
  u16* tln  = (u16*)(base + 96 * MB);      // [96M,104M)
  // final phase:
  u16* ch   = (u16*)(base);                // [0,32M)   (xb/h1 dead)
  u16* kb   = (u16*)(base + 32 * MB);      // [32M,64M)
  u16* vtp  = (u16*)(base + 64 * MB);      // [64M,96M)
  u16* wbf  = (u16*)(base + 104 * MB);     // [104M,~119.8M)
  u16* qh    = (u16*)(base + 120 * MB);
  u16* prefo = qh + 32768;
  float* prefout = (float*)(base + 122 * MB);

  u16* eiw_b  = wbf + 0;
  u16* eow_b  = wbf + 786432;
  u16* f1w_b  = wbf + 1048576;
  u16* f2w_b  = wbf + 2097152;
  u16* thw_b  = wbf + 3145728;
  u16* paiw_b = wbf + 3407872;
  u16* paow_b = wbf + 6553600;
  u16* pqb    = wbf + 7602176;
  u16* veb    = wbf + 7618560;
  u16* seb    = wbf + 7749888;
  u16* lpeb   = wbf + 7750656;
  u16* cpeb   = wbf + 7754752;

  dim3 blk(256);
  cvt_kernel<<<7701, blk, 0, stream>>>(eiw, eow, f1w, f2w, thw, paiw, paow, pq,
                                       ve, se, lpe, cpe, wbf);
  embed_kernel<<<NROW/2, blk, 0, stream>>>(vi, si, mk, veb, seb, lpeb, cpeb, xb);
  for (int i = 0; i < NLAY; ++i) {
    gwide_kernel<384, false, false, false><<<dim3(2, NROW/32), blk, 0, stream>>>(
        xb, eiw_b + (size_t)i*768*DD, eib + i*768, nullptr, nullptr, nullptr, nullptr, nullptr,
        qkvb, 768, DD);
    attn_enc3_kernel<<<dim3(4, 8, BB), blk, 0, stream>>>(qkvb, atto);
    gwide_kernel<256, false, true, false><<<dim3(1, NROW/32), blk, 0, stream>>>(
        atto, eow_b + (size_t)i*DD*DD, eob + i*DD, xb, n1w + i*DD, n1b + i*DD, nullptr, nullptr,
        xb, DD, DD);
    gwide_kernel<256, true, false, false><<<dim3(4, NROW/32), blk, 0, stream>>>(
        xb, f1w_b + (size_t)i*HH*DD, f1b + i*HH, nullptr, nullptr, nullptr, nullptr, nullptr,
        h1, HH, DD);
    if (i < NLAY - 1) {
      gwide_kernel<256, false, true, false><<<dim3(1, NROW/32), blk, 0, stream>>>(
          h1, f2w_b + (size_t)i*DD*HH, f2b + i*DD, xb, n2w + i*DD, n2b + i*DD, nullptr, nullptr,
          xb, DD, HH);
    } else {
      gwide_kernel<256, false, true, true><<<dim3(1, NROW/32), blk, 0, stream>>>(
          h1, f2w_b + (size_t)i*DD*HH, f2b + i*DD, xb, n2w + i*DD, n2b + i*DD, tlw, tlb,
          tln, DD, HH);
    }
  }
  gwide_kernel<256, false, false, false><<<dim3(4, NROW/32), blk, 0, stream>>>(
      tln, thw_b, thb, nullptr, nullptr, nullptr, nullptr, nullptr, ch, HH, DD);
  gemm128s_kernel<<<2056, blk, 0, stream>>>(
      ch, paiw_b + (size_t)HH*HH, paib + HH, kb, vtp,
      pqb, paiw_b, paib, qh, HH);
  attn_pref2_kernel<<<dim3(8, BB), blk, 0, stream>>>(qh, kb, vtp, prefo);
  gemm128_kernel<<<dim3(1024/128, (BB*PP)/128), blk, 0, stream>>>(
      prefo, paow_b, paob, pq, prefout, BB*PP, HH, HH, 2 | 4);
  lnw_kernel<1024><<<(BB*PP)/4, blk, 0, stream>>>(prefout, pnw, pnb, (float*)d_out, nullptr);
}